// Round 4
// baseline (654.052 us; speedup 1.0000x reference)
//
#include <hip/hip_runtime.h>
#include <cstdint>
#include <cstddef>

#define NN 50000
#define NE 1600000
#define ET (NE + NN)          // edges + self loops
#define NG 64
#define SCAN_BLOCKS ((NN + 255) / 256)   // 196

// ---------------- K0: transpose W1 [512][64] -> Wt2 k-packed float4: Wt2f4[k4*64 + c] = W1[4k4..4k4+4][c]
__global__ void k_wt(const float* __restrict__ W1, float* __restrict__ Wt2) {
    int id = blockIdx.x * 256 + threadIdx.x;
    if (id >= 128 * 64) return;
    int k4 = id >> 6, c = id & 63;
    float4 v;
    v.x = W1[(k4 * 4 + 0) * 64 + c];
    v.y = W1[(k4 * 4 + 1) * 64 + c];
    v.z = W1[(k4 * 4 + 2) * 64 + c];
    v.w = W1[(k4 * 4 + 3) * 64 + c];
    reinterpret_cast<float4*>(Wt2)[id] = v;
}

// ---------------- K1: h1 = x @ W1, fused alpha_src/alpha_dst reductions.
// 32 rows/block, 256 thr: tr = t>>4 -> rows {n0+tr, n0+tr+16}, tc = t&15 -> cols {4tc..4tc+3}.
// Explicit A/B register double-buffer over k4 pairs: loads of k4+1 issue before FMAs of k4.
__global__ __launch_bounds__(256) void k_gemm1(
    const float* __restrict__ x, const float* __restrict__ Wt2,
    const float* __restrict__ aS, const float* __restrict__ aD,
    float* __restrict__ h1, float* __restrict__ as1, float* __restrict__ ad1) {
    int t = threadIdx.x;
    int tr = t >> 4, tc = t & 15;
    int n0 = blockIdx.x * 32;
    const float4* __restrict__ xf = reinterpret_cast<const float4*>(x);
    const float4* __restrict__ wf = reinterpret_cast<const float4*>(Wt2);

    int r0 = n0 + tr;      r0 = (r0 < NN) ? r0 : (NN - 1);
    int r1 = n0 + tr + 16; r1 = (r1 < NN) ? r1 : (NN - 1);
    const float4* __restrict__ xp0 = xf + (size_t)r0 * 128;
    const float4* __restrict__ xp1 = xf + (size_t)r1 * 128;

    float acc[2][4];
#pragma unroll
    for (int i = 0; i < 2; ++i)
#pragma unroll
        for (int j = 0; j < 4; ++j) acc[i][j] = 0.f;

    float4 wA0, wA1, wA2, wA3, xA0, xA1;
    float4 wB0, wB1, wB2, wB3, xB0, xB1;

#define LDA(kk) { const float4* wp = wf + (kk) * 64 + tc * 4; \
                  wA0 = wp[0]; wA1 = wp[1]; wA2 = wp[2]; wA3 = wp[3]; \
                  xA0 = xp0[(kk)]; xA1 = xp1[(kk)]; }
#define LDB(kk) { const float4* wp = wf + (kk) * 64 + tc * 4; \
                  wB0 = wp[0]; wB1 = wp[1]; wB2 = wp[2]; wB3 = wp[3]; \
                  xB0 = xp0[(kk)]; xB1 = xp1[(kk)]; }
#define FMA4(a, xv, wv) { a += xv.x * wv.x; a += xv.y * wv.y; a += xv.z * wv.z; a += xv.w * wv.w; }
#define FMAA() { FMA4(acc[0][0], xA0, wA0) FMA4(acc[0][1], xA0, wA1) FMA4(acc[0][2], xA0, wA2) FMA4(acc[0][3], xA0, wA3) \
                 FMA4(acc[1][0], xA1, wA0) FMA4(acc[1][1], xA1, wA1) FMA4(acc[1][2], xA1, wA2) FMA4(acc[1][3], xA1, wA3) }
#define FMAB() { FMA4(acc[0][0], xB0, wB0) FMA4(acc[0][1], xB0, wB1) FMA4(acc[0][2], xB0, wB2) FMA4(acc[0][3], xB0, wB3) \
                 FMA4(acc[1][0], xB1, wB0) FMA4(acc[1][1], xB1, wB1) FMA4(acc[1][2], xB1, wB2) FMA4(acc[1][3], xB1, wB3) }

    LDA(0);
    for (int k4 = 0; k4 < 128; k4 += 2) {
        LDB(k4 + 1);
        FMAA();
        if (k4 + 2 < 128) LDA(k4 + 2);
        FMAB();
    }
#undef LDA
#undef LDB
#undef FMA4
#undef FMAA
#undef FMAB

    // epilogue: store h1 + attention dot-products
    int hh = tc >> 1;                 // head of this lane's 4 cols
    int cb = (tc & 1) * 4;            // channel base within head
#pragma unroll
    for (int i = 0; i < 2; ++i) {
        int r = n0 + tr + 16 * i;
        if (r >= NN) continue;
        float4 hv = make_float4(acc[i][0], acc[i][1], acc[i][2], acc[i][3]);
        reinterpret_cast<float4*>(h1)[r * 16 + tc] = hv;
        float ps = acc[i][0] * aS[hh * 8 + cb + 0] + acc[i][1] * aS[hh * 8 + cb + 1] +
                   acc[i][2] * aS[hh * 8 + cb + 2] + acc[i][3] * aS[hh * 8 + cb + 3];
        float pd = acc[i][0] * aD[hh * 8 + cb + 0] + acc[i][1] * aD[hh * 8 + cb + 1] +
                   acc[i][2] * aD[hh * 8 + cb + 2] + acc[i][3] * aD[hh * 8 + cb + 3];
        ps += __shfl_xor(ps, 1);
        pd += __shfl_xor(pd, 1);
        if ((tc & 1) == 0) { as1[r * 8 + hh] = ps; ad1[r * 8 + hh] = pd; }
    }
}

// ---------------- CSR build
__global__ void k_hist(const int* __restrict__ edst, int* __restrict__ deg) {
    int e = blockIdx.x * 256 + threadIdx.x;
    if (e >= ET) return;
    int d = (e < NE) ? edst[e] : (e - NE);
    atomicAdd(&deg[d], 1);
}

__global__ __launch_bounds__(256) void k_scan1(const int* __restrict__ deg,
                                               int* __restrict__ offs, int* __restrict__ bsum) {
    __shared__ int lds_w[4];
    int i = blockIdx.x * 256 + threadIdx.x;
    int v = (i < NN) ? deg[i] : 0;
    int lane = threadIdx.x & 63, wid = threadIdx.x >> 6;
    int incl = v;
#pragma unroll
    for (int ofs = 1; ofs < 64; ofs <<= 1) {
        int o = __shfl_up(incl, ofs);
        if (lane >= ofs) incl += o;
    }
    if (lane == 63) lds_w[wid] = incl;
    __syncthreads();
    int wadd = 0;
    for (int w = 0; w < wid; ++w) wadd += lds_w[w];
    incl += wadd;
    if (i < NN) offs[i] = incl - v;
    if (threadIdx.x == 255) bsum[blockIdx.x] = incl;
}

__global__ void k_scan2(const int* __restrict__ bsum, int* __restrict__ bpre) {
    __shared__ int lds_w[4];
    int lane = threadIdx.x & 63, wid = threadIdx.x >> 6;
    int v = (threadIdx.x < SCAN_BLOCKS) ? bsum[threadIdx.x] : 0;
    int incl = v;
#pragma unroll
    for (int ofs = 1; ofs < 64; ofs <<= 1) {
        int o = __shfl_up(incl, ofs);
        if (lane >= ofs) incl += o;
    }
    if (lane == 63) lds_w[wid] = incl;
    __syncthreads();
    int wadd = 0;
    for (int w = 0; w < wid; ++w) wadd += lds_w[w];
    incl += wadd;
    bpre[threadIdx.x] = incl - v;
}

__global__ void k_scan3(int* __restrict__ offs, const int* __restrict__ bpre, int* __restrict__ cursor) {
    int i = blockIdx.x * 256 + threadIdx.x;
    if (i < NN) {
        int o = offs[i] + bpre[blockIdx.x];
        offs[i] = o;
        cursor[i] = o;
    }
    if (i == 0) offs[NN] = ET;
}

__global__ void k_scatter(const int* __restrict__ esrc, const int* __restrict__ edst,
                          int* __restrict__ cursor, int* __restrict__ csr) {
    int e = blockIdx.x * 256 + threadIdx.x;
    if (e >= ET) return;
    int s, d;
    if (e < NE) { s = esrc[e]; d = edst[e]; } else { s = d = e - NE; }
    int pos = atomicAdd(&cursor[d], 1);
    csr[pos] = s;
}

// ---------------- K4: layer-1 attention aggregation. One wave per dst; lane = (head<<3)|ch.
__global__ __launch_bounds__(256) void k_agg1(
    const int* __restrict__ offs, const int* __restrict__ csr,
    const float* __restrict__ h1, const float* __restrict__ as1, const float* __restrict__ ad1,
    const float* __restrict__ bias1, float* __restrict__ h1o) {
    int l = threadIdx.x & 63;
    int dst = blockIdx.x * 4 + (threadIdx.x >> 6);
    if (dst >= NN) return;
    int h = l >> 3;
    int beg = offs[dst], end = offs[dst + 1];
    float adh = ad1[dst * 8 + h];
    float acc = 0.f, dsum = 0.f;
#pragma clang loop unroll_count(2)
    for (int j = beg; j < end; ++j) {
        int s = csr[j];
        float e = as1[s * 8 + h] + adh;
        e = (e > 0.f) ? e : 0.2f * e;
        float w = __expf(e);
        acc += w * h1[s * 64 + l];
        dsum += w;
    }
    float v = acc / (dsum + 1e-16f) + bias1[l];
    v = (v > 0.f) ? v : (__expf(v) - 1.f);   // ELU
    h1o[dst * 64 + l] = v;
}

// ---------------- K6: h2 = h1o @ W2 (+ alpha2 reductions). 32 lanes per node.
__global__ __launch_bounds__(256) void k_gemm2(
    const float* __restrict__ h1o, const float* __restrict__ W2,
    const float* __restrict__ aS, const float* __restrict__ aD,
    float* __restrict__ h2, float* __restrict__ as2, float* __restrict__ ad2) {
    int c = threadIdx.x & 31;
    int n = blockIdx.x * 8 + (threadIdx.x >> 5);
    if (n >= NN) return;
    const float4* hf = reinterpret_cast<const float4*>(h1o + n * 64);
    float acc = 0.f;
#pragma unroll
    for (int k4 = 0; k4 < 16; ++k4) {
        float4 hv = hf[k4];
        acc += hv.x * W2[(k4 * 4 + 0) * 32 + c] + hv.y * W2[(k4 * 4 + 1) * 32 + c] +
               hv.z * W2[(k4 * 4 + 2) * 32 + c] + hv.w * W2[(k4 * 4 + 3) * 32 + c];
    }
    h2[n * 32 + c] = acc;
    float ps = acc * aS[c], pd = acc * aD[c];
#pragma unroll
    for (int o = 1; o < 32; o <<= 1) { ps += __shfl_xor(ps, o); pd += __shfl_xor(pd, o); }
    if (c == 0) { as2[n] = ps; ad2[n] = pd; }
}

// ---------------- K7: layer-2 aggregation. Half-wave (32 lanes) per dst.
__global__ __launch_bounds__(256) void k_agg2(
    const int* __restrict__ offs, const int* __restrict__ csr,
    const float* __restrict__ h2, const float* __restrict__ as2, const float* __restrict__ ad2,
    const float* __restrict__ bias2, float* __restrict__ o2) {
    int c = threadIdx.x & 31;
    int dst = blockIdx.x * 8 + (threadIdx.x >> 5);
    if (dst >= NN) return;
    int beg = offs[dst], end = offs[dst + 1];
    float adh = ad2[dst];
    float acc = 0.f, dsum = 0.f;
#pragma clang loop unroll_count(2)
    for (int j = beg; j < end; ++j) {
        int s = csr[j];
        float e = as2[s] + adh;
        e = (e > 0.f) ? e : 0.2f * e;
        float w = __expf(e);
        acc += w * h2[s * 32 + c];
        dsum += w;
    }
    o2[dst * 32 + c] = acc / (dsum + 1e-16f) + bias2[c];
}

// ---------------- K8: graph boundaries from sorted batch. lo[g] = first node with batch >= g.
__global__ void k_bound(const int* __restrict__ batch, int* __restrict__ lo) {
    int n = blockIdx.x * 256 + threadIdx.x;
    if (n >= NN) return;
    int b = batch[n];
    if (n == 0) {
        for (int g = 0; g <= b; ++g) lo[g] = 0;
    } else {
        int pb = batch[n - 1];
        for (int g = pb + 1; g <= b; ++g) lo[g] = n;
    }
    if (n == NN - 1) {
        for (int g = b + 1; g <= NG; ++g) lo[g] = NN;
    }
}

// ---------------- K9: pooled sums. 4 blocks per graph, partial-reduce in LDS, one atomic per (block, ch).
__global__ __launch_bounds__(256) void k_pool(const float* __restrict__ o2, const int* __restrict__ lo,
                                              float* __restrict__ pooled) {
    __shared__ float red[256];
    int g = blockIdx.x & 63, q = blockIdx.x >> 6;
    int beg = lo[g], end = lo[g + 1];
    int c = threadIdx.x & 31, row = threadIdx.x >> 5;
    float s = 0.f;
    for (int n = beg + q * 8 + row; n < end; n += 32) s += o2[n * 32 + c];
    red[threadIdx.x] = s;
    __syncthreads();
    for (int rr = 4; rr >= 1; rr >>= 1) {
        if (row < rr) red[threadIdx.x] += red[(row + rr) * 32 + c];
        __syncthreads();
    }
    if (row == 0) atomicAdd(&pooled[g * 32 + c], red[c]);
}

// ---------------- K10: mean + final linear -> out[64][2]
__global__ void k_fin(const float* __restrict__ pooled, const int* __restrict__ lo,
                      const float* __restrict__ lw, const float* __restrict__ lb,
                      float* __restrict__ out) {
    int t = threadIdx.x;
    if (t >= 128) return;
    int g = t >> 1, o = t & 1;
    int cnt = lo[g + 1] - lo[g];
    float inv = 1.f / fmaxf((float)cnt, 1.f);
    float s = 0.f;
#pragma unroll
    for (int c = 0; c < 32; ++c) s += pooled[g * 32 + c] * lw[c * 2 + o];
    out[g * 2 + o] = s * inv + lb[o];
}

// ----------------------------------------------------------------------------
extern "C" void kernel_launch(void* const* d_in, const int* in_sizes, int n_in,
                              void* d_out, int out_size, void* d_ws, size_t ws_size,
                              hipStream_t stream) {
    const float* x   = (const float*)d_in[0];
    const int*   ei  = (const int*)d_in[1];     // [2][NE]
    const int*   bat = (const int*)d_in[2];
    const float* W1  = (const float*)d_in[3];
    const float* aS1 = (const float*)d_in[4];
    const float* aD1 = (const float*)d_in[5];
    const float* b1  = (const float*)d_in[6];
    const float* W2  = (const float*)d_in[7];
    const float* aS2 = (const float*)d_in[8];
    const float* aD2 = (const float*)d_in[9];
    const float* b2  = (const float*)d_in[10];
    const float* lw  = (const float*)d_in[11];
    const float* lb  = (const float*)d_in[12];
    float* out = (float*)d_out;

    const int* esrc = ei;
    const int* edst = ei + NE;

    char* ws = (char*)d_ws;
    size_t off = 0;
    auto alloc = [&](size_t bytes) -> void* {
        off = (off + 255) & ~(size_t)255;
        void* p = ws + off;
        off += bytes;
        return p;
    };

    float* regA = (float*)alloc((size_t)NN * 64 * 4);   // h1; later reused: h2 @ 0, o2 @ NN*32
    float* h1   = regA;
    float* h2   = regA;                                  // alias (h1 dead after k_agg1)
    float* o2   = regA + (size_t)NN * 32;                // alias
    float* h1o  = (float*)alloc((size_t)NN * 64 * 4);
    float* as1  = (float*)alloc((size_t)NN * 8 * 4);
    float* ad1  = (float*)alloc((size_t)NN * 8 * 4);
    float* as2  = (float*)alloc((size_t)NN * 4);
    float* ad2  = (float*)alloc((size_t)NN * 4);
    int*   offs = (int*)alloc((size_t)(NN + 1) * 4);
    int*   deg  = (int*)alloc((size_t)NN * 4);
    int*   cur  = (int*)alloc((size_t)NN * 4);
    int*   csr  = (int*)alloc((size_t)ET * 4);
    float* Wt2  = (float*)alloc((size_t)512 * 64 * 4);
    int*   bsum = (int*)alloc(256 * 4);
    int*   bpre = (int*)alloc(256 * 4);
    float* pooled = (float*)alloc((size_t)NG * 32 * 4);
    int*   lo   = (int*)alloc((size_t)(NG + 1) * 4);
    if (off > ws_size) return;   // workspace too small: leave d_out poisoned (visible failure)

    hipMemsetAsync(deg, 0, (size_t)NN * 4, stream);
    hipMemsetAsync(pooled, 0, (size_t)NG * 32 * 4, stream);

    k_wt<<<32, 256, 0, stream>>>(W1, Wt2);
    k_gemm1<<<(NN + 31) / 32, 256, 0, stream>>>(x, Wt2, aS1, aD1, h1, as1, ad1);

    int eblocks = (ET + 255) / 256;
    k_hist<<<eblocks, 256, 0, stream>>>(edst, deg);
    k_scan1<<<SCAN_BLOCKS, 256, 0, stream>>>(deg, offs, bsum);
    k_scan2<<<1, 256, 0, stream>>>(bsum, bpre);
    k_scan3<<<SCAN_BLOCKS, 256, 0, stream>>>(offs, bpre, cur);
    k_scatter<<<eblocks, 256, 0, stream>>>(esrc, edst, cur, csr);

    k_agg1<<<(NN + 3) / 4, 256, 0, stream>>>(offs, csr, h1, as1, ad1, b1, h1o);
    k_gemm2<<<(NN + 7) / 8, 256, 0, stream>>>(h1o, W2, aS2, aD2, h2, as2, ad2);
    k_agg2<<<(NN + 7) / 8, 256, 0, stream>>>(offs, csr, h2, as2, ad2, b2, o2);

    k_bound<<<SCAN_BLOCKS, 256, 0, stream>>>(bat, lo);
    k_pool<<<NG * 4, 256, 0, stream>>>(o2, lo, pooled);
    k_fin<<<1, 128, 0, stream>>>(pooled, lo, lw, lb, out);
}

// Round 5
// 561.172 us; speedup vs baseline: 1.1655x; 1.1655x over previous
//
#include <hip/hip_runtime.h>
#include <cstdint>
#include <cstddef>

#define NN 50000
#define NE 1600000
#define ET (NE + NN)          // edges + self loops
#define NG 64
#define SCAN_BLOCKS ((NN + 255) / 256)   // 196

// ---------------- K0: transpose W1 [512][64] -> Wt2 k-packed float4: Wt2f4[k4*64 + c] = W1[4k4..4k4+4][c]
__global__ void k_wt(const float* __restrict__ W1, float* __restrict__ Wt2) {
    int id = blockIdx.x * 256 + threadIdx.x;
    if (id >= 128 * 64) return;
    int k4 = id >> 6, c = id & 63;
    float4 v;
    v.x = W1[(k4 * 4 + 0) * 64 + c];
    v.y = W1[(k4 * 4 + 1) * 64 + c];
    v.z = W1[(k4 * 4 + 2) * 64 + c];
    v.w = W1[(k4 * 4 + 3) * 64 + c];
    reinterpret_cast<float4*>(Wt2)[id] = v;
}

// ---------------- K1: h1 partials = x @ W1 (split-K=2).
// Block: 64 rows (n0 = (bid>>1)*64), K-half = bid&1 (64 k4-groups = 256 k).
// Thread: tr=t>>4 -> rows {n0+tr+16i, i<4}; tc=t&15 -> cols {4tc..4tc+3}.
// A/B register double-buffer over k4 pairs keeps 16 loads in flight.
__global__ __launch_bounds__(256) void k_gemm1(
    const float* __restrict__ x, const float* __restrict__ Wt2,
    float* __restrict__ h1p) {
    int t = threadIdx.x;
    int tr = t >> 4, tc = t & 15;
    int half = blockIdx.x & 1;
    int n0 = (blockIdx.x >> 1) * 64;
    const float4* __restrict__ xf = reinterpret_cast<const float4*>(x);
    const float4* __restrict__ wf = reinterpret_cast<const float4*>(Wt2);

    const float4* __restrict__ xp[4];
    int rows[4];
#pragma unroll
    for (int i = 0; i < 4; ++i) {
        int r = n0 + tr + 16 * i;
        rows[i] = r;
        r = (r < NN) ? r : (NN - 1);
        xp[i] = xf + (size_t)r * 128;
    }

    float acc[4][4];
#pragma unroll
    for (int i = 0; i < 4; ++i)
#pragma unroll
        for (int j = 0; j < 4; ++j) acc[i][j] = 0.f;

    float4 wA0, wA1, wA2, wA3, xA0, xA1, xA2, xA3;
    float4 wB0, wB1, wB2, wB3, xB0, xB1, xB2, xB3;

#define LDA(kk) { const float4* wp = wf + (kk) * 64 + tc * 4; \
                  wA0 = wp[0]; wA1 = wp[1]; wA2 = wp[2]; wA3 = wp[3]; \
                  xA0 = xp[0][(kk)]; xA1 = xp[1][(kk)]; xA2 = xp[2][(kk)]; xA3 = xp[3][(kk)]; }
#define LDB(kk) { const float4* wp = wf + (kk) * 64 + tc * 4; \
                  wB0 = wp[0]; wB1 = wp[1]; wB2 = wp[2]; wB3 = wp[3]; \
                  xB0 = xp[0][(kk)]; xB1 = xp[1][(kk)]; xB2 = xp[2][(kk)]; xB3 = xp[3][(kk)]; }
#define FMA4(a, xv, wv) { a += xv.x * wv.x; a += xv.y * wv.y; a += xv.z * wv.z; a += xv.w * wv.w; }
#define FMAA() { FMA4(acc[0][0], xA0, wA0) FMA4(acc[0][1], xA0, wA1) FMA4(acc[0][2], xA0, wA2) FMA4(acc[0][3], xA0, wA3) \
                 FMA4(acc[1][0], xA1, wA0) FMA4(acc[1][1], xA1, wA1) FMA4(acc[1][2], xA1, wA2) FMA4(acc[1][3], xA1, wA3) \
                 FMA4(acc[2][0], xA2, wA0) FMA4(acc[2][1], xA2, wA1) FMA4(acc[2][2], xA2, wA2) FMA4(acc[2][3], xA2, wA3) \
                 FMA4(acc[3][0], xA3, wA0) FMA4(acc[3][1], xA3, wA1) FMA4(acc[3][2], xA3, wA2) FMA4(acc[3][3], xA3, wA3) }
#define FMAB() { FMA4(acc[0][0], xB0, wB0) FMA4(acc[0][1], xB0, wB1) FMA4(acc[0][2], xB0, wB2) FMA4(acc[0][3], xB0, wB3) \
                 FMA4(acc[1][0], xB1, wB0) FMA4(acc[1][1], xB1, wB1) FMA4(acc[1][2], xB1, wB2) FMA4(acc[1][3], xB1, wB3) \
                 FMA4(acc[2][0], xB2, wB0) FMA4(acc[2][1], xB2, wB1) FMA4(acc[2][2], xB2, wB2) FMA4(acc[2][3], xB2, wB3) \
                 FMA4(acc[3][0], xB3, wB0) FMA4(acc[3][1], xB3, wB1) FMA4(acc[3][2], xB3, wB2) FMA4(acc[3][3], xB3, wB3) }

    int kbase = half * 64;
    LDA(kbase);
    for (int p = 0; p < 64; p += 2) {
        LDB(kbase + p + 1);
        FMAA();
        if (p + 2 < 64) LDA(kbase + p + 2);
        FMAB();
    }
#undef LDA
#undef LDB
#undef FMA4
#undef FMAA
#undef FMAB

    float4* __restrict__ pf = reinterpret_cast<float4*>(h1p) + (size_t)half * NN * 16;
#pragma unroll
    for (int i = 0; i < 4; ++i) {
        int r = rows[i];
        if (r >= NN) continue;
        pf[r * 16 + tc] = make_float4(acc[i][0], acc[i][1], acc[i][2], acc[i][3]);
    }
}

// ---------------- K1b: combine split-K partials, store h1 + as1/ad1 epilogue.
// Thread id -> (r = id>>4, tc = id&15); lanes l and l^1 share row (tc even/odd pair).
__global__ __launch_bounds__(256) void k_comb(
    const float* __restrict__ h1p,
    const float* __restrict__ aS, const float* __restrict__ aD,
    float* __restrict__ h1, float* __restrict__ as1, float* __restrict__ ad1) {
    int id = blockIdx.x * 256 + threadIdx.x;   // grid sized exactly NN*16
    int r = id >> 4, tc = id & 15;
    const float4* p0 = reinterpret_cast<const float4*>(h1p);
    const float4* p1 = p0 + (size_t)NN * 16;
    float4 a = p0[id], b = p1[id];
    float4 v = make_float4(a.x + b.x, a.y + b.y, a.z + b.z, a.w + b.w);
    reinterpret_cast<float4*>(h1)[id] = v;
    int hh = tc >> 1, cb = (tc & 1) * 4;
    float ps = v.x * aS[hh * 8 + cb + 0] + v.y * aS[hh * 8 + cb + 1] +
               v.z * aS[hh * 8 + cb + 2] + v.w * aS[hh * 8 + cb + 3];
    float pd = v.x * aD[hh * 8 + cb + 0] + v.y * aD[hh * 8 + cb + 1] +
               v.z * aD[hh * 8 + cb + 2] + v.w * aD[hh * 8 + cb + 3];
    ps += __shfl_xor(ps, 1);
    pd += __shfl_xor(pd, 1);
    if ((tc & 1) == 0) { as1[r * 8 + hh] = ps; ad1[r * 8 + hh] = pd; }
}

// ---------------- CSR build
__global__ void k_hist(const int* __restrict__ edst, int* __restrict__ deg) {
    int e = blockIdx.x * 256 + threadIdx.x;
    if (e >= ET) return;
    int d = (e < NE) ? edst[e] : (e - NE);
    atomicAdd(&deg[d], 1);
}

__global__ __launch_bounds__(256) void k_scan1(const int* __restrict__ deg,
                                               int* __restrict__ offs, int* __restrict__ bsum) {
    __shared__ int lds_w[4];
    int i = blockIdx.x * 256 + threadIdx.x;
    int v = (i < NN) ? deg[i] : 0;
    int lane = threadIdx.x & 63, wid = threadIdx.x >> 6;
    int incl = v;
#pragma unroll
    for (int ofs = 1; ofs < 64; ofs <<= 1) {
        int o = __shfl_up(incl, ofs);
        if (lane >= ofs) incl += o;
    }
    if (lane == 63) lds_w[wid] = incl;
    __syncthreads();
    int wadd = 0;
    for (int w = 0; w < wid; ++w) wadd += lds_w[w];
    incl += wadd;
    if (i < NN) offs[i] = incl - v;
    if (threadIdx.x == 255) bsum[blockIdx.x] = incl;
}

__global__ void k_scan2(const int* __restrict__ bsum, int* __restrict__ bpre) {
    __shared__ int lds_w[4];
    int lane = threadIdx.x & 63, wid = threadIdx.x >> 6;
    int v = (threadIdx.x < SCAN_BLOCKS) ? bsum[threadIdx.x] : 0;
    int incl = v;
#pragma unroll
    for (int ofs = 1; ofs < 64; ofs <<= 1) {
        int o = __shfl_up(incl, ofs);
        if (lane >= ofs) incl += o;
    }
    if (lane == 63) lds_w[wid] = incl;
    __syncthreads();
    int wadd = 0;
    for (int w = 0; w < wid; ++w) wadd += lds_w[w];
    incl += wadd;
    bpre[threadIdx.x] = incl - v;
}

__global__ void k_scan3(int* __restrict__ offs, const int* __restrict__ bpre, int* __restrict__ cursor) {
    int i = blockIdx.x * 256 + threadIdx.x;
    if (i < NN) {
        int o = offs[i] + bpre[blockIdx.x];
        offs[i] = o;
        cursor[i] = o;
    }
    if (i == 0) offs[NN] = ET;
}

__global__ void k_scatter(const int* __restrict__ esrc, const int* __restrict__ edst,
                          int* __restrict__ cursor, int* __restrict__ csr) {
    int e = blockIdx.x * 256 + threadIdx.x;
    if (e >= ET) return;
    int s, d;
    if (e < NE) { s = esrc[e]; d = edst[e]; } else { s = d = e - NE; }
    int pos = atomicAdd(&cursor[d], 1);
    csr[pos] = s;
}

// ---------------- K4: layer-1 attention aggregation. One wave per dst; lane = (head<<3)|ch.
__global__ __launch_bounds__(256) void k_agg1(
    const int* __restrict__ offs, const int* __restrict__ csr,
    const float* __restrict__ h1, const float* __restrict__ as1, const float* __restrict__ ad1,
    const float* __restrict__ bias1, float* __restrict__ h1o) {
    int l = threadIdx.x & 63;
    int dst = blockIdx.x * 4 + (threadIdx.x >> 6);
    if (dst >= NN) return;
    int h = l >> 3;
    int beg = offs[dst], end = offs[dst + 1];
    float adh = ad1[dst * 8 + h];
    float acc = 0.f, dsum = 0.f;
#pragma clang loop unroll_count(2)
    for (int j = beg; j < end; ++j) {
        int s = csr[j];
        float e = as1[s * 8 + h] + adh;
        e = (e > 0.f) ? e : 0.2f * e;
        float w = __expf(e);
        acc += w * h1[s * 64 + l];
        dsum += w;
    }
    float v = acc / (dsum + 1e-16f) + bias1[l];
    v = (v > 0.f) ? v : (__expf(v) - 1.f);   // ELU
    h1o[dst * 64 + l] = v;
}

// ---------------- K6: h2 = h1o @ W2 (+ alpha2 reductions). 32 lanes per node.
__global__ __launch_bounds__(256) void k_gemm2(
    const float* __restrict__ h1o, const float* __restrict__ W2,
    const float* __restrict__ aS, const float* __restrict__ aD,
    float* __restrict__ h2, float* __restrict__ as2, float* __restrict__ ad2) {
    int c = threadIdx.x & 31;
    int n = blockIdx.x * 8 + (threadIdx.x >> 5);
    if (n >= NN) return;
    const float4* hf = reinterpret_cast<const float4*>(h1o + n * 64);
    float acc = 0.f;
#pragma unroll
    for (int k4 = 0; k4 < 16; ++k4) {
        float4 hv = hf[k4];
        acc += hv.x * W2[(k4 * 4 + 0) * 32 + c] + hv.y * W2[(k4 * 4 + 1) * 32 + c] +
               hv.z * W2[(k4 * 4 + 2) * 32 + c] + hv.w * W2[(k4 * 4 + 3) * 32 + c];
    }
    h2[n * 32 + c] = acc;
    float ps = acc * aS[c], pd = acc * aD[c];
#pragma unroll
    for (int o = 1; o < 32; o <<= 1) { ps += __shfl_xor(ps, o); pd += __shfl_xor(pd, o); }
    if (c == 0) { as2[n] = ps; ad2[n] = pd; }
}

// ---------------- K7: layer-2 aggregation. Half-wave (32 lanes) per dst.
__global__ __launch_bounds__(256) void k_agg2(
    const int* __restrict__ offs, const int* __restrict__ csr,
    const float* __restrict__ h2, const float* __restrict__ as2, const float* __restrict__ ad2,
    const float* __restrict__ bias2, float* __restrict__ o2) {
    int c = threadIdx.x & 31;
    int dst = blockIdx.x * 8 + (threadIdx.x >> 5);
    if (dst >= NN) return;
    int beg = offs[dst], end = offs[dst + 1];
    float adh = ad2[dst];
    float acc = 0.f, dsum = 0.f;
#pragma clang loop unroll_count(2)
    for (int j = beg; j < end; ++j) {
        int s = csr[j];
        float e = as2[s] + adh;
        e = (e > 0.f) ? e : 0.2f * e;
        float w = __expf(e);
        acc += w * h2[s * 32 + c];
        dsum += w;
    }
    o2[dst * 32 + c] = acc / (dsum + 1e-16f) + bias2[c];
}

// ---------------- K8: graph boundaries from sorted batch. lo[g] = first node with batch >= g.
__global__ void k_bound(const int* __restrict__ batch, int* __restrict__ lo) {
    int n = blockIdx.x * 256 + threadIdx.x;
    if (n >= NN) return;
    int b = batch[n];
    if (n == 0) {
        for (int g = 0; g <= b; ++g) lo[g] = 0;
    } else {
        int pb = batch[n - 1];
        for (int g = pb + 1; g <= b; ++g) lo[g] = n;
    }
    if (n == NN - 1) {
        for (int g = b + 1; g <= NG; ++g) lo[g] = NN;
    }
}

// ---------------- K9: pooled sums. 4 blocks per graph, partial-reduce in LDS, one atomic per (block, ch).
__global__ __launch_bounds__(256) void k_pool(const float* __restrict__ o2, const int* __restrict__ lo,
                                              float* __restrict__ pooled) {
    __shared__ float red[256];
    int g = blockIdx.x & 63, q = blockIdx.x >> 6;
    int beg = lo[g], end = lo[g + 1];
    int c = threadIdx.x & 31, row = threadIdx.x >> 5;
    float s = 0.f;
    for (int n = beg + q * 8 + row; n < end; n += 32) s += o2[n * 32 + c];
    red[threadIdx.x] = s;
    __syncthreads();
    for (int rr = 4; rr >= 1; rr >>= 1) {
        if (row < rr) red[threadIdx.x] += red[(row + rr) * 32 + c];
        __syncthreads();
    }
    if (row == 0) atomicAdd(&pooled[g * 32 + c], red[c]);
}

// ---------------- K10: mean + final linear -> out[64][2]
__global__ void k_fin(const float* __restrict__ pooled, const int* __restrict__ lo,
                      const float* __restrict__ lw, const float* __restrict__ lb,
                      float* __restrict__ out) {
    int t = threadIdx.x;
    if (t >= 128) return;
    int g = t >> 1, o = t & 1;
    int cnt = lo[g + 1] - lo[g];
    float inv = 1.f / fmaxf((float)cnt, 1.f);
    float s = 0.f;
#pragma unroll
    for (int c = 0; c < 32; ++c) s += pooled[g * 32 + c] * lw[c * 2 + o];
    out[g * 2 + o] = s * inv + lb[o];
}

// ----------------------------------------------------------------------------
extern "C" void kernel_launch(void* const* d_in, const int* in_sizes, int n_in,
                              void* d_out, int out_size, void* d_ws, size_t ws_size,
                              hipStream_t stream) {
    const float* x   = (const float*)d_in[0];
    const int*   ei  = (const int*)d_in[1];     // [2][NE]
    const int*   bat = (const int*)d_in[2];
    const float* W1  = (const float*)d_in[3];
    const float* aS1 = (const float*)d_in[4];
    const float* aD1 = (const float*)d_in[5];
    const float* b1  = (const float*)d_in[6];
    const float* W2  = (const float*)d_in[7];
    const float* aS2 = (const float*)d_in[8];
    const float* aD2 = (const float*)d_in[9];
    const float* b2  = (const float*)d_in[10];
    const float* lw  = (const float*)d_in[11];
    const float* lb  = (const float*)d_in[12];
    float* out = (float*)d_out;

    const int* esrc = ei;
    const int* edst = ei + NE;

    char* ws = (char*)d_ws;
    size_t off = 0;
    auto alloc = [&](size_t bytes) -> void* {
        off = (off + 255) & ~(size_t)255;
        void* p = ws + off;
        off += bytes;
        return p;
    };

    float* regA = (float*)alloc((size_t)NN * 64 * 4);   // h1; later reused: h2 @ 0, o2 @ NN*32
    float* h1   = regA;
    float* h2   = regA;                                  // alias (h1 dead after k_agg1)
    float* o2   = regA + (size_t)NN * 32;                // alias
    float* h1p  = (float*)alloc((size_t)2 * NN * 64 * 4);  // split-K partials
    float* h1o  = (float*)alloc((size_t)NN * 64 * 4);
    float* as1  = (float*)alloc((size_t)NN * 8 * 4);
    float* ad1  = (float*)alloc((size_t)NN * 8 * 4);
    float* as2  = (float*)alloc((size_t)NN * 4);
    float* ad2  = (float*)alloc((size_t)NN * 4);
    int*   offs = (int*)alloc((size_t)(NN + 1) * 4);
    int*   deg  = (int*)alloc((size_t)NN * 4);
    int*   cur  = (int*)alloc((size_t)NN * 4);
    int*   csr  = (int*)alloc((size_t)ET * 4);
    float* Wt2  = (float*)alloc((size_t)512 * 64 * 4);
    int*   bsum = (int*)alloc(256 * 4);
    int*   bpre = (int*)alloc(256 * 4);
    float* pooled = (float*)alloc((size_t)NG * 32 * 4);
    int*   lo   = (int*)alloc((size_t)(NG + 1) * 4);
    if (off > ws_size) return;   // workspace too small: leave d_out poisoned (visible failure)

    hipMemsetAsync(deg, 0, (size_t)NN * 4, stream);
    hipMemsetAsync(pooled, 0, (size_t)NG * 32 * 4, stream);

    k_wt<<<32, 256, 0, stream>>>(W1, Wt2);
    k_gemm1<<<2 * ((NN + 63) / 64), 256, 0, stream>>>(x, Wt2, h1p);
    k_comb<<<(NN * 16) / 256, 256, 0, stream>>>(h1p, aS1, aD1, h1, as1, ad1);

    int eblocks = (ET + 255) / 256;
    k_hist<<<eblocks, 256, 0, stream>>>(edst, deg);
    k_scan1<<<SCAN_BLOCKS, 256, 0, stream>>>(deg, offs, bsum);
    k_scan2<<<1, 256, 0, stream>>>(bsum, bpre);
    k_scan3<<<SCAN_BLOCKS, 256, 0, stream>>>(offs, bpre, cur);
    k_scatter<<<eblocks, 256, 0, stream>>>(esrc, edst, cur, csr);

    k_agg1<<<(NN + 3) / 4, 256, 0, stream>>>(offs, csr, h1, as1, ad1, b1, h1o);
    k_gemm2<<<(NN + 7) / 8, 256, 0, stream>>>(h1o, W2, aS2, aD2, h2, as2, ad2);
    k_agg2<<<(NN + 7) / 8, 256, 0, stream>>>(offs, csr, h2, as2, ad2, b2, o2);

    k_bound<<<SCAN_BLOCKS, 256, 0, stream>>>(bat, lo);
    k_pool<<<NG * 4, 256, 0, stream>>>(o2, lo, pooled);
    k_fin<<<1, 128, 0, stream>>>(pooled, lo, lw, lb, out);
}

// Round 6
// 511.371 us; speedup vs baseline: 1.2790x; 1.0974x over previous
//
#include <hip/hip_runtime.h>
#include <cstdint>
#include <cstddef>

#define NN 50000
#define NE 1600000
#define ET (NE + NN)          // edges + self loops
#define NG 64
#define SCAN_BLOCKS ((NN + 255) / 256)   // 196

// ---------------- K0: transpose W1 [512][64] -> Wt2 k-packed float4: Wt2f4[k4*64 + c] = W1[4k4..4k4+4][c]
__global__ void k_wt(const float* __restrict__ W1, float* __restrict__ Wt2) {
    int id = blockIdx.x * 256 + threadIdx.x;
    if (id >= 128 * 64) return;
    int k4 = id >> 6, c = id & 63;
    float4 v;
    v.x = W1[(k4 * 4 + 0) * 64 + c];
    v.y = W1[(k4 * 4 + 1) * 64 + c];
    v.z = W1[(k4 * 4 + 2) * 64 + c];
    v.w = W1[(k4 * 4 + 3) * 64 + c];
    reinterpret_cast<float4*>(Wt2)[id] = v;
}

// ---------------- K1: h1 partials = x @ W1 (split-K = SPLIT).
// Block: 64 rows (n0 = (bid/SPLIT)*64), K-part = bid%SPLIT (128/SPLIT k4-groups).
// Thread: tr=t>>4 -> rows {n0+tr+16i, i<4}; tc=t&15 -> cols {4tc..4tc+3}.
// A/B register double-buffer over k4 pairs keeps 16 loads in flight.
template<int SPLIT>
__global__ __launch_bounds__(256) void k_gemm1(
    const float* __restrict__ x, const float* __restrict__ Wt2,
    float* __restrict__ h1p) {
    int t = threadIdx.x;
    int tr = t >> 4, tc = t & 15;
    int part = blockIdx.x & (SPLIT - 1);
    int n0 = (blockIdx.x / SPLIT) * 64;
    const float4* __restrict__ xf = reinterpret_cast<const float4*>(x);
    const float4* __restrict__ wf = reinterpret_cast<const float4*>(Wt2);

    const float4* __restrict__ xp[4];
    int rows[4];
#pragma unroll
    for (int i = 0; i < 4; ++i) {
        int r = n0 + tr + 16 * i;
        rows[i] = r;
        r = (r < NN) ? r : (NN - 1);
        xp[i] = xf + (size_t)r * 128;
    }

    float acc[4][4];
#pragma unroll
    for (int i = 0; i < 4; ++i)
#pragma unroll
        for (int j = 0; j < 4; ++j) acc[i][j] = 0.f;

    float4 wA0, wA1, wA2, wA3, xA0, xA1, xA2, xA3;
    float4 wB0, wB1, wB2, wB3, xB0, xB1, xB2, xB3;

#define LDA(kk) { const float4* wp = wf + (kk) * 64 + tc * 4; \
                  wA0 = wp[0]; wA1 = wp[1]; wA2 = wp[2]; wA3 = wp[3]; \
                  xA0 = xp[0][(kk)]; xA1 = xp[1][(kk)]; xA2 = xp[2][(kk)]; xA3 = xp[3][(kk)]; }
#define LDB(kk) { const float4* wp = wf + (kk) * 64 + tc * 4; \
                  wB0 = wp[0]; wB1 = wp[1]; wB2 = wp[2]; wB3 = wp[3]; \
                  xB0 = xp[0][(kk)]; xB1 = xp[1][(kk)]; xB2 = xp[2][(kk)]; xB3 = xp[3][(kk)]; }
#define FMA4(a, xv, wv) { a += xv.x * wv.x; a += xv.y * wv.y; a += xv.z * wv.z; a += xv.w * wv.w; }
#define FMAA() { FMA4(acc[0][0], xA0, wA0) FMA4(acc[0][1], xA0, wA1) FMA4(acc[0][2], xA0, wA2) FMA4(acc[0][3], xA0, wA3) \
                 FMA4(acc[1][0], xA1, wA0) FMA4(acc[1][1], xA1, wA1) FMA4(acc[1][2], xA1, wA2) FMA4(acc[1][3], xA1, wA3) \
                 FMA4(acc[2][0], xA2, wA0) FMA4(acc[2][1], xA2, wA1) FMA4(acc[2][2], xA2, wA2) FMA4(acc[2][3], xA2, wA3) \
                 FMA4(acc[3][0], xA3, wA0) FMA4(acc[3][1], xA3, wA1) FMA4(acc[3][2], xA3, wA2) FMA4(acc[3][3], xA3, wA3) }
#define FMAB() { FMA4(acc[0][0], xB0, wB0) FMA4(acc[0][1], xB0, wB1) FMA4(acc[0][2], xB0, wB2) FMA4(acc[0][3], xB0, wB3) \
                 FMA4(acc[1][0], xB1, wB0) FMA4(acc[1][1], xB1, wB1) FMA4(acc[1][2], xB1, wB2) FMA4(acc[1][3], xB1, wB3) \
                 FMA4(acc[2][0], xB2, wB0) FMA4(acc[2][1], xB2, wB1) FMA4(acc[2][2], xB2, wB2) FMA4(acc[2][3], xB2, wB3) \
                 FMA4(acc[3][0], xB3, wB0) FMA4(acc[3][1], xB3, wB1) FMA4(acc[3][2], xB3, wB2) FMA4(acc[3][3], xB3, wB3) }

    const int K4 = 128 / SPLIT;
    int kbase = part * K4;
    LDA(kbase);
    for (int p = 0; p < K4; p += 2) {
        LDB(kbase + p + 1);
        FMAA();
        if (p + 2 < K4) LDA(kbase + p + 2);
        FMAB();
    }
#undef LDA
#undef LDB
#undef FMA4
#undef FMAA
#undef FMAB

    float4* __restrict__ pf = reinterpret_cast<float4*>(h1p) + (size_t)part * NN * 16;
#pragma unroll
    for (int i = 0; i < 4; ++i) {
        int r = rows[i];
        if (r >= NN) continue;
        pf[r * 16 + tc] = make_float4(acc[i][0], acc[i][1], acc[i][2], acc[i][3]);
    }
}

// ---------------- K1b: combine split-K partials, store h1 + as1/ad1 epilogue.
template<int SPLIT>
__global__ __launch_bounds__(256) void k_comb(
    const float* __restrict__ h1p,
    const float* __restrict__ aS, const float* __restrict__ aD,
    float* __restrict__ h1, float* __restrict__ as1, float* __restrict__ ad1) {
    int id = blockIdx.x * 256 + threadIdx.x;   // grid sized exactly NN*16
    int r = id >> 4, tc = id & 15;
    const float4* p = reinterpret_cast<const float4*>(h1p);
    float4 v = p[id];
#pragma unroll
    for (int q = 1; q < SPLIT; ++q) {
        float4 b = p[(size_t)q * NN * 16 + id];
        v.x += b.x; v.y += b.y; v.z += b.z; v.w += b.w;
    }
    reinterpret_cast<float4*>(h1)[id] = v;
    int hh = tc >> 1, cb = (tc & 1) * 4;
    float ps = v.x * aS[hh * 8 + cb + 0] + v.y * aS[hh * 8 + cb + 1] +
               v.z * aS[hh * 8 + cb + 2] + v.w * aS[hh * 8 + cb + 3];
    float pd = v.x * aD[hh * 8 + cb + 0] + v.y * aD[hh * 8 + cb + 1] +
               v.z * aD[hh * 8 + cb + 2] + v.w * aD[hh * 8 + cb + 3];
    ps += __shfl_xor(ps, 1);
    pd += __shfl_xor(pd, 1);
    if ((tc & 1) == 0) { as1[r * 8 + hh] = ps; ad1[r * 8 + hh] = pd; }
}

// ---------------- CSR build
__global__ void k_hist(const int* __restrict__ edst, int* __restrict__ deg) {
    int e = blockIdx.x * 256 + threadIdx.x;
    if (e >= ET) return;
    int d = (e < NE) ? edst[e] : (e - NE);
    atomicAdd(&deg[d], 1);
}

__global__ __launch_bounds__(256) void k_scan1(const int* __restrict__ deg,
                                               int* __restrict__ offs, int* __restrict__ bsum) {
    __shared__ int lds_w[4];
    int i = blockIdx.x * 256 + threadIdx.x;
    int v = (i < NN) ? deg[i] : 0;
    int lane = threadIdx.x & 63, wid = threadIdx.x >> 6;
    int incl = v;
#pragma unroll
    for (int ofs = 1; ofs < 64; ofs <<= 1) {
        int o = __shfl_up(incl, ofs);
        if (lane >= ofs) incl += o;
    }
    if (lane == 63) lds_w[wid] = incl;
    __syncthreads();
    int wadd = 0;
    for (int w = 0; w < wid; ++w) wadd += lds_w[w];
    incl += wadd;
    if (i < NN) offs[i] = incl - v;
    if (threadIdx.x == 255) bsum[blockIdx.x] = incl;
}

__global__ void k_scan2(const int* __restrict__ bsum, int* __restrict__ bpre) {
    __shared__ int lds_w[4];
    int lane = threadIdx.x & 63, wid = threadIdx.x >> 6;
    int v = (threadIdx.x < SCAN_BLOCKS) ? bsum[threadIdx.x] : 0;
    int incl = v;
#pragma unroll
    for (int ofs = 1; ofs < 64; ofs <<= 1) {
        int o = __shfl_up(incl, ofs);
        if (lane >= ofs) incl += o;
    }
    if (lane == 63) lds_w[wid] = incl;
    __syncthreads();
    int wadd = 0;
    for (int w = 0; w < wid; ++w) wadd += lds_w[w];
    incl += wadd;
    bpre[threadIdx.x] = incl - v;
}

__global__ void k_scan3(int* __restrict__ offs, const int* __restrict__ bpre, int* __restrict__ cursor) {
    int i = blockIdx.x * 256 + threadIdx.x;
    if (i < NN) {
        int o = offs[i] + bpre[blockIdx.x];
        offs[i] = o;
        cursor[i] = o;
    }
    if (i == 0) offs[NN] = ET;
}

__global__ void k_scatter(const int* __restrict__ esrc, const int* __restrict__ edst,
                          int* __restrict__ cursor, int* __restrict__ csr) {
    int e = blockIdx.x * 256 + threadIdx.x;
    if (e >= ET) return;
    int s, d;
    if (e < NE) { s = esrc[e]; d = edst[e]; } else { s = d = e - NE; }
    int pos = atomicAdd(&cursor[d], 1);
    csr[pos] = s;
}

// ---------------- K4: layer-1 attention aggregation. One wave per dst; lane = (head<<3)|ch.
// Chunked gather pipeline: csr for chunk n+1 issued before gathers of chunk n;
// 8 concurrent (as1,h1) gathers per wave. All array indices compile-time (registers).
__global__ __launch_bounds__(256) void k_agg1(
    const int* __restrict__ offs, const int* __restrict__ csr,
    const float* __restrict__ h1, const float* __restrict__ as1, const float* __restrict__ ad1,
    const float* __restrict__ bias1, float* __restrict__ h1o) {
    int l = threadIdx.x & 63;
    int dst = blockIdx.x * 4 + (threadIdx.x >> 6);
    if (dst >= NN) return;
    int h = l >> 3;
    int beg = offs[dst], end = offs[dst + 1];
    int lastj = end - 1;                 // deg >= 1 always (self-loop)
    float adh = ad1[dst * 8 + h];
    float acc = 0.f, dsum = 0.f;

    const int CH = 8;
    int sA[CH], sB[CH];
#pragma unroll
    for (int p = 0; p < CH; ++p) sA[p] = csr[min(beg + p, lastj)];
    for (int j = beg; j < end; j += CH) {
        int jn = j + CH;
#pragma unroll
        for (int p = 0; p < CH; ++p) sB[p] = csr[min(jn + p, lastj)];
        float av[CH], gv[CH];
#pragma unroll
        for (int p = 0; p < CH; ++p) {
            av[p] = as1[sA[p] * 8 + h];
            gv[p] = h1[sA[p] * 64 + l];
        }
#pragma unroll
        for (int p = 0; p < CH; ++p) {
            float e = av[p] + adh;
            e = (e > 0.f) ? e : 0.2f * e;
            float w = __expf(e);
            w = (j + p < end) ? w : 0.f;
            acc += w * gv[p];
            dsum += w;
        }
#pragma unroll
        for (int p = 0; p < CH; ++p) sA[p] = sB[p];
    }

    float v = acc / (dsum + 1e-16f) + bias1[l];
    v = (v > 0.f) ? v : (__expf(v) - 1.f);   // ELU
    h1o[dst * 64 + l] = v;
}

// ---------------- K6: h2 = h1o @ W2 (+ alpha2 reductions). 32 lanes per node.
__global__ __launch_bounds__(256) void k_gemm2(
    const float* __restrict__ h1o, const float* __restrict__ W2,
    const float* __restrict__ aS, const float* __restrict__ aD,
    float* __restrict__ h2, float* __restrict__ as2, float* __restrict__ ad2) {
    int c = threadIdx.x & 31;
    int n = blockIdx.x * 8 + (threadIdx.x >> 5);
    if (n >= NN) return;
    const float4* hf = reinterpret_cast<const float4*>(h1o + n * 64);
    float acc = 0.f;
#pragma unroll
    for (int k4 = 0; k4 < 16; ++k4) {
        float4 hv = hf[k4];
        acc += hv.x * W2[(k4 * 4 + 0) * 32 + c] + hv.y * W2[(k4 * 4 + 1) * 32 + c] +
               hv.z * W2[(k4 * 4 + 2) * 32 + c] + hv.w * W2[(k4 * 4 + 3) * 32 + c];
    }
    h2[n * 32 + c] = acc;
    float ps = acc * aS[c], pd = acc * aD[c];
#pragma unroll
    for (int o = 1; o < 32; o <<= 1) { ps += __shfl_xor(ps, o); pd += __shfl_xor(pd, o); }
    if (c == 0) { as2[n] = ps; ad2[n] = pd; }
}

// ---------------- K7: layer-2 aggregation. Half-wave (32 lanes) per dst, chunked pipeline.
__global__ __launch_bounds__(256) void k_agg2(
    const int* __restrict__ offs, const int* __restrict__ csr,
    const float* __restrict__ h2, const float* __restrict__ as2, const float* __restrict__ ad2,
    const float* __restrict__ bias2, float* __restrict__ o2) {
    int c = threadIdx.x & 31;
    int dst = blockIdx.x * 8 + (threadIdx.x >> 5);
    if (dst >= NN) return;
    int beg = offs[dst], end = offs[dst + 1];
    int lastj = end - 1;
    float adh = ad2[dst];
    float acc = 0.f, dsum = 0.f;

    const int CH = 8;
    int sA[CH], sB[CH];
#pragma unroll
    for (int p = 0; p < CH; ++p) sA[p] = csr[min(beg + p, lastj)];
    for (int j = beg; j < end; j += CH) {
        int jn = j + CH;
#pragma unroll
        for (int p = 0; p < CH; ++p) sB[p] = csr[min(jn + p, lastj)];
        float av[CH], gv[CH];
#pragma unroll
        for (int p = 0; p < CH; ++p) {
            av[p] = as2[sA[p]];
            gv[p] = h2[sA[p] * 32 + c];
        }
#pragma unroll
        for (int p = 0; p < CH; ++p) {
            float e = av[p] + adh;
            e = (e > 0.f) ? e : 0.2f * e;
            float w = __expf(e);
            w = (j + p < end) ? w : 0.f;
            acc += w * gv[p];
            dsum += w;
        }
#pragma unroll
        for (int p = 0; p < CH; ++p) sA[p] = sB[p];
    }
    o2[dst * 32 + c] = acc / (dsum + 1e-16f) + bias2[c];
}

// ---------------- K8: graph boundaries from sorted batch. lo[g] = first node with batch >= g.
__global__ void k_bound(const int* __restrict__ batch, int* __restrict__ lo) {
    int n = blockIdx.x * 256 + threadIdx.x;
    if (n >= NN) return;
    int b = batch[n];
    if (n == 0) {
        for (int g = 0; g <= b; ++g) lo[g] = 0;
    } else {
        int pb = batch[n - 1];
        for (int g = pb + 1; g <= b; ++g) lo[g] = n;
    }
    if (n == NN - 1) {
        for (int g = b + 1; g <= NG; ++g) lo[g] = NN;
    }
}

// ---------------- K9: pooled sums. 4 blocks per graph, partial-reduce in LDS, one atomic per (block, ch).
__global__ __launch_bounds__(256) void k_pool(const float* __restrict__ o2, const int* __restrict__ lo,
                                              float* __restrict__ pooled) {
    __shared__ float red[256];
    int g = blockIdx.x & 63, q = blockIdx.x >> 6;
    int beg = lo[g], end = lo[g + 1];
    int c = threadIdx.x & 31, row = threadIdx.x >> 5;
    float s = 0.f;
    for (int n = beg + q * 8 + row; n < end; n += 32) s += o2[n * 32 + c];
    red[threadIdx.x] = s;
    __syncthreads();
    for (int rr = 4; rr >= 1; rr >>= 1) {
        if (row < rr) red[threadIdx.x] += red[(row + rr) * 32 + c];
        __syncthreads();
    }
    if (row == 0) atomicAdd(&pooled[g * 32 + c], red[c]);
}

// ---------------- K10: mean + final linear -> out[64][2]
__global__ void k_fin(const float* __restrict__ pooled, const int* __restrict__ lo,
                      const float* __restrict__ lw, const float* __restrict__ lb,
                      float* __restrict__ out) {
    int t = threadIdx.x;
    if (t >= 128) return;
    int g = t >> 1, o = t & 1;
    int cnt = lo[g + 1] - lo[g];
    float inv = 1.f / fmaxf((float)cnt, 1.f);
    float s = 0.f;
#pragma unroll
    for (int c = 0; c < 32; ++c) s += pooled[g * 32 + c] * lw[c * 2 + o];
    out[g * 2 + o] = s * inv + lb[o];
}

// ----------------------------------------------------------------------------
extern "C" void kernel_launch(void* const* d_in, const int* in_sizes, int n_in,
                              void* d_out, int out_size, void* d_ws, size_t ws_size,
                              hipStream_t stream) {
    const float* x   = (const float*)d_in[0];
    const int*   ei  = (const int*)d_in[1];     // [2][NE]
    const int*   bat = (const int*)d_in[2];
    const float* W1  = (const float*)d_in[3];
    const float* aS1 = (const float*)d_in[4];
    const float* aD1 = (const float*)d_in[5];
    const float* b1  = (const float*)d_in[6];
    const float* W2  = (const float*)d_in[7];
    const float* aS2 = (const float*)d_in[8];
    const float* aD2 = (const float*)d_in[9];
    const float* b2  = (const float*)d_in[10];
    const float* lw  = (const float*)d_in[11];
    const float* lb  = (const float*)d_in[12];
    float* out = (float*)d_out;

    const int* esrc = ei;
    const int* edst = ei + NE;

    char* ws = (char*)d_ws;
    size_t off = 0;
    auto alloc = [&](size_t bytes) -> void* {
        off = (off + 255) & ~(size_t)255;
        void* p = ws + off;
        off += bytes;
        return p;
    };

    float *regA, *h1, *h2, *o2, *h1p, *h1o, *as1, *ad1, *as2, *ad2, *Wt2, *pooled;
    int *offs, *deg, *cur, *csr, *bsum, *bpre, *lo;

    int SPLIT = 4;
    for (int attempt = 0; attempt < 2; ++attempt) {
        off = 0;
        regA = (float*)alloc((size_t)NN * 64 * 4);   // h1; later reused: h2 @ 0, o2 @ NN*32
        h1   = regA;
        h2   = regA;                                  // alias (h1 dead after k_agg1)
        o2   = regA + (size_t)NN * 32;                // alias
        h1p  = (float*)alloc((size_t)SPLIT * NN * 64 * 4);  // split-K partials
        h1o  = (float*)alloc((size_t)NN * 64 * 4);
        as1  = (float*)alloc((size_t)NN * 8 * 4);
        ad1  = (float*)alloc((size_t)NN * 8 * 4);
        as2  = (float*)alloc((size_t)NN * 4);
        ad2  = (float*)alloc((size_t)NN * 4);
        offs = (int*)alloc((size_t)(NN + 1) * 4);
        deg  = (int*)alloc((size_t)NN * 4);
        cur  = (int*)alloc((size_t)NN * 4);
        csr  = (int*)alloc((size_t)ET * 4);
        Wt2  = (float*)alloc((size_t)512 * 64 * 4);
        bsum = (int*)alloc(256 * 4);
        bpre = (int*)alloc(256 * 4);
        pooled = (float*)alloc((size_t)NG * 32 * 4);
        lo   = (int*)alloc((size_t)(NG + 1) * 4);
        if (off <= ws_size) break;
        SPLIT = 2;                                   // shrink partials and retry
    }
    if (off > ws_size) return;   // workspace too small: leave d_out poisoned (visible failure)

    hipMemsetAsync(deg, 0, (size_t)NN * 4, stream);
    hipMemsetAsync(pooled, 0, (size_t)NG * 32 * 4, stream);

    k_wt<<<32, 256, 0, stream>>>(W1, Wt2);
    if (SPLIT == 4) {
        k_gemm1<4><<<4 * ((NN + 63) / 64), 256, 0, stream>>>(x, Wt2, h1p);
        k_comb<4><<<(NN * 16) / 256, 256, 0, stream>>>(h1p, aS1, aD1, h1, as1, ad1);
    } else {
        k_gemm1<2><<<2 * ((NN + 63) / 64), 256, 0, stream>>>(x, Wt2, h1p);
        k_comb<2><<<(NN * 16) / 256, 256, 0, stream>>>(h1p, aS1, aD1, h1, as1, ad1);
    }

    int eblocks = (ET + 255) / 256;
    k_hist<<<eblocks, 256, 0, stream>>>(edst, deg);
    k_scan1<<<SCAN_BLOCKS, 256, 0, stream>>>(deg, offs, bsum);
    k_scan2<<<1, 256, 0, stream>>>(bsum, bpre);
    k_scan3<<<SCAN_BLOCKS, 256, 0, stream>>>(offs, bpre, cur);
    k_scatter<<<eblocks, 256, 0, stream>>>(esrc, edst, cur, csr);

    k_agg1<<<(NN + 3) / 4, 256, 0, stream>>>(offs, csr, h1, as1, ad1, b1, h1o);
    k_gemm2<<<(NN + 7) / 8, 256, 0, stream>>>(h1o, W2, aS2, aD2, h2, as2, ad2);
    k_agg2<<<(NN + 7) / 8, 256, 0, stream>>>(offs, csr, h2, as2, ad2, b2, o2);

    k_bound<<<SCAN_BLOCKS, 256, 0, stream>>>(bat, lo);
    k_pool<<<NG * 4, 256, 0, stream>>>(o2, lo, pooled);
    k_fin<<<1, 128, 0, stream>>>(pooled, lo, lw, lb, out);
}

// Round 7
// 413.768 us; speedup vs baseline: 1.5807x; 1.2359x over previous
//
#include <hip/hip_runtime.h>
#include <cstdint>
#include <cstddef>

#define NN 50000
#define NE 1600000
#define ET (NE + NN)          // edges + self loops
#define NG 64
#define SCAN_BLOCKS ((NN + 255) / 256)   // 196

// ---------------- K0: transpose W1 [512][64] -> Wt2 k-packed float4: Wt2f4[k4*64 + c] = W1[4k4..4k4+4][c]
__global__ void k_wt(const float* __restrict__ W1, float* __restrict__ Wt2) {
    int id = blockIdx.x * 256 + threadIdx.x;
    if (id >= 128 * 64) return;
    int k4 = id >> 6, c = id & 63;
    float4 v;
    v.x = W1[(k4 * 4 + 0) * 64 + c];
    v.y = W1[(k4 * 4 + 1) * 64 + c];
    v.z = W1[(k4 * 4 + 2) * 64 + c];
    v.w = W1[(k4 * 4 + 3) * 64 + c];
    reinterpret_cast<float4*>(Wt2)[id] = v;
}

// ---------------- K1: h1 partials = x @ W1 (split-K = SPLIT), LDS-staged tile GEMM.
// Block: 64 rows, K-part of 128/SPLIT float4-k-groups. 256 thr.
// Stage x-tile + W-tile into LDS via global_load_lds(16B), then pure LDS->FMA loop.
// x LDS layout swizzled: slot = row*K4 + (k4 ^ ((row&3)<<1))  [source pre-swizzled, LDS dest linear]
// W LDS layout linear:   slot = k4*64 + c ; thread's cols = {tc, tc+16, tc+32, tc+48} (conflict-free reads)
template<int SPLIT>
__global__ __launch_bounds__(256, 8) void k_gemm1(
    const float* __restrict__ x, const float* __restrict__ Wt2,
    float* __restrict__ h1p) {
    constexpr int K4 = 128 / SPLIT;           // float4 k-groups per part (16 @ SPLIT=8)
    constexpr int LK4 = (SPLIT == 8) ? 4 : ((SPLIT == 4) ? 5 : 6);
    __shared__ float4 xs[64 * K4];
    __shared__ float4 wsr[K4 * 64];

    int t = threadIdx.x;
    int lane = t & 63, wv_id = t >> 6;
    int part = blockIdx.x & (SPLIT - 1);
    int n0 = (blockIdx.x / SPLIT) * 64;
    int kb4 = part * K4;

    const float4* __restrict__ xf = reinterpret_cast<const float4*>(x);
    const float4* __restrict__ wf = reinterpret_cast<const float4*>(Wt2);

    // ---- stage x: 64*K4 slots; wave-uniform LDS base, per-lane (pre-swizzled) global src
    constexpr int XPW = (64 * K4) / 64 / 4;   // issues per wave
#pragma unroll
    for (int q = 0; q < XPW; ++q) {
        int base = (wv_id * XPW + q) * 64;
        int s = base + lane;
        int row = s >> LK4;
        int m = s & (K4 - 1);
        int k4f = m ^ ((row & 3) << 1);       // involution
        int rr = n0 + row; if (rr >= NN) rr = NN - 1;
        const float4* src = xf + (size_t)rr * 128 + kb4 + k4f;
        __builtin_amdgcn_global_load_lds(
            (const __attribute__((address_space(1))) void*)src,
            (__attribute__((address_space(3))) void*)&xs[base], 16, 0, 0);
    }
    // ---- stage W: K4*64 slots, linear
    constexpr int WPW = (K4 * 64) / 64 / 4;
#pragma unroll
    for (int q = 0; q < WPW; ++q) {
        int base = (wv_id * WPW + q) * 64;
        int s = base + lane;
        int k4 = s >> 6, c = s & 63;
        const float4* src = wf + (size_t)(kb4 + k4) * 64 + c;
        __builtin_amdgcn_global_load_lds(
            (const __attribute__((address_space(1))) void*)src,
            (__attribute__((address_space(3))) void*)&wsr[base], 16, 0, 0);
    }
    __syncthreads();   // drains vmcnt before barrier (compiler-inserted)

    int tc = t & 15;
    int trg = t >> 4;                 // 0..15 across block; rows = trg + 16i
    int swz = (trg & 3) << 1;

    float acc[4][4];
#pragma unroll
    for (int i = 0; i < 4; ++i)
#pragma unroll
        for (int j = 0; j < 4; ++j) acc[i][j] = 0.f;

#pragma unroll 2
    for (int k4 = 0; k4 < K4; ++k4) {
        float4 wv0 = wsr[k4 * 64 + tc];
        float4 wv1 = wsr[k4 * 64 + tc + 16];
        float4 wv2 = wsr[k4 * 64 + tc + 32];
        float4 wv3 = wsr[k4 * 64 + tc + 48];
        int kx = k4 ^ swz;
        float4 xv0 = xs[(trg +  0) * K4 + kx];
        float4 xv1 = xs[(trg + 16) * K4 + kx];
        float4 xv2 = xs[(trg + 32) * K4 + kx];
        float4 xv3 = xs[(trg + 48) * K4 + kx];
#define FMA4(a, xv, wv) { a += xv.x * wv.x; a += xv.y * wv.y; a += xv.z * wv.z; a += xv.w * wv.w; }
        FMA4(acc[0][0], xv0, wv0) FMA4(acc[0][1], xv0, wv1) FMA4(acc[0][2], xv0, wv2) FMA4(acc[0][3], xv0, wv3)
        FMA4(acc[1][0], xv1, wv0) FMA4(acc[1][1], xv1, wv1) FMA4(acc[1][2], xv1, wv2) FMA4(acc[1][3], xv1, wv3)
        FMA4(acc[2][0], xv2, wv0) FMA4(acc[2][1], xv2, wv1) FMA4(acc[2][2], xv2, wv2) FMA4(acc[2][3], xv2, wv3)
        FMA4(acc[3][0], xv3, wv0) FMA4(acc[3][1], xv3, wv1) FMA4(acc[3][2], xv3, wv2) FMA4(acc[3][3], xv3, wv3)
#undef FMA4
    }

    // store partials: thread's cols are {tc + 16j}
    float* hp = h1p + (size_t)part * NN * 64;
#pragma unroll
    for (int i = 0; i < 4; ++i) {
        int r = n0 + trg + 16 * i;
        if (r >= NN) continue;
        float* rowp = hp + (size_t)r * 64 + tc;
        rowp[0]  = acc[i][0];
        rowp[16] = acc[i][1];
        rowp[32] = acc[i][2];
        rowp[48] = acc[i][3];
    }
}

// ---------------- K1b: combine split-K partials, store h1 + as1/ad1 epilogue.
template<int SPLIT>
__global__ __launch_bounds__(256) void k_comb(
    const float* __restrict__ h1p,
    const float* __restrict__ aS, const float* __restrict__ aD,
    float* __restrict__ h1, float* __restrict__ as1, float* __restrict__ ad1) {
    int id = blockIdx.x * 256 + threadIdx.x;   // grid sized exactly NN*16
    int r = id >> 4, tc = id & 15;
    const float4* p = reinterpret_cast<const float4*>(h1p);
    float4 v = p[id];
#pragma unroll
    for (int q = 1; q < SPLIT; ++q) {
        float4 b = p[(size_t)q * NN * 16 + id];
        v.x += b.x; v.y += b.y; v.z += b.z; v.w += b.w;
    }
    reinterpret_cast<float4*>(h1)[id] = v;
    int hh = tc >> 1, cb = (tc & 1) * 4;
    float ps = v.x * aS[hh * 8 + cb + 0] + v.y * aS[hh * 8 + cb + 1] +
               v.z * aS[hh * 8 + cb + 2] + v.w * aS[hh * 8 + cb + 3];
    float pd = v.x * aD[hh * 8 + cb + 0] + v.y * aD[hh * 8 + cb + 1] +
               v.z * aD[hh * 8 + cb + 2] + v.w * aD[hh * 8 + cb + 3];
    ps += __shfl_xor(ps, 1);
    pd += __shfl_xor(pd, 1);
    if ((tc & 1) == 0) { as1[r * 8 + hh] = ps; ad1[r * 8 + hh] = pd; }
}

// ---------------- CSR build
__global__ void k_hist(const int* __restrict__ edst, int* __restrict__ deg) {
    int e = blockIdx.x * 256 + threadIdx.x;
    if (e >= ET) return;
    int d = (e < NE) ? edst[e] : (e - NE);
    atomicAdd(&deg[d], 1);
}

__global__ __launch_bounds__(256) void k_scan1(const int* __restrict__ deg,
                                               int* __restrict__ offs, int* __restrict__ bsum) {
    __shared__ int lds_w[4];
    int i = blockIdx.x * 256 + threadIdx.x;
    int v = (i < NN) ? deg[i] : 0;
    int lane = threadIdx.x & 63, wid = threadIdx.x >> 6;
    int incl = v;
#pragma unroll
    for (int ofs = 1; ofs < 64; ofs <<= 1) {
        int o = __shfl_up(incl, ofs);
        if (lane >= ofs) incl += o;
    }
    if (lane == 63) lds_w[wid] = incl;
    __syncthreads();
    int wadd = 0;
    for (int w = 0; w < wid; ++w) wadd += lds_w[w];
    incl += wadd;
    if (i < NN) offs[i] = incl - v;
    if (threadIdx.x == 255) bsum[blockIdx.x] = incl;
}

__global__ void k_scan2(const int* __restrict__ bsum, int* __restrict__ bpre) {
    __shared__ int lds_w[4];
    int lane = threadIdx.x & 63, wid = threadIdx.x >> 6;
    int v = (threadIdx.x < SCAN_BLOCKS) ? bsum[threadIdx.x] : 0;
    int incl = v;
#pragma unroll
    for (int ofs = 1; ofs < 64; ofs <<= 1) {
        int o = __shfl_up(incl, ofs);
        if (lane >= ofs) incl += o;
    }
    if (lane == 63) lds_w[wid] = incl;
    __syncthreads();
    int wadd = 0;
    for (int w = 0; w < wid; ++w) wadd += lds_w[w];
    incl += wadd;
    bpre[threadIdx.x] = incl - v;
}

__global__ void k_scan3(int* __restrict__ offs, const int* __restrict__ bpre, int* __restrict__ cursor) {
    int i = blockIdx.x * 256 + threadIdx.x;
    if (i < NN) {
        int o = offs[i] + bpre[blockIdx.x];
        offs[i] = o;
        cursor[i] = o;
    }
    if (i == 0) offs[NN] = ET;
}

__global__ void k_scatter(const int* __restrict__ esrc, const int* __restrict__ edst,
                          int* __restrict__ cursor, int* __restrict__ csr) {
    int e = blockIdx.x * 256 + threadIdx.x;
    if (e >= ET) return;
    int s, d;
    if (e < NE) { s = esrc[e]; d = edst[e]; } else { s = d = e - NE; }
    int pos = atomicAdd(&cursor[d], 1);
    csr[pos] = s;
}

// ---------------- K4: layer-1 attention aggregation. One wave per dst; lane = (head<<3)|ch.
// Chunked gather pipeline: csr for chunk n+1 issued before gathers of chunk n.
__global__ __launch_bounds__(256) void k_agg1(
    const int* __restrict__ offs, const int* __restrict__ csr,
    const float* __restrict__ h1, const float* __restrict__ as1, const float* __restrict__ ad1,
    const float* __restrict__ bias1, float* __restrict__ h1o) {
    int l = threadIdx.x & 63;
    int dst = blockIdx.x * 4 + (threadIdx.x >> 6);
    if (dst >= NN) return;
    int h = l >> 3;
    int beg = offs[dst], end = offs[dst + 1];
    int lastj = end - 1;                 // deg >= 1 always (self-loop)
    float adh = ad1[dst * 8 + h];
    float acc = 0.f, dsum = 0.f;

    const int CH = 8;
    int sA[CH], sB[CH];
#pragma unroll
    for (int p = 0; p < CH; ++p) sA[p] = csr[min(beg + p, lastj)];
    for (int j = beg; j < end; j += CH) {
        int jn = j + CH;
#pragma unroll
        for (int p = 0; p < CH; ++p) sB[p] = csr[min(jn + p, lastj)];
        float av[CH], gv[CH];
#pragma unroll
        for (int p = 0; p < CH; ++p) {
            av[p] = as1[sA[p] * 8 + h];
            gv[p] = h1[sA[p] * 64 + l];
        }
#pragma unroll
        for (int p = 0; p < CH; ++p) {
            float e = av[p] + adh;
            e = (e > 0.f) ? e : 0.2f * e;
            float w = __expf(e);
            w = (j + p < end) ? w : 0.f;
            acc += w * gv[p];
            dsum += w;
        }
#pragma unroll
        for (int p = 0; p < CH; ++p) sA[p] = sB[p];
    }

    float v = acc / (dsum + 1e-16f) + bias1[l];
    v = (v > 0.f) ? v : (__expf(v) - 1.f);   // ELU
    h1o[dst * 64 + l] = v;
}

// ---------------- K6: h2 = h1o @ W2 (+ alpha2 reductions). 32 lanes per node.
__global__ __launch_bounds__(256) void k_gemm2(
    const float* __restrict__ h1o, const float* __restrict__ W2,
    const float* __restrict__ aS, const float* __restrict__ aD,
    float* __restrict__ h2, float* __restrict__ as2, float* __restrict__ ad2) {
    int c = threadIdx.x & 31;
    int n = blockIdx.x * 8 + (threadIdx.x >> 5);
    if (n >= NN) return;
    const float4* hf = reinterpret_cast<const float4*>(h1o + n * 64);
    float acc = 0.f;
#pragma unroll
    for (int k4 = 0; k4 < 16; ++k4) {
        float4 hv = hf[k4];
        acc += hv.x * W2[(k4 * 4 + 0) * 32 + c] + hv.y * W2[(k4 * 4 + 1) * 32 + c] +
               hv.z * W2[(k4 * 4 + 2) * 32 + c] + hv.w * W2[(k4 * 4 + 3) * 32 + c];
    }
    h2[n * 32 + c] = acc;
    float ps = acc * aS[c], pd = acc * aD[c];
#pragma unroll
    for (int o = 1; o < 32; o <<= 1) { ps += __shfl_xor(ps, o); pd += __shfl_xor(pd, o); }
    if (c == 0) { as2[n] = ps; ad2[n] = pd; }
}

// ---------------- K7: layer-2 aggregation. Half-wave (32 lanes) per dst, chunked pipeline.
__global__ __launch_bounds__(256) void k_agg2(
    const int* __restrict__ offs, const int* __restrict__ csr,
    const float* __restrict__ h2, const float* __restrict__ as2, const float* __restrict__ ad2,
    const float* __restrict__ bias2, float* __restrict__ o2) {
    int c = threadIdx.x & 31;
    int dst = blockIdx.x * 8 + (threadIdx.x >> 5);
    if (dst >= NN) return;
    int beg = offs[dst], end = offs[dst + 1];
    int lastj = end - 1;
    float adh = ad2[dst];
    float acc = 0.f, dsum = 0.f;

    const int CH = 8;
    int sA[CH], sB[CH];
#pragma unroll
    for (int p = 0; p < CH; ++p) sA[p] = csr[min(beg + p, lastj)];
    for (int j = beg; j < end; j += CH) {
        int jn = j + CH;
#pragma unroll
        for (int p = 0; p < CH; ++p) sB[p] = csr[min(jn + p, lastj)];
        float av[CH], gv[CH];
#pragma unroll
        for (int p = 0; p < CH; ++p) {
            av[p] = as2[sA[p]];
            gv[p] = h2[sA[p] * 32 + c];
        }
#pragma unroll
        for (int p = 0; p < CH; ++p) {
            float e = av[p] + adh;
            e = (e > 0.f) ? e : 0.2f * e;
            float w = __expf(e);
            w = (j + p < end) ? w : 0.f;
            acc += w * gv[p];
            dsum += w;
        }
#pragma unroll
        for (int p = 0; p < CH; ++p) sA[p] = sB[p];
    }
    o2[dst * 32 + c] = acc / (dsum + 1e-16f) + bias2[c];
}

// ---------------- K8: graph boundaries from sorted batch. lo[g] = first node with batch >= g.
__global__ void k_bound(const int* __restrict__ batch, int* __restrict__ lo) {
    int n = blockIdx.x * 256 + threadIdx.x;
    if (n >= NN) return;
    int b = batch[n];
    if (n == 0) {
        for (int g = 0; g <= b; ++g) lo[g] = 0;
    } else {
        int pb = batch[n - 1];
        for (int g = pb + 1; g <= b; ++g) lo[g] = n;
    }
    if (n == NN - 1) {
        for (int g = b + 1; g <= NG; ++g) lo[g] = NN;
    }
}

// ---------------- K9: pooled sums. 4 blocks per graph, partial-reduce in LDS, one atomic per (block, ch).
__global__ __launch_bounds__(256) void k_pool(const float* __restrict__ o2, const int* __restrict__ lo,
                                              float* __restrict__ pooled) {
    __shared__ float red[256];
    int g = blockIdx.x & 63, q = blockIdx.x >> 6;
    int beg = lo[g], end = lo[g + 1];
    int c = threadIdx.x & 31, row = threadIdx.x >> 5;
    float s = 0.f;
    for (int n = beg + q * 8 + row; n < end; n += 32) s += o2[n * 32 + c];
    red[threadIdx.x] = s;
    __syncthreads();
    for (int rr = 4; rr >= 1; rr >>= 1) {
        if (row < rr) red[threadIdx.x] += red[(row + rr) * 32 + c];
        __syncthreads();
    }
    if (row == 0) atomicAdd(&pooled[g * 32 + c], red[c]);
}

// ---------------- K10: mean + final linear -> out[64][2]
__global__ void k_fin(const float* __restrict__ pooled, const int* __restrict__ lo,
                      const float* __restrict__ lw, const float* __restrict__ lb,
                      float* __restrict__ out) {
    int t = threadIdx.x;
    if (t >= 128) return;
    int g = t >> 1, o = t & 1;
    int cnt = lo[g + 1] - lo[g];
    float inv = 1.f / fmaxf((float)cnt, 1.f);
    float s = 0.f;
#pragma unroll
    for (int c = 0; c < 32; ++c) s += pooled[g * 32 + c] * lw[c * 2 + o];
    out[g * 2 + o] = s * inv + lb[o];
}

// ----------------------------------------------------------------------------
extern "C" void kernel_launch(void* const* d_in, const int* in_sizes, int n_in,
                              void* d_out, int out_size, void* d_ws, size_t ws_size,
                              hipStream_t stream) {
    const float* x   = (const float*)d_in[0];
    const int*   ei  = (const int*)d_in[1];     // [2][NE]
    const int*   bat = (const int*)d_in[2];
    const float* W1  = (const float*)d_in[3];
    const float* aS1 = (const float*)d_in[4];
    const float* aD1 = (const float*)d_in[5];
    const float* b1  = (const float*)d_in[6];
    const float* W2  = (const float*)d_in[7];
    const float* aS2 = (const float*)d_in[8];
    const float* aD2 = (const float*)d_in[9];
    const float* b2  = (const float*)d_in[10];
    const float* lw  = (const float*)d_in[11];
    const float* lb  = (const float*)d_in[12];
    float* out = (float*)d_out;

    const int* esrc = ei;
    const int* edst = ei + NE;

    char* ws = (char*)d_ws;
    size_t off = 0;
    auto alloc = [&](size_t bytes) -> void* {
        off = (off + 255) & ~(size_t)255;
        void* p = ws + off;
        off += bytes;
        return p;
    };

    float *regA, *h1, *h2, *o2, *h1p, *h1o, *as1, *ad1, *as2, *ad2, *Wt2, *pooled;
    int *offs, *deg, *cur, *csr, *bsum, *bpre, *lo;

    int SPLIT = 8;
    for (int attempt = 0; attempt < 2; ++attempt) {
        off = 0;
        regA = (float*)alloc((size_t)NN * 64 * 4);   // h1; later reused: h2 @ 0, o2 @ NN*32
        h1   = regA;
        h2   = regA;                                  // alias (h1 dead after k_agg1)
        o2   = regA + (size_t)NN * 32;                // alias
        h1p  = (float*)alloc((size_t)SPLIT * NN * 64 * 4);  // split-K partials
        h1o  = (float*)alloc((size_t)NN * 64 * 4);
        as1  = (float*)alloc((size_t)NN * 8 * 4);
        ad1  = (float*)alloc((size_t)NN * 8 * 4);
        as2  = (float*)alloc((size_t)NN * 4);
        ad2  = (float*)alloc((size_t)NN * 4);
        offs = (int*)alloc((size_t)(NN + 1) * 4);
        deg  = (int*)alloc((size_t)NN * 4);
        cur  = (int*)alloc((size_t)NN * 4);
        csr  = (int*)alloc((size_t)ET * 4);
        Wt2  = (float*)alloc((size_t)512 * 64 * 4);
        bsum = (int*)alloc(256 * 4);
        bpre = (int*)alloc(256 * 4);
        pooled = (float*)alloc((size_t)NG * 32 * 4);
        lo   = (int*)alloc((size_t)(NG + 1) * 4);
        if (off <= ws_size) break;
        SPLIT = 4;                                   // shrink partials and retry
    }
    if (off > ws_size) return;   // workspace too small: leave d_out poisoned (visible failure)

    hipMemsetAsync(deg, 0, (size_t)NN * 4, stream);
    hipMemsetAsync(pooled, 0, (size_t)NG * 32 * 4, stream);

    k_wt<<<32, 256, 0, stream>>>(W1, Wt2);
    if (SPLIT == 8) {
        k_gemm1<8><<<8 * ((NN + 63) / 64), 256, 0, stream>>>(x, Wt2, h1p);
        k_comb<8><<<(NN * 16) / 256, 256, 0, stream>>>(h1p, aS1, aD1, h1, as1, ad1);
    } else {
        k_gemm1<4><<<4 * ((NN + 63) / 64), 256, 0, stream>>>(x, Wt2, h1p);
        k_comb<4><<<(NN * 16) / 256, 256, 0, stream>>>(h1p, aS1, aD1, h1, as1, ad1);
    }

    int eblocks = (ET + 255) / 256;
    k_hist<<<eblocks, 256, 0, stream>>>(edst, deg);
    k_scan1<<<SCAN_BLOCKS, 256, 0, stream>>>(deg, offs, bsum);
    k_scan2<<<1, 256, 0, stream>>>(bsum, bpre);
    k_scan3<<<SCAN_BLOCKS, 256, 0, stream>>>(offs, bpre, cur);
    k_scatter<<<eblocks, 256, 0, stream>>>(esrc, edst, cur, csr);

    k_agg1<<<(NN + 3) / 4, 256, 0, stream>>>(offs, csr, h1, as1, ad1, b1, h1o);
    k_gemm2<<<(NN + 7) / 8, 256, 0, stream>>>(h1o, W2, aS2, aD2, h2, as2, ad2);
    k_agg2<<<(NN + 7) / 8, 256, 0, stream>>>(offs, csr, h2, as2, ad2, b2, o2);

    k_bound<<<SCAN_BLOCKS, 256, 0, stream>>>(bat, lo);
    k_pool<<<NG * 4, 256, 0, stream>>>(o2, lo, pooled);
    k_fin<<<1, 128, 0, stream>>>(pooled, lo, lw, lb, out);
}

// Round 9
// 368.914 us; speedup vs baseline: 1.7729x; 1.1216x over previous
//
#include <hip/hip_runtime.h>
#include <cstdint>
#include <cstddef>

#define NN 50000
#define NE 1600000
#define ET (NE + NN)          // edges + self loops
#define NG 64
#define SCAN_BLOCKS ((NN + 255) / 256)   // 196
#define NB ((NN + 127) >> 7)             // 391 dst-buckets, 128 nodes each
#define EPT 16
#define EPB (256 * EPT)                  // 4096 edges per bin-block
#define BIN_BLOCKS ((ET + EPB - 1) / EPB)

// ---------------- K0: transpose W1 [512][64] -> Wt2 k-packed float4
__global__ void k_wt(const float* __restrict__ W1, float* __restrict__ Wt2) {
    int id = blockIdx.x * 256 + threadIdx.x;
    if (id >= 128 * 64) return;
    int k4 = id >> 6, c = id & 63;
    float4 v;
    v.x = W1[(k4 * 4 + 0) * 64 + c];
    v.y = W1[(k4 * 4 + 1) * 64 + c];
    v.z = W1[(k4 * 4 + 2) * 64 + c];
    v.w = W1[(k4 * 4 + 3) * 64 + c];
    reinterpret_cast<float4*>(Wt2)[id] = v;
}

// ---------------- K1: h1 partials = x @ W1 (split-K = SPLIT), LDS-staged tile GEMM.
template<int SPLIT>
__global__ __launch_bounds__(256, 8) void k_gemm1(
    const float* __restrict__ x, const float* __restrict__ Wt2,
    float* __restrict__ h1p) {
    constexpr int K4 = 128 / SPLIT;
    constexpr int LK4 = (SPLIT == 8) ? 4 : ((SPLIT == 4) ? 5 : 6);
    __shared__ float4 xs[64 * K4];
    __shared__ float4 wsr[K4 * 64];

    int t = threadIdx.x;
    int lane = t & 63, wv_id = t >> 6;
    int part = blockIdx.x & (SPLIT - 1);
    int n0 = (blockIdx.x / SPLIT) * 64;
    int kb4 = part * K4;

    const float4* __restrict__ xf = reinterpret_cast<const float4*>(x);
    const float4* __restrict__ wf = reinterpret_cast<const float4*>(Wt2);

    constexpr int XPW = (64 * K4) / 64 / 4;
#pragma unroll
    for (int q = 0; q < XPW; ++q) {
        int base = (wv_id * XPW + q) * 64;
        int s = base + lane;
        int row = s >> LK4;
        int m = s & (K4 - 1);
        int k4f = m ^ ((row & 3) << 1);
        int rr = n0 + row; if (rr >= NN) rr = NN - 1;
        const float4* src = xf + (size_t)rr * 128 + kb4 + k4f;
        __builtin_amdgcn_global_load_lds(
            (const __attribute__((address_space(1))) void*)src,
            (__attribute__((address_space(3))) void*)&xs[base], 16, 0, 0);
    }
    constexpr int WPW = (K4 * 64) / 64 / 4;
#pragma unroll
    for (int q = 0; q < WPW; ++q) {
        int base = (wv_id * WPW + q) * 64;
        int s = base + lane;
        int k4 = s >> 6, c = s & 63;
        const float4* src = wf + (size_t)(kb4 + k4) * 64 + c;
        __builtin_amdgcn_global_load_lds(
            (const __attribute__((address_space(1))) void*)src,
            (__attribute__((address_space(3))) void*)&wsr[base], 16, 0, 0);
    }
    __syncthreads();

    int tc = t & 15;
    int trg = t >> 4;
    int swz = (trg & 3) << 1;

    float acc[4][4];
#pragma unroll
    for (int i = 0; i < 4; ++i)
#pragma unroll
        for (int j = 0; j < 4; ++j) acc[i][j] = 0.f;

#pragma unroll 2
    for (int k4 = 0; k4 < K4; ++k4) {
        float4 wv0 = wsr[k4 * 64 + tc];
        float4 wv1 = wsr[k4 * 64 + tc + 16];
        float4 wv2 = wsr[k4 * 64 + tc + 32];
        float4 wv3 = wsr[k4 * 64 + tc + 48];
        int kx = k4 ^ swz;
        float4 xv0 = xs[(trg +  0) * K4 + kx];
        float4 xv1 = xs[(trg + 16) * K4 + kx];
        float4 xv2 = xs[(trg + 32) * K4 + kx];
        float4 xv3 = xs[(trg + 48) * K4 + kx];
#define FMA4(a, xv, wv) { a += xv.x * wv.x; a += xv.y * wv.y; a += xv.z * wv.z; a += xv.w * wv.w; }
        FMA4(acc[0][0], xv0, wv0) FMA4(acc[0][1], xv0, wv1) FMA4(acc[0][2], xv0, wv2) FMA4(acc[0][3], xv0, wv3)
        FMA4(acc[1][0], xv1, wv0) FMA4(acc[1][1], xv1, wv1) FMA4(acc[1][2], xv1, wv2) FMA4(acc[1][3], xv1, wv3)
        FMA4(acc[2][0], xv2, wv0) FMA4(acc[2][1], xv2, wv1) FMA4(acc[2][2], xv2, wv2) FMA4(acc[2][3], xv2, wv3)
        FMA4(acc[3][0], xv3, wv0) FMA4(acc[3][1], xv3, wv1) FMA4(acc[3][2], xv3, wv2) FMA4(acc[3][3], xv3, wv3)
#undef FMA4
    }

    float* hp = h1p + (size_t)part * NN * 64;
#pragma unroll
    for (int i = 0; i < 4; ++i) {
        int r = n0 + trg + 16 * i;
        if (r >= NN) continue;
        float* rowp = hp + (size_t)r * 64 + tc;
        rowp[0]  = acc[i][0];
        rowp[16] = acc[i][1];
        rowp[32] = acc[i][2];
        rowp[48] = acc[i][3];
    }
}

// ---------------- K1b: combine split-K partials, store h1 + as1/ad1 epilogue.
template<int SPLIT>
__global__ __launch_bounds__(256) void k_comb(
    const float* __restrict__ h1p,
    const float* __restrict__ aS, const float* __restrict__ aD,
    float* __restrict__ h1, float* __restrict__ as1, float* __restrict__ ad1) {
    int id = blockIdx.x * 256 + threadIdx.x;   // grid sized exactly NN*16
    int r = id >> 4, tc = id & 15;
    const float4* p = reinterpret_cast<const float4*>(h1p);
    float4 v = p[id];
#pragma unroll
    for (int q = 1; q < SPLIT; ++q) {
        float4 b = p[(size_t)q * NN * 16 + id];
        v.x += b.x; v.y += b.y; v.z += b.z; v.w += b.w;
    }
    reinterpret_cast<float4*>(h1)[id] = v;
    int hh = tc >> 1, cb = (tc & 1) * 4;
    float ps = v.x * aS[hh * 8 + cb + 0] + v.y * aS[hh * 8 + cb + 1] +
               v.z * aS[hh * 8 + cb + 2] + v.w * aS[hh * 8 + cb + 3];
    float pd = v.x * aD[hh * 8 + cb + 0] + v.y * aD[hh * 8 + cb + 1] +
               v.z * aD[hh * 8 + cb + 2] + v.w * aD[hh * 8 + cb + 3];
    ps += __shfl_xor(ps, 1);
    pd += __shfl_xor(pd, 1);
    if ((tc & 1) == 0) { as1[r * 8 + hh] = ps; ad1[r * 8 + hh] = pd; }
}

// ---------------- CSR build: hist -> scan -> bin -> unbin
__global__ void k_hist(const int* __restrict__ edst, int* __restrict__ deg) {
    int e = blockIdx.x * 256 + threadIdx.x;
    if (e >= ET) return;
    int d = (e < NE) ? edst[e] : (e - NE);
    atomicAdd(&deg[d], 1);
}

__global__ __launch_bounds__(256) void k_scan1(const int* __restrict__ deg,
                                               int* __restrict__ offs, int* __restrict__ bsum) {
    __shared__ int lds_w[4];
    int i = blockIdx.x * 256 + threadIdx.x;
    int v = (i < NN) ? deg[i] : 0;
    int lane = threadIdx.x & 63, wid = threadIdx.x >> 6;
    int incl = v;
#pragma unroll
    for (int ofs = 1; ofs < 64; ofs <<= 1) {
        int o = __shfl_up(incl, ofs);
        if (lane >= ofs) incl += o;
    }
    if (lane == 63) lds_w[wid] = incl;
    __syncthreads();
    int wadd = 0;
    for (int w = 0; w < wid; ++w) wadd += lds_w[w];
    incl += wadd;
    if (i < NN) offs[i] = incl - v;
    if (threadIdx.x == 255) bsum[blockIdx.x] = incl;
}

__global__ void k_scan2(const int* __restrict__ bsum, int* __restrict__ bpre) {
    __shared__ int lds_w[4];
    int lane = threadIdx.x & 63, wid = threadIdx.x >> 6;
    int v = (threadIdx.x < SCAN_BLOCKS) ? bsum[threadIdx.x] : 0;
    int incl = v;
#pragma unroll
    for (int ofs = 1; ofs < 64; ofs <<= 1) {
        int o = __shfl_up(incl, ofs);
        if (lane >= ofs) incl += o;
    }
    if (lane == 63) lds_w[wid] = incl;
    __syncthreads();
    int wadd = 0;
    for (int w = 0; w < wid; ++w) wadd += lds_w[w];
    incl += wadd;
    bpre[threadIdx.x] = incl - v;
}

__global__ void k_scan3(int* __restrict__ offs, const int* __restrict__ bpre, int* __restrict__ cursor) {
    int i = blockIdx.x * 256 + threadIdx.x;
    if (i < NN) {
        int o = offs[i] + bpre[blockIdx.x];
        offs[i] = o;
        cursor[i] = o;
    }
    if (i == 0) offs[NN] = ET;
}

__global__ __launch_bounds__(256) void k_binit(const int* __restrict__ offs, int* __restrict__ bcur) {
    int b = blockIdx.x * 256 + threadIdx.x;
    if (b < NB) bcur[b] = offs[b << 7];
}

// bin: block-aggregated bucket scatter of (src,dst) records into dst-bucket streams.
__global__ __launch_bounds__(256) void k_bin(
    const int* __restrict__ esrc, const int* __restrict__ edst,
    int* __restrict__ bcur, uint2* __restrict__ rec) {
    __shared__ int bcnt[NB];
    int tid = threadIdx.x;
    for (int b = tid; b < NB; b += 256) bcnt[b] = 0;
    __syncthreads();
    int e0 = blockIdx.x * EPB;
    uint2 rv[EPT]; int rk[EPT];
#pragma unroll
    for (int q = 0; q < EPT; ++q) {
        int e = e0 + q * 256 + tid;
        rk[q] = -1;
        if (e < ET) {
            int s, d;
            if (e < NE) { s = esrc[e]; d = edst[e]; } else { s = d = e - NE; }
            rv[q] = make_uint2((unsigned)s, (unsigned)d);
            rk[q] = atomicAdd(&bcnt[d >> 7], 1);
        }
    }
    __syncthreads();
    for (int b = tid; b < NB; b += 256)
        bcnt[b] = atomicAdd(&bcur[b], bcnt[b]);
    __syncthreads();
#pragma unroll
    for (int q = 0; q < EPT; ++q) {
        if (rk[q] >= 0) rec[bcnt[rv[q].y >> 7] + rk[q]] = rv[q];
    }
}

// unbin: one block per bucket; all csr writes land in the bucket's ~17KB region (one XCD).
__global__ __launch_bounds__(512) void k_unbin(
    const int* __restrict__ offs, const uint2* __restrict__ rec,
    int* __restrict__ cur, int* __restrict__ csr) {
    int b = blockIdx.x;
    int lo = offs[b << 7];
    int ne = (b + 1) << 7;
    int hi = offs[(ne < NN) ? ne : NN];
    for (int i = lo + threadIdx.x; i < hi; i += 512) {
        uint2 r = rec[i];
        int pos = atomicAdd(&cur[r.y], 1);
        csr[pos] = (int)r.x;
    }
}

// ---------------- K4: layer-1 attention aggregation. One wave per dst; lane = (head<<3)|ch.
__global__ __launch_bounds__(256) void k_agg1(
    const int* __restrict__ offs, const int* __restrict__ csr,
    const float* __restrict__ h1, const float* __restrict__ as1, const float* __restrict__ ad1,
    const float* __restrict__ bias1, float* __restrict__ h1o) {
    int l = threadIdx.x & 63;
    int dst = blockIdx.x * 4 + (threadIdx.x >> 6);
    if (dst >= NN) return;
    int h = l >> 3;
    int beg = offs[dst], end = offs[dst + 1];
    int lastj = end - 1;                 // deg >= 1 always (self-loop)
    float adh = ad1[dst * 8 + h];
    float acc = 0.f, dsum = 0.f;

    const int CH = 8;
    int sA[CH], sB[CH];
#pragma unroll
    for (int p = 0; p < CH; ++p) sA[p] = csr[min(beg + p, lastj)];
    for (int j = beg; j < end; j += CH) {
        int jn = j + CH;
#pragma unroll
        for (int p = 0; p < CH; ++p) sB[p] = csr[min(jn + p, lastj)];
        float av[CH], gv[CH];
#pragma unroll
        for (int p = 0; p < CH; ++p) {
            av[p] = as1[sA[p] * 8 + h];
            gv[p] = h1[sA[p] * 64 + l];
        }
#pragma unroll
        for (int p = 0; p < CH; ++p) {
            float e = av[p] + adh;
            e = (e > 0.f) ? e : 0.2f * e;
            float w = __expf(e);
            w = (j + p < end) ? w : 0.f;
            acc += w * gv[p];
            dsum += w;
        }
#pragma unroll
        for (int p = 0; p < CH; ++p) sA[p] = sB[p];
    }

    float v = acc / (dsum + 1e-16f) + bias1[l];
    v = (v > 0.f) ? v : (__expf(v) - 1.f);   // ELU
    h1o[dst * 64 + l] = v;
}

// ---------------- K6: h2 = h1o @ W2 (+ alpha2 reductions). 32 lanes per node.
__global__ __launch_bounds__(256) void k_gemm2(
    const float* __restrict__ h1o, const float* __restrict__ W2,
    const float* __restrict__ aS, const float* __restrict__ aD,
    float* __restrict__ h2, float* __restrict__ as2, float* __restrict__ ad2) {
    int c = threadIdx.x & 31;
    int n = blockIdx.x * 8 + (threadIdx.x >> 5);
    if (n >= NN) return;
    const float4* hf = reinterpret_cast<const float4*>(h1o + n * 64);
    float acc = 0.f;
#pragma unroll
    for (int k4 = 0; k4 < 16; ++k4) {
        float4 hv = hf[k4];
        acc += hv.x * W2[(k4 * 4 + 0) * 32 + c] + hv.y * W2[(k4 * 4 + 1) * 32 + c] +
               hv.z * W2[(k4 * 4 + 2) * 32 + c] + hv.w * W2[(k4 * 4 + 3) * 32 + c];
    }
    h2[n * 32 + c] = acc;
    float ps = acc * aS[c], pd = acc * aD[c];
#pragma unroll
    for (int o = 1; o < 32; o <<= 1) { ps += __shfl_xor(ps, o); pd += __shfl_xor(pd, o); }
    if (c == 0) { as2[n] = ps; ad2[n] = pd; }
}

// ---------------- K7: layer-2 aggregation. Half-wave (32 lanes) per dst, chunked pipeline.
__global__ __launch_bounds__(256) void k_agg2(
    const int* __restrict__ offs, const int* __restrict__ csr,
    const float* __restrict__ h2, const float* __restrict__ as2, const float* __restrict__ ad2,
    const float* __restrict__ bias2, float* __restrict__ o2) {
    int c = threadIdx.x & 31;
    int dst = blockIdx.x * 8 + (threadIdx.x >> 5);
    if (dst >= NN) return;
    int beg = offs[dst], end = offs[dst + 1];
    int lastj = end - 1;
    float adh = ad2[dst];
    float acc = 0.f, dsum = 0.f;

    const int CH = 8;
    int sA[CH], sB[CH];
#pragma unroll
    for (int p = 0; p < CH; ++p) sA[p] = csr[min(beg + p, lastj)];
    for (int j = beg; j < end; j += CH) {
        int jn = j + CH;
#pragma unroll
        for (int p = 0; p < CH; ++p) sB[p] = csr[min(jn + p, lastj)];
        float av[CH], gv[CH];
#pragma unroll
        for (int p = 0; p < CH; ++p) {
            av[p] = as2[sA[p]];
            gv[p] = h2[sA[p] * 32 + c];
        }
#pragma unroll
        for (int p = 0; p < CH; ++p) {
            float e = av[p] + adh;
            e = (e > 0.f) ? e : 0.2f * e;
            float w = __expf(e);
            w = (j + p < end) ? w : 0.f;
            acc += w * gv[p];
            dsum += w;
        }
#pragma unroll
        for (int p = 0; p < CH; ++p) sA[p] = sB[p];
    }
    o2[dst * 32 + c] = acc / (dsum + 1e-16f) + bias2[c];
}

// ---------------- K8: graph boundaries from sorted batch.
__global__ void k_bound(const int* __restrict__ batch, int* __restrict__ lo) {
    int n = blockIdx.x * 256 + threadIdx.x;
    if (n >= NN) return;
    int b = batch[n];
    if (n == 0) {
        for (int g = 0; g <= b; ++g) lo[g] = 0;
    } else {
        int pb = batch[n - 1];
        for (int g = pb + 1; g <= b; ++g) lo[g] = n;
    }
    if (n == NN - 1) {
        for (int g = b + 1; g <= NG; ++g) lo[g] = NN;
    }
}

// ---------------- K9: pooled sums.
__global__ __launch_bounds__(256) void k_pool(const float* __restrict__ o2, const int* __restrict__ lo,
                                              float* __restrict__ pooled) {
    __shared__ float red[256];
    int g = blockIdx.x & 63, q = blockIdx.x >> 6;
    int beg = lo[g], end = lo[g + 1];
    int c = threadIdx.x & 31, row = threadIdx.x >> 5;
    float s = 0.f;
    for (int n = beg + q * 8 + row; n < end; n += 32) s += o2[n * 32 + c];
    red[threadIdx.x] = s;
    __syncthreads();
    for (int rr = 4; rr >= 1; rr >>= 1) {
        if (row < rr) red[threadIdx.x] += red[(row + rr) * 32 + c];
        __syncthreads();
    }
    if (row == 0) atomicAdd(&pooled[g * 32 + c], red[c]);
}

// ---------------- K10: mean + final linear -> out[64][2]
__global__ void k_fin(const float* __restrict__ pooled, const int* __restrict__ lo,
                      const float* __restrict__ lw, const float* __restrict__ lb,
                      float* __restrict__ out) {
    int t = threadIdx.x;
    if (t >= 128) return;
    int g = t >> 1, o = t & 1;
    int cnt = lo[g + 1] - lo[g];
    float inv = 1.f / fmaxf((float)cnt, 1.f);
    float s = 0.f;
#pragma unroll
    for (int c = 0; c < 32; ++c) s += pooled[g * 32 + c] * lw[c * 2 + o];
    out[g * 2 + o] = s * inv + lb[o];
}

// ----------------------------------------------------------------------------
extern "C" void kernel_launch(void* const* d_in, const int* in_sizes, int n_in,
                              void* d_out, int out_size, void* d_ws, size_t ws_size,
                              hipStream_t stream) {
    const float* x   = (const float*)d_in[0];
    const int*   ei  = (const int*)d_in[1];     // [2][NE]
    const int*   bat = (const int*)d_in[2];
    const float* W1  = (const float*)d_in[3];
    const float* aS1 = (const float*)d_in[4];
    const float* aD1 = (const float*)d_in[5];
    const float* b1  = (const float*)d_in[6];
    const float* W2  = (const float*)d_in[7];
    const float* aS2 = (const float*)d_in[8];
    const float* aD2 = (const float*)d_in[9];
    const float* b2  = (const float*)d_in[10];
    const float* lw  = (const float*)d_in[11];
    const float* lb  = (const float*)d_in[12];
    float* out = (float*)d_out;

    const int* esrc = ei;
    const int* edst = ei + NE;

    char* ws = (char*)d_ws;
    size_t off = 0;
    auto alloc = [&](size_t bytes) -> void* {
        off = (off + 255) & ~(size_t)255;
        void* p = ws + off;
        off += bytes;
        return p;
    };

    float *regA, *h1, *h2, *o2, *h1p, *h1o, *as1, *ad1, *as2, *ad2, *Wt2, *pooled;
    int *offs, *deg, *cur, *csr, *bsum, *bpre, *lo, *bcur;
    uint2 *rec;

    int SPLIT = 8;
    for (int attempt = 0; attempt < 2; ++attempt) {
        off = 0;
        regA = (float*)alloc((size_t)NN * 64 * 4);   // h1; later reused: h2 @ 0, o2 @ NN*32
        h1   = regA;
        h2   = regA;                                  // alias (h1 dead after k_agg1)
        o2   = regA + (size_t)NN * 32;                // alias
        h1p  = (float*)alloc((size_t)SPLIT * NN * 64 * 4);  // split-K partials
        h1o  = (float*)alloc((size_t)NN * 64 * 4);
        as1  = (float*)alloc((size_t)NN * 8 * 4);
        ad1  = (float*)alloc((size_t)NN * 8 * 4);
        as2  = (float*)alloc((size_t)NN * 4);
        ad2  = (float*)alloc((size_t)NN * 4);
        offs = (int*)alloc((size_t)(NN + 1) * 4);
        deg  = (int*)alloc((size_t)NN * 4);
        cur  = (int*)alloc((size_t)NN * 4);
        csr  = (int*)alloc((size_t)ET * 4);
        rec  = (uint2*)alloc((size_t)ET * 8);
        bcur = (int*)alloc((size_t)NB * 4);
        Wt2  = (float*)alloc((size_t)512 * 64 * 4);
        bsum = (int*)alloc(256 * 4);
        bpre = (int*)alloc(256 * 4);
        pooled = (float*)alloc((size_t)NG * 32 * 4);
        lo   = (int*)alloc((size_t)(NG + 1) * 4);
        if (off <= ws_size) break;
        SPLIT = 4;                                   // shrink partials and retry
    }
    if (off > ws_size) return;   // workspace too small: leave d_out poisoned (visible failure)

    hipMemsetAsync(deg, 0, (size_t)NN * 4, stream);
    hipMemsetAsync(pooled, 0, (size_t)NG * 32 * 4, stream);

    k_wt<<<32, 256, 0, stream>>>(W1, Wt2);
    if (SPLIT == 8) {
        k_gemm1<8><<<8 * ((NN + 63) / 64), 256, 0, stream>>>(x, Wt2, h1p);
        k_comb<8><<<(NN * 16) / 256, 256, 0, stream>>>(h1p, aS1, aD1, h1, as1, ad1);
    } else {
        k_gemm1<4><<<4 * ((NN + 63) / 64), 256, 0, stream>>>(x, Wt2, h1p);
        k_comb<4><<<(NN * 16) / 256, 256, 0, stream>>>(h1p, aS1, aD1, h1, as1, ad1);
    }

    int eblocks = (ET + 255) / 256;
    k_hist<<<eblocks, 256, 0, stream>>>(edst, deg);
    k_scan1<<<SCAN_BLOCKS, 256, 0, stream>>>(deg, offs, bsum);
    k_scan2<<<1, 256, 0, stream>>>(bsum, bpre);
    k_scan3<<<SCAN_BLOCKS, 256, 0, stream>>>(offs, bpre, cur);
    k_binit<<<(NB + 255) / 256, 256, 0, stream>>>(offs, bcur);
    k_bin<<<BIN_BLOCKS, 256, 0, stream>>>(esrc, edst, bcur, rec);
    k_unbin<<<NB, 512, 0, stream>>>(offs, rec, cur, csr);

    k_agg1<<<(NN + 3) / 4, 256, 0, stream>>>(offs, csr, h1, as1, ad1, b1, h1o);
    k_gemm2<<<(NN + 7) / 8, 256, 0, stream>>>(h1o, W2, aS2, aD2, h2, as2, ad2);
    k_agg2<<<(NN + 7) / 8, 256, 0, stream>>>(offs, csr, h2, as2, ad2, b2, o2);

    k_bound<<<SCAN_BLOCKS, 256, 0, stream>>>(bat, lo);
    k_pool<<<NG * 4, 256, 0, stream>>>(o2, lo, pooled);
    k_fin<<<1, 128, 0, stream>>>(pooled, lo, lw, lb, out);
}

// Round 10
// 356.932 us; speedup vs baseline: 1.8324x; 1.0336x over previous
//
#include <hip/hip_runtime.h>
#include <cstdint>
#include <cstddef>

#define NN 50000
#define NE 1600000
#define ET (NE + NN)          // edges + self loops
#define NG 64
#define SCAN_BLOCKS ((NN + 255) / 256)   // 196
#define NB ((NN + 127) >> 7)             // 391 dst-buckets, 128 nodes each
#define EPT 16
#define EPB (256 * EPT)                  // 4096 edges per bin-block
#define BIN_BLOCKS ((ET + EPB - 1) / EPB)

// ---------------- K0: transpose W1 [512][64] -> Wt2 k-packed float4
__global__ void k_wt(const float* __restrict__ W1, float* __restrict__ Wt2) {
    int id = blockIdx.x * 256 + threadIdx.x;
    if (id >= 128 * 64) return;
    int k4 = id >> 6, c = id & 63;
    float4 v;
    v.x = W1[(k4 * 4 + 0) * 64 + c];
    v.y = W1[(k4 * 4 + 1) * 64 + c];
    v.z = W1[(k4 * 4 + 2) * 64 + c];
    v.w = W1[(k4 * 4 + 3) * 64 + c];
    reinterpret_cast<float4*>(Wt2)[id] = v;
}

// ---------------- K1: h1 partials = x @ W1 (split-K = SPLIT), LDS-staged tile GEMM.
template<int SPLIT>
__global__ __launch_bounds__(256, 8) void k_gemm1(
    const float* __restrict__ x, const float* __restrict__ Wt2,
    float* __restrict__ h1p) {
    constexpr int K4 = 128 / SPLIT;
    constexpr int LK4 = (SPLIT == 8) ? 4 : ((SPLIT == 4) ? 5 : 6);
    __shared__ float4 xs[64 * K4];
    __shared__ float4 wsr[K4 * 64];

    int t = threadIdx.x;
    int lane = t & 63, wv_id = t >> 6;
    int part = blockIdx.x & (SPLIT - 1);
    int n0 = (blockIdx.x / SPLIT) * 64;
    int kb4 = part * K4;

    const float4* __restrict__ xf = reinterpret_cast<const float4*>(x);
    const float4* __restrict__ wf = reinterpret_cast<const float4*>(Wt2);

    constexpr int XPW = (64 * K4) / 64 / 4;
#pragma unroll
    for (int q = 0; q < XPW; ++q) {
        int base = (wv_id * XPW + q) * 64;
        int s = base + lane;
        int row = s >> LK4;
        int m = s & (K4 - 1);
        int k4f = m ^ ((row & 3) << 1);
        int rr = n0 + row; if (rr >= NN) rr = NN - 1;
        const float4* src = xf + (size_t)rr * 128 + kb4 + k4f;
        __builtin_amdgcn_global_load_lds(
            (const __attribute__((address_space(1))) void*)src,
            (__attribute__((address_space(3))) void*)&xs[base], 16, 0, 0);
    }
    constexpr int WPW = (K4 * 64) / 64 / 4;
#pragma unroll
    for (int q = 0; q < WPW; ++q) {
        int base = (wv_id * WPW + q) * 64;
        int s = base + lane;
        int k4 = s >> 6, c = s & 63;
        const float4* src = wf + (size_t)(kb4 + k4) * 64 + c;
        __builtin_amdgcn_global_load_lds(
            (const __attribute__((address_space(1))) void*)src,
            (__attribute__((address_space(3))) void*)&wsr[base], 16, 0, 0);
    }
    __syncthreads();

    int tc = t & 15;
    int trg = t >> 4;
    int swz = (trg & 3) << 1;

    float acc[4][4];
#pragma unroll
    for (int i = 0; i < 4; ++i)
#pragma unroll
        for (int j = 0; j < 4; ++j) acc[i][j] = 0.f;

#pragma unroll 2
    for (int k4 = 0; k4 < K4; ++k4) {
        float4 wv0 = wsr[k4 * 64 + tc];
        float4 wv1 = wsr[k4 * 64 + tc + 16];
        float4 wv2 = wsr[k4 * 64 + tc + 32];
        float4 wv3 = wsr[k4 * 64 + tc + 48];
        int kx = k4 ^ swz;
        float4 xv0 = xs[(trg +  0) * K4 + kx];
        float4 xv1 = xs[(trg + 16) * K4 + kx];
        float4 xv2 = xs[(trg + 32) * K4 + kx];
        float4 xv3 = xs[(trg + 48) * K4 + kx];
#define FMA4(a, xv, wv) { a += xv.x * wv.x; a += xv.y * wv.y; a += xv.z * wv.z; a += xv.w * wv.w; }
        FMA4(acc[0][0], xv0, wv0) FMA4(acc[0][1], xv0, wv1) FMA4(acc[0][2], xv0, wv2) FMA4(acc[0][3], xv0, wv3)
        FMA4(acc[1][0], xv1, wv0) FMA4(acc[1][1], xv1, wv1) FMA4(acc[1][2], xv1, wv2) FMA4(acc[1][3], xv1, wv3)
        FMA4(acc[2][0], xv2, wv0) FMA4(acc[2][1], xv2, wv1) FMA4(acc[2][2], xv2, wv2) FMA4(acc[2][3], xv2, wv3)
        FMA4(acc[3][0], xv3, wv0) FMA4(acc[3][1], xv3, wv1) FMA4(acc[3][2], xv3, wv2) FMA4(acc[3][3], xv3, wv3)
#undef FMA4
    }

    float* hp = h1p + (size_t)part * NN * 64;
#pragma unroll
    for (int i = 0; i < 4; ++i) {
        int r = n0 + trg + 16 * i;
        if (r >= NN) continue;
        float* rowp = hp + (size_t)r * 64 + tc;
        rowp[0]  = acc[i][0];
        rowp[16] = acc[i][1];
        rowp[32] = acc[i][2];
        rowp[48] = acc[i][3];
    }
}

// ---------------- K1b: combine split-K partials, store h1 + as1/ad1 epilogue.
template<int SPLIT>
__global__ __launch_bounds__(256) void k_comb(
    const float* __restrict__ h1p,
    const float* __restrict__ aS, const float* __restrict__ aD,
    float* __restrict__ h1, float* __restrict__ as1, float* __restrict__ ad1) {
    int id = blockIdx.x * 256 + threadIdx.x;   // grid sized exactly NN*16
    int r = id >> 4, tc = id & 15;
    const float4* p = reinterpret_cast<const float4*>(h1p);
    float4 v = p[id];
#pragma unroll
    for (int q = 1; q < SPLIT; ++q) {
        float4 b = p[(size_t)q * NN * 16 + id];
        v.x += b.x; v.y += b.y; v.z += b.z; v.w += b.w;
    }
    reinterpret_cast<float4*>(h1)[id] = v;
    int hh = tc >> 1, cb = (tc & 1) * 4;
    float ps = v.x * aS[hh * 8 + cb + 0] + v.y * aS[hh * 8 + cb + 1] +
               v.z * aS[hh * 8 + cb + 2] + v.w * aS[hh * 8 + cb + 3];
    float pd = v.x * aD[hh * 8 + cb + 0] + v.y * aD[hh * 8 + cb + 1] +
               v.z * aD[hh * 8 + cb + 2] + v.w * aD[hh * 8 + cb + 3];
    ps += __shfl_xor(ps, 1);
    pd += __shfl_xor(pd, 1);
    if ((tc & 1) == 0) { as1[r * 8 + hh] = ps; ad1[r * 8 + hh] = pd; }
}

// ---------------- CSR build: hist -> scan -> bin -> unbin
__global__ void k_hist(const int* __restrict__ edst, int* __restrict__ deg) {
    int e = blockIdx.x * 256 + threadIdx.x;
    if (e >= ET) return;
    int d = (e < NE) ? edst[e] : (e - NE);
    atomicAdd(&deg[d], 1);
}

__global__ __launch_bounds__(256) void k_scan1(const int* __restrict__ deg,
                                               int* __restrict__ offs, int* __restrict__ bsum) {
    __shared__ int lds_w[4];
    int i = blockIdx.x * 256 + threadIdx.x;
    int v = (i < NN) ? deg[i] : 0;
    int lane = threadIdx.x & 63, wid = threadIdx.x >> 6;
    int incl = v;
#pragma unroll
    for (int ofs = 1; ofs < 64; ofs <<= 1) {
        int o = __shfl_up(incl, ofs);
        if (lane >= ofs) incl += o;
    }
    if (lane == 63) lds_w[wid] = incl;
    __syncthreads();
    int wadd = 0;
    for (int w = 0; w < wid; ++w) wadd += lds_w[w];
    incl += wadd;
    if (i < NN) offs[i] = incl - v;
    if (threadIdx.x == 255) bsum[blockIdx.x] = incl;
}

__global__ void k_scan2(const int* __restrict__ bsum, int* __restrict__ bpre) {
    __shared__ int lds_w[4];
    int lane = threadIdx.x & 63, wid = threadIdx.x >> 6;
    int v = (threadIdx.x < SCAN_BLOCKS) ? bsum[threadIdx.x] : 0;
    int incl = v;
#pragma unroll
    for (int ofs = 1; ofs < 64; ofs <<= 1) {
        int o = __shfl_up(incl, ofs);
        if (lane >= ofs) incl += o;
    }
    if (lane == 63) lds_w[wid] = incl;
    __syncthreads();
    int wadd = 0;
    for (int w = 0; w < wid; ++w) wadd += lds_w[w];
    incl += wadd;
    bpre[threadIdx.x] = incl - v;
}

__global__ void k_scan3(int* __restrict__ offs, const int* __restrict__ bpre, int* __restrict__ cursor) {
    int i = blockIdx.x * 256 + threadIdx.x;
    if (i < NN) {
        int o = offs[i] + bpre[blockIdx.x];
        offs[i] = o;
        cursor[i] = o;
    }
    if (i == 0) offs[NN] = ET;
}

__global__ __launch_bounds__(256) void k_binit(const int* __restrict__ offs, int* __restrict__ bcur) {
    int b = blockIdx.x * 256 + threadIdx.x;
    if (b < NB) bcur[b] = offs[b << 7];
}

// bin: block-aggregated bucket scatter of (src,dst) records into dst-bucket streams.
__global__ __launch_bounds__(256) void k_bin(
    const int* __restrict__ esrc, const int* __restrict__ edst,
    int* __restrict__ bcur, uint2* __restrict__ rec) {
    __shared__ int bcnt[NB];
    int tid = threadIdx.x;
    for (int b = tid; b < NB; b += 256) bcnt[b] = 0;
    __syncthreads();
    int e0 = blockIdx.x * EPB;
    uint2 rv[EPT]; int rk[EPT];
#pragma unroll
    for (int q = 0; q < EPT; ++q) {
        int e = e0 + q * 256 + tid;
        rk[q] = -1;
        if (e < ET) {
            int s, d;
            if (e < NE) { s = esrc[e]; d = edst[e]; } else { s = d = e - NE; }
            rv[q] = make_uint2((unsigned)s, (unsigned)d);
            rk[q] = atomicAdd(&bcnt[d >> 7], 1);
        }
    }
    __syncthreads();
    for (int b = tid; b < NB; b += 256)
        bcnt[b] = atomicAdd(&bcur[b], bcnt[b]);
    __syncthreads();
#pragma unroll
    for (int q = 0; q < EPT; ++q) {
        if (rk[q] >= 0) rec[bcnt[rv[q].y >> 7] + rk[q]] = rv[q];
    }
}

// unbin: one block per bucket; all csr writes land in the bucket's ~17KB region (one XCD).
__global__ __launch_bounds__(512) void k_unbin(
    const int* __restrict__ offs, const uint2* __restrict__ rec,
    int* __restrict__ cur, int* __restrict__ csr) {
    int b = blockIdx.x;
    int lo = offs[b << 7];
    int ne = (b + 1) << 7;
    int hi = offs[(ne < NN) ? ne : NN];
    for (int i = lo + threadIdx.x; i < hi; i += 512) {
        uint2 r = rec[i];
        int pos = atomicAdd(&cur[r.y], 1);
        csr[pos] = (int)r.x;
    }
}

// ---------------- K4: layer-1 aggregation. One wave per dst; lane = (edge-slot g = l>>4, f4 q = l&15).
// One dwordx4 gather instruction covers 4 edges; 2-quad prefetch = 8 edges/iter.
__global__ __launch_bounds__(256) void k_agg1(
    const int* __restrict__ offs, const int* __restrict__ csr,
    const float* __restrict__ h1, const float* __restrict__ as1, const float* __restrict__ ad1,
    const float* __restrict__ bias1, float* __restrict__ h1o) {
    int l = threadIdx.x & 63;
    int dst = blockIdx.x * 4 + (threadIdx.x >> 6);
    if (dst >= NN) return;
    int g = l >> 4;            // edge slot 0..3
    int q = l & 15;            // float4 index in 64-ch row
    int h = q >> 1;            // head
    int beg = offs[dst], end = offs[dst + 1];
    int lastj = end - 1;       // deg >= 1 (self-loop)
    float adh = ad1[dst * 8 + h];
    const float4* __restrict__ h1f = reinterpret_cast<const float4*>(h1);

    float4 acc = make_float4(0.f, 0.f, 0.f, 0.f);
    float dsum = 0.f;

    int s0 = csr[min(beg + g, lastj)];
    int s1 = csr[min(beg + 4 + g, lastj)];
    for (int j = beg; j < end; j += 8) {
        int t0 = csr[min(j + 8 + g, lastj)];
        int t1 = csr[min(j + 12 + g, lastj)];
        float a0 = as1[s0 * 8 + h];
        float a1 = as1[s1 * 8 + h];
        float4 v0 = h1f[s0 * 16 + q];
        float4 v1 = h1f[s1 * 16 + q];
        float e0 = a0 + adh; e0 = (e0 > 0.f) ? e0 : 0.2f * e0;
        float w0 = __expf(e0); w0 = (j + g < end) ? w0 : 0.f;
        float e1 = a1 + adh; e1 = (e1 > 0.f) ? e1 : 0.2f * e1;
        float w1 = __expf(e1); w1 = (j + 4 + g < end) ? w1 : 0.f;
        acc.x += w0 * v0.x; acc.y += w0 * v0.y; acc.z += w0 * v0.z; acc.w += w0 * v0.w;
        acc.x += w1 * v1.x; acc.y += w1 * v1.y; acc.z += w1 * v1.z; acc.w += w1 * v1.w;
        dsum += w0 + w1;
        s0 = t0; s1 = t1;
    }

    // reduce the 4 edge slots (lanes sharing q): xor 16, 32
#pragma unroll
    for (int ofs = 16; ofs <= 32; ofs <<= 1) {
        acc.x += __shfl_xor(acc.x, ofs);
        acc.y += __shfl_xor(acc.y, ofs);
        acc.z += __shfl_xor(acc.z, ofs);
        acc.w += __shfl_xor(acc.w, ofs);
        dsum  += __shfl_xor(dsum, ofs);
    }

    if (g == 0) {
        float inv = 1.f / (dsum + 1e-16f);
        const float4 bq = reinterpret_cast<const float4*>(bias1)[q];
        float4 r;
        r.x = acc.x * inv + bq.x;
        r.y = acc.y * inv + bq.y;
        r.z = acc.z * inv + bq.z;
        r.w = acc.w * inv + bq.w;
        r.x = (r.x > 0.f) ? r.x : (__expf(r.x) - 1.f);
        r.y = (r.y > 0.f) ? r.y : (__expf(r.y) - 1.f);
        r.z = (r.z > 0.f) ? r.z : (__expf(r.z) - 1.f);
        r.w = (r.w > 0.f) ? r.w : (__expf(r.w) - 1.f);
        reinterpret_cast<float4*>(h1o)[dst * 16 + q] = r;
    }
}

// ---------------- K6: h2 = h1o @ W2 (+ alpha2 reductions). 32 lanes per node.
__global__ __launch_bounds__(256) void k_gemm2(
    const float* __restrict__ h1o, const float* __restrict__ W2,
    const float* __restrict__ aS, const float* __restrict__ aD,
    float* __restrict__ h2, float* __restrict__ as2, float* __restrict__ ad2) {
    int c = threadIdx.x & 31;
    int n = blockIdx.x * 8 + (threadIdx.x >> 5);
    if (n >= NN) return;
    const float4* hf = reinterpret_cast<const float4*>(h1o + n * 64);
    float acc = 0.f;
#pragma unroll
    for (int k4 = 0; k4 < 16; ++k4) {
        float4 hv = hf[k4];
        acc += hv.x * W2[(k4 * 4 + 0) * 32 + c] + hv.y * W2[(k4 * 4 + 1) * 32 + c] +
               hv.z * W2[(k4 * 4 + 2) * 32 + c] + hv.w * W2[(k4 * 4 + 3) * 32 + c];
    }
    h2[n * 32 + c] = acc;
    float ps = acc * aS[c], pd = acc * aD[c];
#pragma unroll
    for (int o = 1; o < 32; o <<= 1) { ps += __shfl_xor(ps, o); pd += __shfl_xor(pd, o); }
    if (c == 0) { as2[n] = ps; ad2[n] = pd; }
}

// ---------------- K7: layer-2 aggregation. One wave per dst; lane = (edge-slot g = l>>3, f4 q = l&7).
// One dwordx4 gather instruction covers 8 edges; 2-group prefetch = 16 edges/iter.
__global__ __launch_bounds__(256) void k_agg2(
    const int* __restrict__ offs, const int* __restrict__ csr,
    const float* __restrict__ h2, const float* __restrict__ as2, const float* __restrict__ ad2,
    const float* __restrict__ bias2, float* __restrict__ o2) {
    int l = threadIdx.x & 63;
    int dst = blockIdx.x * 4 + (threadIdx.x >> 6);
    if (dst >= NN) return;
    int g = l >> 3;            // edge slot 0..7
    int q = l & 7;             // float4 index in 32-ch row
    int beg = offs[dst], end = offs[dst + 1];
    int lastj = end - 1;
    float adh = ad2[dst];
    const float4* __restrict__ h2f = reinterpret_cast<const float4*>(h2);

    float4 acc = make_float4(0.f, 0.f, 0.f, 0.f);
    float dsum = 0.f;

    int s0 = csr[min(beg + g, lastj)];
    int s1 = csr[min(beg + 8 + g, lastj)];
    for (int j = beg; j < end; j += 16) {
        int t0 = csr[min(j + 16 + g, lastj)];
        int t1 = csr[min(j + 24 + g, lastj)];
        float a0 = as2[s0];
        float a1 = as2[s1];
        float4 v0 = h2f[s0 * 8 + q];
        float4 v1 = h2f[s1 * 8 + q];
        float e0 = a0 + adh; e0 = (e0 > 0.f) ? e0 : 0.2f * e0;
        float w0 = __expf(e0); w0 = (j + g < end) ? w0 : 0.f;
        float e1 = a1 + adh; e1 = (e1 > 0.f) ? e1 : 0.2f * e1;
        float w1 = __expf(e1); w1 = (j + 8 + g < end) ? w1 : 0.f;
        acc.x += w0 * v0.x; acc.y += w0 * v0.y; acc.z += w0 * v0.z; acc.w += w0 * v0.w;
        acc.x += w1 * v1.x; acc.y += w1 * v1.y; acc.z += w1 * v1.z; acc.w += w1 * v1.w;
        dsum += w0 + w1;
        s0 = t0; s1 = t1;
    }

#pragma unroll
    for (int ofs = 8; ofs <= 32; ofs <<= 1) {
        acc.x += __shfl_xor(acc.x, ofs);
        acc.y += __shfl_xor(acc.y, ofs);
        acc.z += __shfl_xor(acc.z, ofs);
        acc.w += __shfl_xor(acc.w, ofs);
        dsum  += __shfl_xor(dsum, ofs);
    }

    if (g == 0) {
        float inv = 1.f / (dsum + 1e-16f);
        const float4 bq = reinterpret_cast<const float4*>(bias2)[q];
        float4 r;
        r.x = acc.x * inv + bq.x;
        r.y = acc.y * inv + bq.y;
        r.z = acc.z * inv + bq.z;
        r.w = acc.w * inv + bq.w;
        reinterpret_cast<float4*>(o2)[dst * 8 + q] = r;
    }
}

// ---------------- K8: graph boundaries from sorted batch.
__global__ void k_bound(const int* __restrict__ batch, int* __restrict__ lo) {
    int n = blockIdx.x * 256 + threadIdx.x;
    if (n >= NN) return;
    int b = batch[n];
    if (n == 0) {
        for (int g = 0; g <= b; ++g) lo[g] = 0;
    } else {
        int pb = batch[n - 1];
        for (int g = pb + 1; g <= b; ++g) lo[g] = n;
    }
    if (n == NN - 1) {
        for (int g = b + 1; g <= NG; ++g) lo[g] = NN;
    }
}

// ---------------- K9: pooled sums.
__global__ __launch_bounds__(256) void k_pool(const float* __restrict__ o2, const int* __restrict__ lo,
                                              float* __restrict__ pooled) {
    __shared__ float red[256];
    int g = blockIdx.x & 63, q = blockIdx.x >> 6;
    int beg = lo[g], end = lo[g + 1];
    int c = threadIdx.x & 31, row = threadIdx.x >> 5;
    float s = 0.f;
    for (int n = beg + q * 8 + row; n < end; n += 32) s += o2[n * 32 + c];
    red[threadIdx.x] = s;
    __syncthreads();
    for (int rr = 4; rr >= 1; rr >>= 1) {
        if (row < rr) red[threadIdx.x] += red[(row + rr) * 32 + c];
        __syncthreads();
    }
    if (row == 0) atomicAdd(&pooled[g * 32 + c], red[c]);
}

// ---------------- K10: mean + final linear -> out[64][2]
__global__ void k_fin(const float* __restrict__ pooled, const int* __restrict__ lo,
                      const float* __restrict__ lw, const float* __restrict__ lb,
                      float* __restrict__ out) {
    int t = threadIdx.x;
    if (t >= 128) return;
    int g = t >> 1, o = t & 1;
    int cnt = lo[g + 1] - lo[g];
    float inv = 1.f / fmaxf((float)cnt, 1.f);
    float s = 0.f;
#pragma unroll
    for (int c = 0; c < 32; ++c) s += pooled[g * 32 + c] * lw[c * 2 + o];
    out[g * 2 + o] = s * inv + lb[o];
}

// ----------------------------------------------------------------------------
extern "C" void kernel_launch(void* const* d_in, const int* in_sizes, int n_in,
                              void* d_out, int out_size, void* d_ws, size_t ws_size,
                              hipStream_t stream) {
    const float* x   = (const float*)d_in[0];
    const int*   ei  = (const int*)d_in[1];     // [2][NE]
    const int*   bat = (const int*)d_in[2];
    const float* W1  = (const float*)d_in[3];
    const float* aS1 = (const float*)d_in[4];
    const float* aD1 = (const float*)d_in[5];
    const float* b1  = (const float*)d_in[6];
    const float* W2  = (const float*)d_in[7];
    const float* aS2 = (const float*)d_in[8];
    const float* aD2 = (const float*)d_in[9];
    const float* b2  = (const float*)d_in[10];
    const float* lw  = (const float*)d_in[11];
    const float* lb  = (const float*)d_in[12];
    float* out = (float*)d_out;

    const int* esrc = ei;
    const int* edst = ei + NE;

    char* ws = (char*)d_ws;
    size_t off = 0;
    auto alloc = [&](size_t bytes) -> void* {
        off = (off + 255) & ~(size_t)255;
        void* p = ws + off;
        off += bytes;
        return p;
    };

    float *regA, *h1, *h2, *o2, *h1p, *h1o, *as1, *ad1, *as2, *ad2, *Wt2, *pooled;
    int *offs, *deg, *cur, *csr, *bsum, *bpre, *lo, *bcur;
    uint2 *rec;

    int SPLIT = 8;
    for (int attempt = 0; attempt < 2; ++attempt) {
        off = 0;
        regA = (float*)alloc((size_t)NN * 64 * 4);   // h1; later reused: h2 @ 0, o2 @ NN*32
        h1   = regA;
        h2   = regA;                                  // alias (h1 dead after k_agg1)
        o2   = regA + (size_t)NN * 32;                // alias
        h1p  = (float*)alloc((size_t)SPLIT * NN * 64 * 4);  // split-K partials
        h1o  = (float*)alloc((size_t)NN * 64 * 4);
        as1  = (float*)alloc((size_t)NN * 8 * 4);
        ad1  = (float*)alloc((size_t)NN * 8 * 4);
        as2  = (float*)alloc((size_t)NN * 4);
        ad2  = (float*)alloc((size_t)NN * 4);
        offs = (int*)alloc((size_t)(NN + 1) * 4);
        deg  = (int*)alloc((size_t)NN * 4);
        cur  = (int*)alloc((size_t)NN * 4);
        csr  = (int*)alloc((size_t)ET * 4);
        rec  = (uint2*)alloc((size_t)ET * 8);
        bcur = (int*)alloc((size_t)NB * 4);
        Wt2  = (float*)alloc((size_t)512 * 64 * 4);
        bsum = (int*)alloc(256 * 4);
        bpre = (int*)alloc(256 * 4);
        pooled = (float*)alloc((size_t)NG * 32 * 4);
        lo   = (int*)alloc((size_t)(NG + 1) * 4);
        if (off <= ws_size) break;
        SPLIT = 4;                                   // shrink partials and retry
    }
    if (off > ws_size) return;   // workspace too small: leave d_out poisoned (visible failure)

    hipMemsetAsync(deg, 0, (size_t)NN * 4, stream);
    hipMemsetAsync(pooled, 0, (size_t)NG * 32 * 4, stream);

    k_wt<<<32, 256, 0, stream>>>(W1, Wt2);
    if (SPLIT == 8) {
        k_gemm1<8><<<8 * ((NN + 63) / 64), 256, 0, stream>>>(x, Wt2, h1p);
        k_comb<8><<<(NN * 16) / 256, 256, 0, stream>>>(h1p, aS1, aD1, h1, as1, ad1);
    } else {
        k_gemm1<4><<<4 * ((NN + 63) / 64), 256, 0, stream>>>(x, Wt2, h1p);
        k_comb<4><<<(NN * 16) / 256, 256, 0, stream>>>(h1p, aS1, aD1, h1, as1, ad1);
    }

    int eblocks = (ET + 255) / 256;
    k_hist<<<eblocks, 256, 0, stream>>>(edst, deg);
    k_scan1<<<SCAN_BLOCKS, 256, 0, stream>>>(deg, offs, bsum);
    k_scan2<<<1, 256, 0, stream>>>(bsum, bpre);
    k_scan3<<<SCAN_BLOCKS, 256, 0, stream>>>(offs, bpre, cur);
    k_binit<<<(NB + 255) / 256, 256, 0, stream>>>(offs, bcur);
    k_bin<<<BIN_BLOCKS, 256, 0, stream>>>(esrc, edst, bcur, rec);
    k_unbin<<<NB, 512, 0, stream>>>(offs, rec, cur, csr);

    k_agg1<<<(NN + 3) / 4, 256, 0, stream>>>(offs, csr, h1, as1, ad1, b1, h1o);
    k_gemm2<<<(NN + 7) / 8, 256, 0, stream>>>(h1o, W2, aS2, aD2, h2, as2, ad2);
    k_agg2<<<(NN + 3) / 4, 256, 0, stream>>>(offs, csr, h2, as2, ad2, b2, o2);

    k_bound<<<SCAN_BLOCKS, 256, 0, stream>>>(bat, lo);
    k_pool<<<NG * 4, 256, 0, stream>>>(o2, lo, pooled);
    k_fin<<<1, 128, 0, stream>>>(pooled, lo, lw, lb, out);
}

// Round 11
// 273.705 us; speedup vs baseline: 2.3896x; 1.3041x over previous
//
#include <hip/hip_runtime.h>
#include <cstdint>
#include <cstddef>

#define NN 50000
#define NE 1600000
#define ET (NE + NN)          // edges + self loops
#define NG 64
#define SCAN_BLOCKS ((NN + 255) / 256)   // 196
#define NB ((NN + 127) >> 7)             // 391 dst-buckets, 128 nodes each
#define EPT 16
#define EPB (256 * EPT)                  // 4096 edges per bin-block
#define BIN_BLOCKS ((ET + EPB - 1) / EPB)

// ---------------- K0: transpose W1 [512][64] -> Wt2 k-packed float4
__global__ void k_wt(const float* __restrict__ W1, float* __restrict__ Wt2) {
    int id = blockIdx.x * 256 + threadIdx.x;
    if (id >= 128 * 64) return;
    int k4 = id >> 6, c = id & 63;
    float4 v;
    v.x = W1[(k4 * 4 + 0) * 64 + c];
    v.y = W1[(k4 * 4 + 1) * 64 + c];
    v.z = W1[(k4 * 4 + 2) * 64 + c];
    v.w = W1[(k4 * 4 + 3) * 64 + c];
    reinterpret_cast<float4*>(Wt2)[id] = v;
}

// ---------------- K1: h1 partials = x @ W1 (split-K = SPLIT), LDS-staged tile GEMM.
template<int SPLIT>
__global__ __launch_bounds__(256, 8) void k_gemm1(
    const float* __restrict__ x, const float* __restrict__ Wt2,
    float* __restrict__ h1p) {
    constexpr int K4 = 128 / SPLIT;
    constexpr int LK4 = (SPLIT == 8) ? 4 : ((SPLIT == 4) ? 5 : 6);
    __shared__ float4 xs[64 * K4];
    __shared__ float4 wsr[K4 * 64];

    int t = threadIdx.x;
    int lane = t & 63, wv_id = t >> 6;
    int part = blockIdx.x & (SPLIT - 1);
    int n0 = (blockIdx.x / SPLIT) * 64;
    int kb4 = part * K4;

    const float4* __restrict__ xf = reinterpret_cast<const float4*>(x);
    const float4* __restrict__ wf = reinterpret_cast<const float4*>(Wt2);

    constexpr int XPW = (64 * K4) / 64 / 4;
#pragma unroll
    for (int q = 0; q < XPW; ++q) {
        int base = (wv_id * XPW + q) * 64;
        int s = base + lane;
        int row = s >> LK4;
        int m = s & (K4 - 1);
        int k4f = m ^ ((row & 3) << 1);
        int rr = n0 + row; if (rr >= NN) rr = NN - 1;
        const float4* src = xf + (size_t)rr * 128 + kb4 + k4f;
        __builtin_amdgcn_global_load_lds(
            (const __attribute__((address_space(1))) void*)src,
            (__attribute__((address_space(3))) void*)&xs[base], 16, 0, 0);
    }
    constexpr int WPW = (K4 * 64) / 64 / 4;
#pragma unroll
    for (int q = 0; q < WPW; ++q) {
        int base = (wv_id * WPW + q) * 64;
        int s = base + lane;
        int k4 = s >> 6, c = s & 63;
        const float4* src = wf + (size_t)(kb4 + k4) * 64 + c;
        __builtin_amdgcn_global_load_lds(
            (const __attribute__((address_space(1))) void*)src,
            (__attribute__((address_space(3))) void*)&wsr[base], 16, 0, 0);
    }
    __syncthreads();

    int tc = t & 15;
    int trg = t >> 4;
    int swz = (trg & 3) << 1;

    float acc[4][4];
#pragma unroll
    for (int i = 0; i < 4; ++i)
#pragma unroll
        for (int j = 0; j < 4; ++j) acc[i][j] = 0.f;

#pragma unroll 2
    for (int k4 = 0; k4 < K4; ++k4) {
        float4 wv0 = wsr[k4 * 64 + tc];
        float4 wv1 = wsr[k4 * 64 + tc + 16];
        float4 wv2 = wsr[k4 * 64 + tc + 32];
        float4 wv3 = wsr[k4 * 64 + tc + 48];
        int kx = k4 ^ swz;
        float4 xv0 = xs[(trg +  0) * K4 + kx];
        float4 xv1 = xs[(trg + 16) * K4 + kx];
        float4 xv2 = xs[(trg + 32) * K4 + kx];
        float4 xv3 = xs[(trg + 48) * K4 + kx];
#define FMA4(a, xv, wv) { a += xv.x * wv.x; a += xv.y * wv.y; a += xv.z * wv.z; a += xv.w * wv.w; }
        FMA4(acc[0][0], xv0, wv0) FMA4(acc[0][1], xv0, wv1) FMA4(acc[0][2], xv0, wv2) FMA4(acc[0][3], xv0, wv3)
        FMA4(acc[1][0], xv1, wv0) FMA4(acc[1][1], xv1, wv1) FMA4(acc[1][2], xv1, wv2) FMA4(acc[1][3], xv1, wv3)
        FMA4(acc[2][0], xv2, wv0) FMA4(acc[2][1], xv2, wv1) FMA4(acc[2][2], xv2, wv2) FMA4(acc[2][3], xv2, wv3)
        FMA4(acc[3][0], xv3, wv0) FMA4(acc[3][1], xv3, wv1) FMA4(acc[3][2], xv3, wv2) FMA4(acc[3][3], xv3, wv3)
#undef FMA4
    }

    float* hp = h1p + (size_t)part * NN * 64;
#pragma unroll
    for (int i = 0; i < 4; ++i) {
        int r = n0 + trg + 16 * i;
        if (r >= NN) continue;
        float* rowp = hp + (size_t)r * 64 + tc;
        rowp[0]  = acc[i][0];
        rowp[16] = acc[i][1];
        rowp[32] = acc[i][2];
        rowp[48] = acc[i][3];
    }
}

// ---------------- K1b: combine split-K partials, store h1 + as1/ad1 epilogue.
template<int SPLIT>
__global__ __launch_bounds__(256) void k_comb(
    const float* __restrict__ h1p,
    const float* __restrict__ aS, const float* __restrict__ aD,
    float* __restrict__ h1, float* __restrict__ as1, float* __restrict__ ad1) {
    int id = blockIdx.x * 256 + threadIdx.x;   // grid sized exactly NN*16
    int r = id >> 4, tc = id & 15;
    const float4* p = reinterpret_cast<const float4*>(h1p);
    float4 v = p[id];
#pragma unroll
    for (int q = 1; q < SPLIT; ++q) {
        float4 b = p[(size_t)q * NN * 16 + id];
        v.x += b.x; v.y += b.y; v.z += b.z; v.w += b.w;
    }
    reinterpret_cast<float4*>(h1)[id] = v;
    int hh = tc >> 1, cb = (tc & 1) * 4;
    float ps = v.x * aS[hh * 8 + cb + 0] + v.y * aS[hh * 8 + cb + 1] +
               v.z * aS[hh * 8 + cb + 2] + v.w * aS[hh * 8 + cb + 3];
    float pd = v.x * aD[hh * 8 + cb + 0] + v.y * aD[hh * 8 + cb + 1] +
               v.z * aD[hh * 8 + cb + 2] + v.w * aD[hh * 8 + cb + 3];
    ps += __shfl_xor(ps, 1);
    pd += __shfl_xor(pd, 1);
    if ((tc & 1) == 0) { as1[r * 8 + hh] = ps; ad1[r * 8 + hh] = pd; }
}

// ---------------- CSR build: bhist -> bscan -> bin -> bdeg -> scan -> unbin
// bucket-level histogram: LDS aggregate, one global atomic per (block,bucket)
__global__ __launch_bounds__(256) void k_bhist(const int* __restrict__ edst, int* __restrict__ bdeg) {
    __shared__ int cnt[NB];
    int tid = threadIdx.x;
    for (int b = tid; b < NB; b += 256) cnt[b] = 0;
    __syncthreads();
    int e0 = blockIdx.x * EPB;
#pragma unroll
    for (int q = 0; q < EPT; ++q) {
        int e = e0 + q * 256 + tid;
        if (e < ET) {
            int d = (e < NE) ? edst[e] : (e - NE);
            atomicAdd(&cnt[d >> 7], 1);
        }
    }
    __syncthreads();
    for (int b = tid; b < NB; b += 256)
        if (cnt[b]) atomicAdd(&bdeg[b], cnt[b]);
}

// bucket scan: bo = exclusive scan of bdeg; bcur = bo
__global__ __launch_bounds__(512) void k_bscan(const int* __restrict__ bdeg,
                                               int* __restrict__ bo, int* __restrict__ bcur) {
    __shared__ int lds_w[8];
    int tid = threadIdx.x;
    int lane = tid & 63, wid = tid >> 6;
    int v = (tid < NB) ? bdeg[tid] : 0;
    int incl = v;
#pragma unroll
    for (int ofs = 1; ofs < 64; ofs <<= 1) {
        int o = __shfl_up(incl, ofs);
        if (lane >= ofs) incl += o;
    }
    if (lane == 63) lds_w[wid] = incl;
    __syncthreads();
    int wadd = 0;
    for (int w = 0; w < wid; ++w) wadd += lds_w[w];
    incl += wadd;
    int ex = incl - v;
    if (tid < NB) { bo[tid] = ex; bcur[tid] = ex; }
    if (tid == NB - 1) bo[NB] = ex + v;   // == ET
}

// bin: block-aggregated bucket scatter of (src,dst) records into dst-bucket streams.
__global__ __launch_bounds__(256) void k_bin(
    const int* __restrict__ esrc, const int* __restrict__ edst,
    int* __restrict__ bcur, uint2* __restrict__ rec) {
    __shared__ int bcnt[NB];
    int tid = threadIdx.x;
    for (int b = tid; b < NB; b += 256) bcnt[b] = 0;
    __syncthreads();
    int e0 = blockIdx.x * EPB;
    uint2 rv[EPT]; int rk[EPT];
#pragma unroll
    for (int q = 0; q < EPT; ++q) {
        int e = e0 + q * 256 + tid;
        rk[q] = -1;
        if (e < ET) {
            int s, d;
            if (e < NE) { s = esrc[e]; d = edst[e]; } else { s = d = e - NE; }
            rv[q] = make_uint2((unsigned)s, (unsigned)d);
            rk[q] = atomicAdd(&bcnt[d >> 7], 1);
        }
    }
    __syncthreads();
    for (int b = tid; b < NB; b += 256)
        bcnt[b] = atomicAdd(&bcur[b], bcnt[b]);
    __syncthreads();
#pragma unroll
    for (int q = 0; q < EPT; ++q) {
        if (rk[q] >= 0) rec[bcnt[rv[q].y >> 7] + rk[q]] = rv[q];
    }
}

// per-node degrees from bucket records (LDS counters, one plain store per node)
__global__ __launch_bounds__(256) void k_bdeg(const int* __restrict__ bo, const uint2* __restrict__ rec,
                                              int* __restrict__ deg) {
    __shared__ int cnt[128];
    int b = blockIdx.x, tid = threadIdx.x;
    if (tid < 128) cnt[tid] = 0;
    __syncthreads();
    int lo = bo[b], hi = bo[b + 1];
    for (int i = lo + tid; i < hi; i += 256)
        atomicAdd(&cnt[rec[i].y & 127], 1);
    __syncthreads();
    if (tid < 128) {
        int n = (b << 7) + tid;
        if (n < NN) deg[n] = cnt[tid];
    }
}

__global__ __launch_bounds__(256) void k_scan1(const int* __restrict__ deg,
                                               int* __restrict__ offs, int* __restrict__ bsum) {
    __shared__ int lds_w[4];
    int i = blockIdx.x * 256 + threadIdx.x;
    int v = (i < NN) ? deg[i] : 0;
    int lane = threadIdx.x & 63, wid = threadIdx.x >> 6;
    int incl = v;
#pragma unroll
    for (int ofs = 1; ofs < 64; ofs <<= 1) {
        int o = __shfl_up(incl, ofs);
        if (lane >= ofs) incl += o;
    }
    if (lane == 63) lds_w[wid] = incl;
    __syncthreads();
    int wadd = 0;
    for (int w = 0; w < wid; ++w) wadd += lds_w[w];
    incl += wadd;
    if (i < NN) offs[i] = incl - v;
    if (threadIdx.x == 255) bsum[blockIdx.x] = incl;
}

__global__ void k_scan2(const int* __restrict__ bsum, int* __restrict__ bpre) {
    __shared__ int lds_w[4];
    int lane = threadIdx.x & 63, wid = threadIdx.x >> 6;
    int v = (threadIdx.x < SCAN_BLOCKS) ? bsum[threadIdx.x] : 0;
    int incl = v;
#pragma unroll
    for (int ofs = 1; ofs < 64; ofs <<= 1) {
        int o = __shfl_up(incl, ofs);
        if (lane >= ofs) incl += o;
    }
    if (lane == 63) lds_w[wid] = incl;
    __syncthreads();
    int wadd = 0;
    for (int w = 0; w < wid; ++w) wadd += lds_w[w];
    incl += wadd;
    bpre[threadIdx.x] = incl - v;
}

__global__ void k_scan3(int* __restrict__ offs, const int* __restrict__ bpre) {
    int i = blockIdx.x * 256 + threadIdx.x;
    if (i < NN) offs[i] = offs[i] + bpre[blockIdx.x];
    if (i == 0) offs[NN] = ET;
}

// unbin: one block per bucket; LDS cursors (no global atomics); csr writes land in ~17KB region.
__global__ __launch_bounds__(256) void k_unbin(
    const int* __restrict__ offs, const int* __restrict__ bo,
    const uint2* __restrict__ rec, int* __restrict__ csr) {
    __shared__ int lcur[128];
    int b = blockIdx.x, tid = threadIdx.x;
    if (tid < 128) {
        int n = (b << 7) + tid;
        lcur[tid] = (n < NN) ? offs[n] : 0;
    }
    __syncthreads();
    int lo = bo[b], hi = bo[b + 1];
    for (int i = lo + tid; i < hi; i += 256) {
        uint2 r = rec[i];
        int pos = atomicAdd(&lcur[r.y & 127], 1);
        csr[pos] = (int)r.x;
    }
}

// ---------------- K4: layer-1 aggregation. One wave per dst; lane = (edge-slot g = l>>4, f4 q = l&15).
__global__ __launch_bounds__(256) void k_agg1(
    const int* __restrict__ offs, const int* __restrict__ csr,
    const float* __restrict__ h1, const float* __restrict__ as1, const float* __restrict__ ad1,
    const float* __restrict__ bias1, float* __restrict__ h1o) {
    int l = threadIdx.x & 63;
    int dst = blockIdx.x * 4 + (threadIdx.x >> 6);
    if (dst >= NN) return;
    int g = l >> 4;            // edge slot 0..3
    int q = l & 15;            // float4 index in 64-ch row
    int h = q >> 1;            // head
    int beg = offs[dst], end = offs[dst + 1];
    int lastj = end - 1;       // deg >= 1 (self-loop)
    float adh = ad1[dst * 8 + h];
    const float4* __restrict__ h1f = reinterpret_cast<const float4*>(h1);

    float4 acc = make_float4(0.f, 0.f, 0.f, 0.f);
    float dsum = 0.f;

    int s0 = csr[min(beg + g, lastj)];
    int s1 = csr[min(beg + 4 + g, lastj)];
    for (int j = beg; j < end; j += 8) {
        int t0 = csr[min(j + 8 + g, lastj)];
        int t1 = csr[min(j + 12 + g, lastj)];
        float a0 = as1[s0 * 8 + h];
        float a1 = as1[s1 * 8 + h];
        float4 v0 = h1f[s0 * 16 + q];
        float4 v1 = h1f[s1 * 16 + q];
        float e0 = a0 + adh; e0 = (e0 > 0.f) ? e0 : 0.2f * e0;
        float w0 = __expf(e0); w0 = (j + g < end) ? w0 : 0.f;
        float e1 = a1 + adh; e1 = (e1 > 0.f) ? e1 : 0.2f * e1;
        float w1 = __expf(e1); w1 = (j + 4 + g < end) ? w1 : 0.f;
        acc.x += w0 * v0.x; acc.y += w0 * v0.y; acc.z += w0 * v0.z; acc.w += w0 * v0.w;
        acc.x += w1 * v1.x; acc.y += w1 * v1.y; acc.z += w1 * v1.z; acc.w += w1 * v1.w;
        dsum += w0 + w1;
        s0 = t0; s1 = t1;
    }

#pragma unroll
    for (int ofs = 16; ofs <= 32; ofs <<= 1) {
        acc.x += __shfl_xor(acc.x, ofs);
        acc.y += __shfl_xor(acc.y, ofs);
        acc.z += __shfl_xor(acc.z, ofs);
        acc.w += __shfl_xor(acc.w, ofs);
        dsum  += __shfl_xor(dsum, ofs);
    }

    if (g == 0) {
        float inv = 1.f / (dsum + 1e-16f);
        const float4 bq = reinterpret_cast<const float4*>(bias1)[q];
        float4 r;
        r.x = acc.x * inv + bq.x;
        r.y = acc.y * inv + bq.y;
        r.z = acc.z * inv + bq.z;
        r.w = acc.w * inv + bq.w;
        r.x = (r.x > 0.f) ? r.x : (__expf(r.x) - 1.f);
        r.y = (r.y > 0.f) ? r.y : (__expf(r.y) - 1.f);
        r.z = (r.z > 0.f) ? r.z : (__expf(r.z) - 1.f);
        r.w = (r.w > 0.f) ? r.w : (__expf(r.w) - 1.f);
        reinterpret_cast<float4*>(h1o)[dst * 16 + q] = r;
    }
}

// ---------------- K6: h2 = h1o @ W2 (+ alpha2 reductions). 32 lanes per node.
__global__ __launch_bounds__(256) void k_gemm2(
    const float* __restrict__ h1o, const float* __restrict__ W2,
    const float* __restrict__ aS, const float* __restrict__ aD,
    float* __restrict__ h2, float* __restrict__ as2, float* __restrict__ ad2) {
    int c = threadIdx.x & 31;
    int n = blockIdx.x * 8 + (threadIdx.x >> 5);
    if (n >= NN) return;
    const float4* hf = reinterpret_cast<const float4*>(h1o + n * 64);
    float acc = 0.f;
#pragma unroll
    for (int k4 = 0; k4 < 16; ++k4) {
        float4 hv = hf[k4];
        acc += hv.x * W2[(k4 * 4 + 0) * 32 + c] + hv.y * W2[(k4 * 4 + 1) * 32 + c] +
               hv.z * W2[(k4 * 4 + 2) * 32 + c] + hv.w * W2[(k4 * 4 + 3) * 32 + c];
    }
    h2[n * 32 + c] = acc;
    float ps = acc * aS[c], pd = acc * aD[c];
#pragma unroll
    for (int o = 1; o < 32; o <<= 1) { ps += __shfl_xor(ps, o); pd += __shfl_xor(pd, o); }
    if (c == 0) { as2[n] = ps; ad2[n] = pd; }
}

// ---------------- K7: layer-2 aggregation. One wave per dst; lane = (edge-slot g = l>>3, f4 q = l&7).
__global__ __launch_bounds__(256) void k_agg2(
    const int* __restrict__ offs, const int* __restrict__ csr,
    const float* __restrict__ h2, const float* __restrict__ as2, const float* __restrict__ ad2,
    const float* __restrict__ bias2, float* __restrict__ o2) {
    int l = threadIdx.x & 63;
    int dst = blockIdx.x * 4 + (threadIdx.x >> 6);
    if (dst >= NN) return;
    int g = l >> 3;            // edge slot 0..7
    int q = l & 7;             // float4 index in 32-ch row
    int beg = offs[dst], end = offs[dst + 1];
    int lastj = end - 1;
    float adh = ad2[dst];
    const float4* __restrict__ h2f = reinterpret_cast<const float4*>(h2);

    float4 acc = make_float4(0.f, 0.f, 0.f, 0.f);
    float dsum = 0.f;

    int s0 = csr[min(beg + g, lastj)];
    int s1 = csr[min(beg + 8 + g, lastj)];
    for (int j = beg; j < end; j += 16) {
        int t0 = csr[min(j + 16 + g, lastj)];
        int t1 = csr[min(j + 24 + g, lastj)];
        float a0 = as2[s0];
        float a1 = as2[s1];
        float4 v0 = h2f[s0 * 8 + q];
        float4 v1 = h2f[s1 * 8 + q];
        float e0 = a0 + adh; e0 = (e0 > 0.f) ? e0 : 0.2f * e0;
        float w0 = __expf(e0); w0 = (j + g < end) ? w0 : 0.f;
        float e1 = a1 + adh; e1 = (e1 > 0.f) ? e1 : 0.2f * e1;
        float w1 = __expf(e1); w1 = (j + 8 + g < end) ? w1 : 0.f;
        acc.x += w0 * v0.x; acc.y += w0 * v0.y; acc.z += w0 * v0.z; acc.w += w0 * v0.w;
        acc.x += w1 * v1.x; acc.y += w1 * v1.y; acc.z += w1 * v1.z; acc.w += w1 * v1.w;
        dsum += w0 + w1;
        s0 = t0; s1 = t1;
    }

#pragma unroll
    for (int ofs = 8; ofs <= 32; ofs <<= 1) {
        acc.x += __shfl_xor(acc.x, ofs);
        acc.y += __shfl_xor(acc.y, ofs);
        acc.z += __shfl_xor(acc.z, ofs);
        acc.w += __shfl_xor(acc.w, ofs);
        dsum  += __shfl_xor(dsum, ofs);
    }

    if (g == 0) {
        float inv = 1.f / (dsum + 1e-16f);
        const float4 bq = reinterpret_cast<const float4*>(bias2)[q];
        float4 r;
        r.x = acc.x * inv + bq.x;
        r.y = acc.y * inv + bq.y;
        r.z = acc.z * inv + bq.z;
        r.w = acc.w * inv + bq.w;
        reinterpret_cast<float4*>(o2)[dst * 8 + q] = r;
    }
}

// ---------------- K8: graph boundaries from sorted batch.
__global__ void k_bound(const int* __restrict__ batch, int* __restrict__ lo) {
    int n = blockIdx.x * 256 + threadIdx.x;
    if (n >= NN) return;
    int b = batch[n];
    if (n == 0) {
        for (int g = 0; g <= b; ++g) lo[g] = 0;
    } else {
        int pb = batch[n - 1];
        for (int g = pb + 1; g <= b; ++g) lo[g] = n;
    }
    if (n == NN - 1) {
        for (int g = b + 1; g <= NG; ++g) lo[g] = NN;
    }
}

// ---------------- K9: pooled sums.
__global__ __launch_bounds__(256) void k_pool(const float* __restrict__ o2, const int* __restrict__ lo,
                                              float* __restrict__ pooled) {
    __shared__ float red[256];
    int g = blockIdx.x & 63, q = blockIdx.x >> 6;
    int beg = lo[g], end = lo[g + 1];
    int c = threadIdx.x & 31, row = threadIdx.x >> 5;
    float s = 0.f;
    for (int n = beg + q * 8 + row; n < end; n += 32) s += o2[n * 32 + c];
    red[threadIdx.x] = s;
    __syncthreads();
    for (int rr = 4; rr >= 1; rr >>= 1) {
        if (row < rr) red[threadIdx.x] += red[(row + rr) * 32 + c];
        __syncthreads();
    }
    if (row == 0) atomicAdd(&pooled[g * 32 + c], red[c]);
}

// ---------------- K10: mean + final linear -> out[64][2]
__global__ void k_fin(const float* __restrict__ pooled, const int* __restrict__ lo,
                      const float* __restrict__ lw, const float* __restrict__ lb,
                      float* __restrict__ out) {
    int t = threadIdx.x;
    if (t >= 128) return;
    int g = t >> 1, o = t & 1;
    int cnt = lo[g + 1] - lo[g];
    float inv = 1.f / fmaxf((float)cnt, 1.f);
    float s = 0.f;
#pragma unroll
    for (int c = 0; c < 32; ++c) s += pooled[g * 32 + c] * lw[c * 2 + o];
    out[g * 2 + o] = s * inv + lb[o];
}

// ----------------------------------------------------------------------------
extern "C" void kernel_launch(void* const* d_in, const int* in_sizes, int n_in,
                              void* d_out, int out_size, void* d_ws, size_t ws_size,
                              hipStream_t stream) {
    const float* x   = (const float*)d_in[0];
    const int*   ei  = (const int*)d_in[1];     // [2][NE]
    const int*   bat = (const int*)d_in[2];
    const float* W1  = (const float*)d_in[3];
    const float* aS1 = (const float*)d_in[4];
    const float* aD1 = (const float*)d_in[5];
    const float* b1  = (const float*)d_in[6];
    const float* W2  = (const float*)d_in[7];
    const float* aS2 = (const float*)d_in[8];
    const float* aD2 = (const float*)d_in[9];
    const float* b2  = (const float*)d_in[10];
    const float* lw  = (const float*)d_in[11];
    const float* lb  = (const float*)d_in[12];
    float* out = (float*)d_out;

    const int* esrc = ei;
    const int* edst = ei + NE;

    char* ws = (char*)d_ws;
    size_t off = 0;
    auto alloc = [&](size_t bytes) -> void* {
        off = (off + 255) & ~(size_t)255;
        void* p = ws + off;
        off += bytes;
        return p;
    };

    float *regA, *h1, *h2, *o2, *h1p, *h1o, *as1, *ad1, *as2, *ad2, *Wt2, *pooled;
    int *offs, *deg, *csr, *bsum, *bpre, *lo, *bdeg, *bo, *bcur;
    uint2 *rec;

    int SPLIT = 8;
    for (int attempt = 0; attempt < 2; ++attempt) {
        off = 0;
        regA = (float*)alloc((size_t)NN * 64 * 4);   // h1; later reused: h2 @ 0, o2 @ NN*32
        h1   = regA;
        h2   = regA;                                  // alias (h1 dead after k_agg1)
        o2   = regA + (size_t)NN * 32;                // alias
        h1p  = (float*)alloc((size_t)SPLIT * NN * 64 * 4);  // split-K partials
        h1o  = (float*)alloc((size_t)NN * 64 * 4);
        as1  = (float*)alloc((size_t)NN * 8 * 4);
        ad1  = (float*)alloc((size_t)NN * 8 * 4);
        as2  = (float*)alloc((size_t)NN * 4);
        ad2  = (float*)alloc((size_t)NN * 4);
        offs = (int*)alloc((size_t)(NN + 1) * 4);
        deg  = (int*)alloc((size_t)NN * 4);
        csr  = (int*)alloc((size_t)ET * 4);
        rec  = (uint2*)alloc((size_t)ET * 8);
        bdeg = (int*)alloc((size_t)NB * 4);
        bo   = (int*)alloc((size_t)(NB + 1) * 4);
        bcur = (int*)alloc((size_t)NB * 4);
        Wt2  = (float*)alloc((size_t)512 * 64 * 4);
        bsum = (int*)alloc(256 * 4);
        bpre = (int*)alloc(256 * 4);
        pooled = (float*)alloc((size_t)NG * 32 * 4);
        lo   = (int*)alloc((size_t)(NG + 1) * 4);
        if (off <= ws_size) break;
        SPLIT = 4;                                   // shrink partials and retry
    }
    if (off > ws_size) return;   // workspace too small: leave d_out poisoned (visible failure)

    hipMemsetAsync(bdeg, 0, (size_t)NB * 4, stream);
    hipMemsetAsync(pooled, 0, (size_t)NG * 32 * 4, stream);

    k_wt<<<32, 256, 0, stream>>>(W1, Wt2);
    if (SPLIT == 8) {
        k_gemm1<8><<<8 * ((NN + 63) / 64), 256, 0, stream>>>(x, Wt2, h1p);
        k_comb<8><<<(NN * 16) / 256, 256, 0, stream>>>(h1p, aS1, aD1, h1, as1, ad1);
    } else {
        k_gemm1<4><<<4 * ((NN + 63) / 64), 256, 0, stream>>>(x, Wt2, h1p);
        k_comb<4><<<(NN * 16) / 256, 256, 0, stream>>>(h1p, aS1, aD1, h1, as1, ad1);
    }

    k_bhist<<<BIN_BLOCKS, 256, 0, stream>>>(edst, bdeg);
    k_bscan<<<1, 512, 0, stream>>>(bdeg, bo, bcur);
    k_bin<<<BIN_BLOCKS, 256, 0, stream>>>(esrc, edst, bcur, rec);
    k_bdeg<<<NB, 256, 0, stream>>>(bo, rec, deg);
    k_scan1<<<SCAN_BLOCKS, 256, 0, stream>>>(deg, offs, bsum);
    k_scan2<<<1, 256, 0, stream>>>(bsum, bpre);
    k_scan3<<<SCAN_BLOCKS, 256, 0, stream>>>(offs, bpre);
    k_unbin<<<NB, 256, 0, stream>>>(offs, bo, rec, csr);

    k_agg1<<<(NN + 3) / 4, 256, 0, stream>>>(offs, csr, h1, as1, ad1, b1, h1o);
    k_gemm2<<<(NN + 7) / 8, 256, 0, stream>>>(h1o, W2, aS2, aD2, h2, as2, ad2);
    k_agg2<<<(NN + 3) / 4, 256, 0, stream>>>(offs, csr, h2, as2, ad2, b2, o2);

    k_bound<<<SCAN_BLOCKS, 256, 0, stream>>>(bat, lo);
    k_pool<<<NG * 4, 256, 0, stream>>>(o2, lo, pooled);
    k_fin<<<1, 128, 0, stream>>>(pooled, lo, lw, lb, out);
}

// Round 12
// 273.517 us; speedup vs baseline: 2.3913x; 1.0007x over previous
//
#include <hip/hip_runtime.h>
#include <cstdint>
#include <cstddef>

#define NN 50000
#define NE 1600000
#define ET (NE + NN)          // edges + self loops
#define NG 64
#define SCAN_BLOCKS ((NN + 255) / 256)   // 196
#define NB ((NN + 127) >> 7)             // 391 dst-buckets, 128 nodes each
#define EPT 16
#define EPB (256 * EPT)                  // 4096 edges per bin-block
#define BIN_BLOCKS ((ET + EPB - 1) / EPB)

// ---------------- K0: transpose W1 [512][64] -> Wt2 k-packed float4
__global__ void k_wt(const float* __restrict__ W1, float* __restrict__ Wt2) {
    int id = blockIdx.x * 256 + threadIdx.x;
    if (id >= 128 * 64) return;
    int k4 = id >> 6, c = id & 63;
    float4 v;
    v.x = W1[(k4 * 4 + 0) * 64 + c];
    v.y = W1[(k4 * 4 + 1) * 64 + c];
    v.z = W1[(k4 * 4 + 2) * 64 + c];
    v.w = W1[(k4 * 4 + 3) * 64 + c];
    reinterpret_cast<float4*>(Wt2)[id] = v;
}

// ---------------- K1: h1 partials = x @ W1 (split-K = SPLIT), LDS-staged tile GEMM.
template<int SPLIT>
__global__ __launch_bounds__(256, 8) void k_gemm1(
    const float* __restrict__ x, const float* __restrict__ Wt2,
    float* __restrict__ h1p) {
    constexpr int K4 = 128 / SPLIT;
    constexpr int LK4 = (SPLIT == 8) ? 4 : ((SPLIT == 4) ? 5 : 6);
    __shared__ float4 xs[64 * K4];
    __shared__ float4 wsr[K4 * 64];

    int t = threadIdx.x;
    int lane = t & 63, wv_id = t >> 6;
    int part = blockIdx.x & (SPLIT - 1);
    int n0 = (blockIdx.x / SPLIT) * 64;
    int kb4 = part * K4;

    const float4* __restrict__ xf = reinterpret_cast<const float4*>(x);
    const float4* __restrict__ wf = reinterpret_cast<const float4*>(Wt2);

    constexpr int XPW = (64 * K4) / 64 / 4;
#pragma unroll
    for (int q = 0; q < XPW; ++q) {
        int base = (wv_id * XPW + q) * 64;
        int s = base + lane;
        int row = s >> LK4;
        int m = s & (K4 - 1);
        int k4f = m ^ ((row & 3) << 1);
        int rr = n0 + row; if (rr >= NN) rr = NN - 1;
        const float4* src = xf + (size_t)rr * 128 + kb4 + k4f;
        __builtin_amdgcn_global_load_lds(
            (const __attribute__((address_space(1))) void*)src,
            (__attribute__((address_space(3))) void*)&xs[base], 16, 0, 0);
    }
    constexpr int WPW = (K4 * 64) / 64 / 4;
#pragma unroll
    for (int q = 0; q < WPW; ++q) {
        int base = (wv_id * WPW + q) * 64;
        int s = base + lane;
        int k4 = s >> 6, c = s & 63;
        const float4* src = wf + (size_t)(kb4 + k4) * 64 + c;
        __builtin_amdgcn_global_load_lds(
            (const __attribute__((address_space(1))) void*)src,
            (__attribute__((address_space(3))) void*)&wsr[base], 16, 0, 0);
    }
    __syncthreads();

    int tc = t & 15;
    int trg = t >> 4;
    int swz = (trg & 3) << 1;

    float acc[4][4];
#pragma unroll
    for (int i = 0; i < 4; ++i)
#pragma unroll
        for (int j = 0; j < 4; ++j) acc[i][j] = 0.f;

#pragma unroll 2
    for (int k4 = 0; k4 < K4; ++k4) {
        float4 wv0 = wsr[k4 * 64 + tc];
        float4 wv1 = wsr[k4 * 64 + tc + 16];
        float4 wv2 = wsr[k4 * 64 + tc + 32];
        float4 wv3 = wsr[k4 * 64 + tc + 48];
        int kx = k4 ^ swz;
        float4 xv0 = xs[(trg +  0) * K4 + kx];
        float4 xv1 = xs[(trg + 16) * K4 + kx];
        float4 xv2 = xs[(trg + 32) * K4 + kx];
        float4 xv3 = xs[(trg + 48) * K4 + kx];
#define FMA4(a, xv, wv) { a += xv.x * wv.x; a += xv.y * wv.y; a += xv.z * wv.z; a += xv.w * wv.w; }
        FMA4(acc[0][0], xv0, wv0) FMA4(acc[0][1], xv0, wv1) FMA4(acc[0][2], xv0, wv2) FMA4(acc[0][3], xv0, wv3)
        FMA4(acc[1][0], xv1, wv0) FMA4(acc[1][1], xv1, wv1) FMA4(acc[1][2], xv1, wv2) FMA4(acc[1][3], xv1, wv3)
        FMA4(acc[2][0], xv2, wv0) FMA4(acc[2][1], xv2, wv1) FMA4(acc[2][2], xv2, wv2) FMA4(acc[2][3], xv2, wv3)
        FMA4(acc[3][0], xv3, wv0) FMA4(acc[3][1], xv3, wv1) FMA4(acc[3][2], xv3, wv2) FMA4(acc[3][3], xv3, wv3)
#undef FMA4
    }

    float* hp = h1p + (size_t)part * NN * 64;
#pragma unroll
    for (int i = 0; i < 4; ++i) {
        int r = n0 + trg + 16 * i;
        if (r >= NN) continue;
        float* rowp = hp + (size_t)r * 64 + tc;
        rowp[0]  = acc[i][0];
        rowp[16] = acc[i][1];
        rowp[32] = acc[i][2];
        rowp[48] = acc[i][3];
    }
}

// ---------------- K1b: combine split-K partials, store h1 + as1/ad1 epilogue.
template<int SPLIT>
__global__ __launch_bounds__(256) void k_comb(
    const float* __restrict__ h1p,
    const float* __restrict__ aS, const float* __restrict__ aD,
    float* __restrict__ h1, float* __restrict__ as1, float* __restrict__ ad1) {
    int id = blockIdx.x * 256 + threadIdx.x;   // grid sized exactly NN*16
    int r = id >> 4, tc = id & 15;
    const float4* p = reinterpret_cast<const float4*>(h1p);
    float4 v = p[id];
#pragma unroll
    for (int q = 1; q < SPLIT; ++q) {
        float4 b = p[(size_t)q * NN * 16 + id];
        v.x += b.x; v.y += b.y; v.z += b.z; v.w += b.w;
    }
    reinterpret_cast<float4*>(h1)[id] = v;
    int hh = tc >> 1, cb = (tc & 1) * 4;
    float ps = v.x * aS[hh * 8 + cb + 0] + v.y * aS[hh * 8 + cb + 1] +
               v.z * aS[hh * 8 + cb + 2] + v.w * aS[hh * 8 + cb + 3];
    float pd = v.x * aD[hh * 8 + cb + 0] + v.y * aD[hh * 8 + cb + 1] +
               v.z * aD[hh * 8 + cb + 2] + v.w * aD[hh * 8 + cb + 3];
    ps += __shfl_xor(ps, 1);
    pd += __shfl_xor(pd, 1);
    if ((tc & 1) == 0) { as1[r * 8 + hh] = ps; ad1[r * 8 + hh] = pd; }
}

// ---------------- CSR build: bhist -> bscan -> bin -> bdeg -> scan -> unbin
__global__ __launch_bounds__(256) void k_bhist(const int* __restrict__ edst, int* __restrict__ bdeg) {
    __shared__ int cnt[NB];
    int tid = threadIdx.x;
    for (int b = tid; b < NB; b += 256) cnt[b] = 0;
    __syncthreads();
    int e0 = blockIdx.x * EPB;
#pragma unroll
    for (int q = 0; q < EPT; ++q) {
        int e = e0 + q * 256 + tid;
        if (e < ET) {
            int d = (e < NE) ? edst[e] : (e - NE);
            atomicAdd(&cnt[d >> 7], 1);
        }
    }
    __syncthreads();
    for (int b = tid; b < NB; b += 256)
        if (cnt[b]) atomicAdd(&bdeg[b], cnt[b]);
}

__global__ __launch_bounds__(512) void k_bscan(const int* __restrict__ bdeg,
                                               int* __restrict__ bo, int* __restrict__ bcur) {
    __shared__ int lds_w[8];
    int tid = threadIdx.x;
    int lane = tid & 63, wid = tid >> 6;
    int v = (tid < NB) ? bdeg[tid] : 0;
    int incl = v;
#pragma unroll
    for (int ofs = 1; ofs < 64; ofs <<= 1) {
        int o = __shfl_up(incl, ofs);
        if (lane >= ofs) incl += o;
    }
    if (lane == 63) lds_w[wid] = incl;
    __syncthreads();
    int wadd = 0;
    for (int w = 0; w < wid; ++w) wadd += lds_w[w];
    incl += wadd;
    int ex = incl - v;
    if (tid < NB) { bo[tid] = ex; bcur[tid] = ex; }
    if (tid == NB - 1) bo[NB] = ex + v;   // == ET
}

__global__ __launch_bounds__(256) void k_bin(
    const int* __restrict__ esrc, const int* __restrict__ edst,
    int* __restrict__ bcur, uint2* __restrict__ rec) {
    __shared__ int bcnt[NB];
    int tid = threadIdx.x;
    for (int b = tid; b < NB; b += 256) bcnt[b] = 0;
    __syncthreads();
    int e0 = blockIdx.x * EPB;
    uint2 rv[EPT]; int rk[EPT];
#pragma unroll
    for (int q = 0; q < EPT; ++q) {
        int e = e0 + q * 256 + tid;
        rk[q] = -1;
        if (e < ET) {
            int s, d;
            if (e < NE) { s = esrc[e]; d = edst[e]; } else { s = d = e - NE; }
            rv[q] = make_uint2((unsigned)s, (unsigned)d);
            rk[q] = atomicAdd(&bcnt[d >> 7], 1);
        }
    }
    __syncthreads();
    for (int b = tid; b < NB; b += 256)
        bcnt[b] = atomicAdd(&bcur[b], bcnt[b]);
    __syncthreads();
#pragma unroll
    for (int q = 0; q < EPT; ++q) {
        if (rk[q] >= 0) rec[bcnt[rv[q].y >> 7] + rk[q]] = rv[q];
    }
}

__global__ __launch_bounds__(256) void k_bdeg(const int* __restrict__ bo, const uint2* __restrict__ rec,
                                              int* __restrict__ deg) {
    __shared__ int cnt[128];
    int b = blockIdx.x, tid = threadIdx.x;
    if (tid < 128) cnt[tid] = 0;
    __syncthreads();
    int lo = bo[b], hi = bo[b + 1];
    for (int i = lo + tid; i < hi; i += 256)
        atomicAdd(&cnt[rec[i].y & 127], 1);
    __syncthreads();
    if (tid < 128) {
        int n = (b << 7) + tid;
        if (n < NN) deg[n] = cnt[tid];
    }
}

__global__ __launch_bounds__(256) void k_scan1(const int* __restrict__ deg,
                                               int* __restrict__ offs, int* __restrict__ bsum) {
    __shared__ int lds_w[4];
    int i = blockIdx.x * 256 + threadIdx.x;
    int v = (i < NN) ? deg[i] : 0;
    int lane = threadIdx.x & 63, wid = threadIdx.x >> 6;
    int incl = v;
#pragma unroll
    for (int ofs = 1; ofs < 64; ofs <<= 1) {
        int o = __shfl_up(incl, ofs);
        if (lane >= ofs) incl += o;
    }
    if (lane == 63) lds_w[wid] = incl;
    __syncthreads();
    int wadd = 0;
    for (int w = 0; w < wid; ++w) wadd += lds_w[w];
    incl += wadd;
    if (i < NN) offs[i] = incl - v;
    if (threadIdx.x == 255) bsum[blockIdx.x] = incl;
}

__global__ void k_scan2(const int* __restrict__ bsum, int* __restrict__ bpre) {
    __shared__ int lds_w[4];
    int lane = threadIdx.x & 63, wid = threadIdx.x >> 6;
    int v = (threadIdx.x < SCAN_BLOCKS) ? bsum[threadIdx.x] : 0;
    int incl = v;
#pragma unroll
    for (int ofs = 1; ofs < 64; ofs <<= 1) {
        int o = __shfl_up(incl, ofs);
        if (lane >= ofs) incl += o;
    }
    if (lane == 63) lds_w[wid] = incl;
    __syncthreads();
    int wadd = 0;
    for (int w = 0; w < wid; ++w) wadd += lds_w[w];
    incl += wadd;
    bpre[threadIdx.x] = incl - v;
}

__global__ void k_scan3(int* __restrict__ offs, const int* __restrict__ bpre) {
    int i = blockIdx.x * 256 + threadIdx.x;
    if (i < NN) offs[i] = offs[i] + bpre[blockIdx.x];
    if (i == 0) offs[NN] = ET;
}

__global__ __launch_bounds__(256) void k_unbin(
    const int* __restrict__ offs, const int* __restrict__ bo,
    const uint2* __restrict__ rec, int* __restrict__ csr) {
    __shared__ int lcur[128];
    int b = blockIdx.x, tid = threadIdx.x;
    if (tid < 128) {
        int n = (b << 7) + tid;
        lcur[tid] = (n < NN) ? offs[n] : 0;
    }
    __syncthreads();
    int lo = bo[b], hi = bo[b + 1];
    for (int i = lo + tid; i < hi; i += 256) {
        uint2 r = rec[i];
        int pos = atomicAdd(&lcur[r.y & 127], 1);
        csr[pos] = (int)r.x;
    }
}

// ---------------- K4: layer-1 aggregation. Wave per dst; lane = (slot g = l>>4, f4 q = l&15).
// 16 edges/iter: 4 csr prefetch + 4 as1 + 4 h1-f4 gathers concurrently in flight.
__global__ __launch_bounds__(256) void k_agg1(
    const int* __restrict__ offs, const int* __restrict__ csr,
    const float* __restrict__ h1, const float* __restrict__ as1, const float* __restrict__ ad1,
    const float* __restrict__ bias1, float* __restrict__ h1o) {
    int l = threadIdx.x & 63;
    int dst = blockIdx.x * 4 + (threadIdx.x >> 6);
    if (dst >= NN) return;
    int g = l >> 4;            // edge slot 0..3
    int q = l & 15;            // float4 index in 64-ch row
    int h = q >> 1;            // head
    int beg = offs[dst], end = offs[dst + 1];
    int lastj = end - 1;       // deg >= 1 (self-loop)
    float adh = ad1[dst * 8 + h];
    const float4* __restrict__ h1f = reinterpret_cast<const float4*>(h1);

    float4 acc = make_float4(0.f, 0.f, 0.f, 0.f);
    float dsum = 0.f;

    int sA[4], sB[4];
#pragma unroll
    for (int p = 0; p < 4; ++p) sA[p] = csr[min(beg + p * 4 + g, lastj)];
    for (int j = beg; j < end; j += 16) {
#pragma unroll
        for (int p = 0; p < 4; ++p) sB[p] = csr[min(j + 16 + p * 4 + g, lastj)];
        float av[4]; float4 vv[4];
#pragma unroll
        for (int p = 0; p < 4; ++p) {
            av[p] = as1[sA[p] * 8 + h];
            vv[p] = h1f[sA[p] * 16 + q];
        }
#pragma unroll
        for (int p = 0; p < 4; ++p) {
            float e = av[p] + adh; e = (e > 0.f) ? e : 0.2f * e;
            float w = __expf(e);
            w = (j + p * 4 + g < end) ? w : 0.f;
            acc.x += w * vv[p].x; acc.y += w * vv[p].y;
            acc.z += w * vv[p].z; acc.w += w * vv[p].w;
            dsum += w;
        }
#pragma unroll
        for (int p = 0; p < 4; ++p) sA[p] = sB[p];
    }

#pragma unroll
    for (int ofs = 16; ofs <= 32; ofs <<= 1) {
        acc.x += __shfl_xor(acc.x, ofs);
        acc.y += __shfl_xor(acc.y, ofs);
        acc.z += __shfl_xor(acc.z, ofs);
        acc.w += __shfl_xor(acc.w, ofs);
        dsum  += __shfl_xor(dsum, ofs);
    }

    if (g == 0) {
        float inv = 1.f / (dsum + 1e-16f);
        const float4 bq = reinterpret_cast<const float4*>(bias1)[q];
        float4 r;
        r.x = acc.x * inv + bq.x;
        r.y = acc.y * inv + bq.y;
        r.z = acc.z * inv + bq.z;
        r.w = acc.w * inv + bq.w;
        r.x = (r.x > 0.f) ? r.x : (__expf(r.x) - 1.f);
        r.y = (r.y > 0.f) ? r.y : (__expf(r.y) - 1.f);
        r.z = (r.z > 0.f) ? r.z : (__expf(r.z) - 1.f);
        r.w = (r.w > 0.f) ? r.w : (__expf(r.w) - 1.f);
        reinterpret_cast<float4*>(h1o)[dst * 16 + q] = r;
    }
}

// ---------------- K6: h2 = h1o @ W2 (+ alpha2 reductions). 32 lanes per node.
__global__ __launch_bounds__(256) void k_gemm2(
    const float* __restrict__ h1o, const float* __restrict__ W2,
    const float* __restrict__ aS, const float* __restrict__ aD,
    float* __restrict__ h2, float* __restrict__ as2, float* __restrict__ ad2) {
    int c = threadIdx.x & 31;
    int n = blockIdx.x * 8 + (threadIdx.x >> 5);
    if (n >= NN) return;
    const float4* hf = reinterpret_cast<const float4*>(h1o + n * 64);
    float acc = 0.f;
#pragma unroll
    for (int k4 = 0; k4 < 16; ++k4) {
        float4 hv = hf[k4];
        acc += hv.x * W2[(k4 * 4 + 0) * 32 + c] + hv.y * W2[(k4 * 4 + 1) * 32 + c] +
               hv.z * W2[(k4 * 4 + 2) * 32 + c] + hv.w * W2[(k4 * 4 + 3) * 32 + c];
    }
    h2[n * 32 + c] = acc;
    float ps = acc * aS[c], pd = acc * aD[c];
#pragma unroll
    for (int o = 1; o < 32; o <<= 1) { ps += __shfl_xor(ps, o); pd += __shfl_xor(pd, o); }
    if (c == 0) { as2[n] = ps; ad2[n] = pd; }
}

// ---------------- K7: layer-2 aggregation. Wave per dst; lane = (slot g = l>>3, f4 q = l&7).
// 32 edges/iter: 4 csr prefetch + 4 as2 + 4 h2-f4 gathers concurrently in flight.
__global__ __launch_bounds__(256) void k_agg2(
    const int* __restrict__ offs, const int* __restrict__ csr,
    const float* __restrict__ h2, const float* __restrict__ as2, const float* __restrict__ ad2,
    const float* __restrict__ bias2, float* __restrict__ o2) {
    int l = threadIdx.x & 63;
    int dst = blockIdx.x * 4 + (threadIdx.x >> 6);
    if (dst >= NN) return;
    int g = l >> 3;            // edge slot 0..7
    int q = l & 7;             // float4 index in 32-ch row
    int beg = offs[dst], end = offs[dst + 1];
    int lastj = end - 1;
    float adh = ad2[dst];
    const float4* __restrict__ h2f = reinterpret_cast<const float4*>(h2);

    float4 acc = make_float4(0.f, 0.f, 0.f, 0.f);
    float dsum = 0.f;

    int sA[4], sB[4];
#pragma unroll
    for (int p = 0; p < 4; ++p) sA[p] = csr[min(beg + p * 8 + g, lastj)];
    for (int j = beg; j < end; j += 32) {
#pragma unroll
        for (int p = 0; p < 4; ++p) sB[p] = csr[min(j + 32 + p * 8 + g, lastj)];
        float av[4]; float4 vv[4];
#pragma unroll
        for (int p = 0; p < 4; ++p) {
            av[p] = as2[sA[p]];
            vv[p] = h2f[sA[p] * 8 + q];
        }
#pragma unroll
        for (int p = 0; p < 4; ++p) {
            float e = av[p] + adh; e = (e > 0.f) ? e : 0.2f * e;
            float w = __expf(e);
            w = (j + p * 8 + g < end) ? w : 0.f;
            acc.x += w * vv[p].x; acc.y += w * vv[p].y;
            acc.z += w * vv[p].z; acc.w += w * vv[p].w;
            dsum += w;
        }
#pragma unroll
        for (int p = 0; p < 4; ++p) sA[p] = sB[p];
    }

#pragma unroll
    for (int ofs = 8; ofs <= 32; ofs <<= 1) {
        acc.x += __shfl_xor(acc.x, ofs);
        acc.y += __shfl_xor(acc.y, ofs);
        acc.z += __shfl_xor(acc.z, ofs);
        acc.w += __shfl_xor(acc.w, ofs);
        dsum  += __shfl_xor(dsum, ofs);
    }

    if (g == 0) {
        float inv = 1.f / (dsum + 1e-16f);
        const float4 bq = reinterpret_cast<const float4*>(bias2)[q];
        float4 r;
        r.x = acc.x * inv + bq.x;
        r.y = acc.y * inv + bq.y;
        r.z = acc.z * inv + bq.z;
        r.w = acc.w * inv + bq.w;
        reinterpret_cast<float4*>(o2)[dst * 8 + q] = r;
    }
}

// ---------------- K8: graph boundaries from sorted batch.
__global__ void k_bound(const int* __restrict__ batch, int* __restrict__ lo) {
    int n = blockIdx.x * 256 + threadIdx.x;
    if (n >= NN) return;
    int b = batch[n];
    if (n == 0) {
        for (int g = 0; g <= b; ++g) lo[g] = 0;
    } else {
        int pb = batch[n - 1];
        for (int g = pb + 1; g <= b; ++g) lo[g] = n;
    }
    if (n == NN - 1) {
        for (int g = b + 1; g <= NG; ++g) lo[g] = NN;
    }
}

// ---------------- K9: pooled sums.
__global__ __launch_bounds__(256) void k_pool(const float* __restrict__ o2, const int* __restrict__ lo,
                                              float* __restrict__ pooled) {
    __shared__ float red[256];
    int g = blockIdx.x & 63, q = blockIdx.x >> 6;
    int beg = lo[g], end = lo[g + 1];
    int c = threadIdx.x & 31, row = threadIdx.x >> 5;
    float s = 0.f;
    for (int n = beg + q * 8 + row; n < end; n += 32) s += o2[n * 32 + c];
    red[threadIdx.x] = s;
    __syncthreads();
    for (int rr = 4; rr >= 1; rr >>= 1) {
        if (row < rr) red[threadIdx.x] += red[(row + rr) * 32 + c];
        __syncthreads();
    }
    if (row == 0) atomicAdd(&pooled[g * 32 + c], red[c]);
}

// ---------------- K10: mean + final linear -> out[64][2]
__global__ void k_fin(const float* __restrict__ pooled, const int* __restrict__ lo,
                      const float* __restrict__ lw, const float* __restrict__ lb,
                      float* __restrict__ out) {
    int t = threadIdx.x;
    if (t >= 128) return;
    int g = t >> 1, o = t & 1;
    int cnt = lo[g + 1] - lo[g];
    float inv = 1.f / fmaxf((float)cnt, 1.f);
    float s = 0.f;
#pragma unroll
    for (int c = 0; c < 32; ++c) s += pooled[g * 32 + c] * lw[c * 2 + o];
    out[g * 2 + o] = s * inv + lb[o];
}

// ----------------------------------------------------------------------------
extern "C" void kernel_launch(void* const* d_in, const int* in_sizes, int n_in,
                              void* d_out, int out_size, void* d_ws, size_t ws_size,
                              hipStream_t stream) {
    const float* x   = (const float*)d_in[0];
    const int*   ei  = (const int*)d_in[1];     // [2][NE]
    const int*   bat = (const int*)d_in[2];
    const float* W1  = (const float*)d_in[3];
    const float* aS1 = (const float*)d_in[4];
    const float* aD1 = (const float*)d_in[5];
    const float* b1  = (const float*)d_in[6];
    const float* W2  = (const float*)d_in[7];
    const float* aS2 = (const float*)d_in[8];
    const float* aD2 = (const float*)d_in[9];
    const float* b2  = (const float*)d_in[10];
    const float* lw  = (const float*)d_in[11];
    const float* lb  = (const float*)d_in[12];
    float* out = (float*)d_out;

    const int* esrc = ei;
    const int* edst = ei + NE;

    char* ws = (char*)d_ws;
    size_t off = 0;
    auto alloc = [&](size_t bytes) -> void* {
        off = (off + 255) & ~(size_t)255;
        void* p = ws + off;
        off += bytes;
        return p;
    };

    float *regA, *h1, *h2, *o2, *h1p, *h1o, *as1, *ad1, *as2, *ad2, *Wt2, *pooled;
    int *offs, *deg, *csr, *bsum, *bpre, *lo, *bdeg, *bo, *bcur;
    uint2 *rec;

    int SPLIT = 8;
    for (int attempt = 0; attempt < 2; ++attempt) {
        off = 0;
        regA = (float*)alloc((size_t)NN * 64 * 4);   // h1; later reused: h2 @ 0, o2 @ NN*32
        h1   = regA;
        h2   = regA;                                  // alias (h1 dead after k_agg1)
        o2   = regA + (size_t)NN * 32;                // alias
        h1p  = (float*)alloc((size_t)SPLIT * NN * 64 * 4);  // split-K partials
        h1o  = (float*)alloc((size_t)NN * 64 * 4);
        as1  = (float*)alloc((size_t)NN * 8 * 4);
        ad1  = (float*)alloc((size_t)NN * 8 * 4);
        as2  = (float*)alloc((size_t)NN * 4);
        ad2  = (float*)alloc((size_t)NN * 4);
        offs = (int*)alloc((size_t)(NN + 1) * 4);
        deg  = (int*)alloc((size_t)NN * 4);
        csr  = (int*)alloc((size_t)ET * 4);
        rec  = (uint2*)alloc((size_t)ET * 8);
        bdeg = (int*)alloc((size_t)NB * 4);
        bo   = (int*)alloc((size_t)(NB + 1) * 4);
        bcur = (int*)alloc((size_t)NB * 4);
        Wt2  = (float*)alloc((size_t)512 * 64 * 4);
        bsum = (int*)alloc(256 * 4);
        bpre = (int*)alloc(256 * 4);
        pooled = (float*)alloc((size_t)NG * 32 * 4);
        lo   = (int*)alloc((size_t)(NG + 1) * 4);
        if (off <= ws_size) break;
        SPLIT = 4;                                   // shrink partials and retry
    }
    if (off > ws_size) return;   // workspace too small: leave d_out poisoned (visible failure)

    hipMemsetAsync(bdeg, 0, (size_t)NB * 4, stream);
    hipMemsetAsync(pooled, 0, (size_t)NG * 32 * 4, stream);

    k_wt<<<32, 256, 0, stream>>>(W1, Wt2);
    if (SPLIT == 8) {
        k_gemm1<8><<<8 * ((NN + 63) / 64), 256, 0, stream>>>(x, Wt2, h1p);
        k_comb<8><<<(NN * 16) / 256, 256, 0, stream>>>(h1p, aS1, aD1, h1, as1, ad1);
    } else {
        k_gemm1<4><<<4 * ((NN + 63) / 64), 256, 0, stream>>>(x, Wt2, h1p);
        k_comb<4><<<(NN * 16) / 256, 256, 0, stream>>>(h1p, aS1, aD1, h1, as1, ad1);
    }

    k_bhist<<<BIN_BLOCKS, 256, 0, stream>>>(edst, bdeg);
    k_bscan<<<1, 512, 0, stream>>>(bdeg, bo, bcur);
    k_bin<<<BIN_BLOCKS, 256, 0, stream>>>(esrc, edst, bcur, rec);
    k_bdeg<<<NB, 256, 0, stream>>>(bo, rec, deg);
    k_scan1<<<SCAN_BLOCKS, 256, 0, stream>>>(deg, offs, bsum);
    k_scan2<<<1, 256, 0, stream>>>(bsum, bpre);
    k_scan3<<<SCAN_BLOCKS, 256, 0, stream>>>(offs, bpre);
    k_unbin<<<NB, 256, 0, stream>>>(offs, bo, rec, csr);

    k_agg1<<<(NN + 3) / 4, 256, 0, stream>>>(offs, csr, h1, as1, ad1, b1, h1o);
    k_gemm2<<<(NN + 7) / 8, 256, 0, stream>>>(h1o, W2, aS2, aD2, h2, as2, ad2);
    k_agg2<<<(NN + 3) / 4, 256, 0, stream>>>(offs, csr, h2, as2, ad2, b2, o2);

    k_bound<<<SCAN_BLOCKS, 256, 0, stream>>>(bat, lo);
    k_pool<<<NG * 4, 256, 0, stream>>>(o2, lo, pooled);
    k_fin<<<1, 128, 0, stream>>>(pooled, lo, lw, lb, out);
}

// Round 13
// 266.936 us; speedup vs baseline: 2.4502x; 1.0247x over previous
//
#include <hip/hip_runtime.h>
#include <cstdint>
#include <cstddef>

#define NN 50000
#define NE 1600000
#define ET (NE + NN)          // edges + self loops
#define NG 64
#define SCAN_BLOCKS ((NN + 255) / 256)   // 196
#define NB ((NN + 127) >> 7)             // 391 dst-buckets, 128 nodes each
#define EPT 16
#define EPB (256 * EPT)                  // 4096 edges per bin-block
#define BIN_BLOCKS ((ET + EPB - 1) / EPB)

// ---------------- K0: transpose W1 [512][64] -> Wt2 k-packed float4
__global__ void k_wt(const float* __restrict__ W1, float* __restrict__ Wt2) {
    int id = blockIdx.x * 256 + threadIdx.x;
    if (id >= 128 * 64) return;
    int k4 = id >> 6, c = id & 63;
    float4 v;
    v.x = W1[(k4 * 4 + 0) * 64 + c];
    v.y = W1[(k4 * 4 + 1) * 64 + c];
    v.z = W1[(k4 * 4 + 2) * 64 + c];
    v.w = W1[(k4 * 4 + 3) * 64 + c];
    reinterpret_cast<float4*>(Wt2)[id] = v;
}

// ---------------- K1: h1 = x @ W1, full-K per block, LDS-staged in 8 phases.
// 64 rows/block; per phase stage 16 k4-groups of x (swizzled) + W (linear), then FMA.
__global__ __launch_bounds__(256, 8) void k_gemm1(
    const float* __restrict__ x, const float* __restrict__ Wt2,
    float* __restrict__ h1) {
    __shared__ float4 xs[64 * 16];    // 16 KB
    __shared__ float4 wsr[16 * 64];   // 16 KB

    int t = threadIdx.x;
    int lane = t & 63, wv_id = t >> 6;
    int n0 = blockIdx.x * 64;

    const float4* __restrict__ xf = reinterpret_cast<const float4*>(x);
    const float4* __restrict__ wf = reinterpret_cast<const float4*>(Wt2);

    int tc = t & 15;
    int trg = t >> 4;
    int swz = (trg & 3) << 1;

    float acc[4][4];
#pragma unroll
    for (int i = 0; i < 4; ++i)
#pragma unroll
        for (int j = 0; j < 4; ++j) acc[i][j] = 0.f;

    for (int ph = 0; ph < 8; ++ph) {
        int kb4 = ph * 16;
        // stage x: 1024 slots; swizzled source, linear LDS dest (rule #21)
#pragma unroll
        for (int q = 0; q < 4; ++q) {
            int base = (wv_id * 4 + q) * 64;
            int s = base + lane;
            int row = s >> 4;
            int m = s & 15;
            int k4f = m ^ ((row & 3) << 1);
            int rr = n0 + row; if (rr >= NN) rr = NN - 1;
            const float4* src = xf + (size_t)rr * 128 + kb4 + k4f;
            __builtin_amdgcn_global_load_lds(
                (const __attribute__((address_space(1))) void*)src,
                (__attribute__((address_space(3))) void*)&xs[base], 16, 0, 0);
        }
        // stage W: 1024 slots, linear
#pragma unroll
        for (int q = 0; q < 4; ++q) {
            int base = (wv_id * 4 + q) * 64;
            int s = base + lane;
            int k4 = s >> 6, c = s & 63;
            const float4* src = wf + (size_t)(kb4 + k4) * 64 + c;
            __builtin_amdgcn_global_load_lds(
                (const __attribute__((address_space(1))) void*)src,
                (__attribute__((address_space(3))) void*)&wsr[base], 16, 0, 0);
        }
        __syncthreads();

#pragma unroll 2
        for (int k4 = 0; k4 < 16; ++k4) {
            float4 wv0 = wsr[k4 * 64 + tc];
            float4 wv1 = wsr[k4 * 64 + tc + 16];
            float4 wv2 = wsr[k4 * 64 + tc + 32];
            float4 wv3 = wsr[k4 * 64 + tc + 48];
            int kx = k4 ^ swz;
            float4 xv0 = xs[(trg +  0) * 16 + kx];
            float4 xv1 = xs[(trg + 16) * 16 + kx];
            float4 xv2 = xs[(trg + 32) * 16 + kx];
            float4 xv3 = xs[(trg + 48) * 16 + kx];
#define FMA4(a, xv, wv) { a += xv.x * wv.x; a += xv.y * wv.y; a += xv.z * wv.z; a += xv.w * wv.w; }
            FMA4(acc[0][0], xv0, wv0) FMA4(acc[0][1], xv0, wv1) FMA4(acc[0][2], xv0, wv2) FMA4(acc[0][3], xv0, wv3)
            FMA4(acc[1][0], xv1, wv0) FMA4(acc[1][1], xv1, wv1) FMA4(acc[1][2], xv1, wv2) FMA4(acc[1][3], xv1, wv3)
            FMA4(acc[2][0], xv2, wv0) FMA4(acc[2][1], xv2, wv1) FMA4(acc[2][2], xv2, wv2) FMA4(acc[2][3], xv2, wv3)
            FMA4(acc[3][0], xv3, wv0) FMA4(acc[3][1], xv3, wv1) FMA4(acc[3][2], xv3, wv2) FMA4(acc[3][3], xv3, wv3)
#undef FMA4
        }
        __syncthreads();   // protect LDS before next phase's staging
    }

    // store h1: thread's cols are {tc + 16j}; lanes tc=0..15 coalesce 64B runs
#pragma unroll
    for (int i = 0; i < 4; ++i) {
        int r = n0 + trg + 16 * i;
        if (r >= NN) continue;
        float* rowp = h1 + (size_t)r * 64 + tc;
        rowp[0]  = acc[i][0];
        rowp[16] = acc[i][1];
        rowp[32] = acc[i][2];
        rowp[48] = acc[i][3];
    }
}

// ---------------- K1b: as1/ad1 epilogue from h1 (L3-warm read).
__global__ __launch_bounds__(256) void k_asad(
    const float* __restrict__ h1,
    const float* __restrict__ aS, const float* __restrict__ aD,
    float* __restrict__ as1, float* __restrict__ ad1) {
    int id = blockIdx.x * 256 + threadIdx.x;   // grid sized exactly NN*16
    int r = id >> 4, tc = id & 15;
    float4 v = reinterpret_cast<const float4*>(h1)[id];
    int hh = tc >> 1, cb = (tc & 1) * 4;
    float ps = v.x * aS[hh * 8 + cb + 0] + v.y * aS[hh * 8 + cb + 1] +
               v.z * aS[hh * 8 + cb + 2] + v.w * aS[hh * 8 + cb + 3];
    float pd = v.x * aD[hh * 8 + cb + 0] + v.y * aD[hh * 8 + cb + 1] +
               v.z * aD[hh * 8 + cb + 2] + v.w * aD[hh * 8 + cb + 3];
    ps += __shfl_xor(ps, 1);
    pd += __shfl_xor(pd, 1);
    if ((tc & 1) == 0) { as1[r * 8 + hh] = ps; ad1[r * 8 + hh] = pd; }
}

// ---------------- CSR build: bhist -> bscan -> bin -> bdeg -> scan -> unbin
__global__ __launch_bounds__(256) void k_bhist(const int* __restrict__ edst, int* __restrict__ bdeg) {
    __shared__ int cnt[NB];
    int tid = threadIdx.x;
    for (int b = tid; b < NB; b += 256) cnt[b] = 0;
    __syncthreads();
    int e0 = blockIdx.x * EPB;
#pragma unroll
    for (int q = 0; q < EPT; ++q) {
        int e = e0 + q * 256 + tid;
        if (e < ET) {
            int d = (e < NE) ? edst[e] : (e - NE);
            atomicAdd(&cnt[d >> 7], 1);
        }
    }
    __syncthreads();
    for (int b = tid; b < NB; b += 256)
        if (cnt[b]) atomicAdd(&bdeg[b], cnt[b]);
}

__global__ __launch_bounds__(512) void k_bscan(const int* __restrict__ bdeg,
                                               int* __restrict__ bo, int* __restrict__ bcur) {
    __shared__ int lds_w[8];
    int tid = threadIdx.x;
    int lane = tid & 63, wid = tid >> 6;
    int v = (tid < NB) ? bdeg[tid] : 0;
    int incl = v;
#pragma unroll
    for (int ofs = 1; ofs < 64; ofs <<= 1) {
        int o = __shfl_up(incl, ofs);
        if (lane >= ofs) incl += o;
    }
    if (lane == 63) lds_w[wid] = incl;
    __syncthreads();
    int wadd = 0;
    for (int w = 0; w < wid; ++w) wadd += lds_w[w];
    incl += wadd;
    int ex = incl - v;
    if (tid < NB) { bo[tid] = ex; bcur[tid] = ex; }
    if (tid == NB - 1) bo[NB] = ex + v;   // == ET
}

__global__ __launch_bounds__(256) void k_bin(
    const int* __restrict__ esrc, const int* __restrict__ edst,
    int* __restrict__ bcur, uint2* __restrict__ rec) {
    __shared__ int bcnt[NB];
    int tid = threadIdx.x;
    for (int b = tid; b < NB; b += 256) bcnt[b] = 0;
    __syncthreads();
    int e0 = blockIdx.x * EPB;
    uint2 rv[EPT]; int rk[EPT];
#pragma unroll
    for (int q = 0; q < EPT; ++q) {
        int e = e0 + q * 256 + tid;
        rk[q] = -1;
        if (e < ET) {
            int s, d;
            if (e < NE) { s = esrc[e]; d = edst[e]; } else { s = d = e - NE; }
            rv[q] = make_uint2((unsigned)s, (unsigned)d);
            rk[q] = atomicAdd(&bcnt[d >> 7], 1);
        }
    }
    __syncthreads();
    for (int b = tid; b < NB; b += 256)
        bcnt[b] = atomicAdd(&bcur[b], bcnt[b]);
    __syncthreads();
#pragma unroll
    for (int q = 0; q < EPT; ++q) {
        if (rk[q] >= 0) rec[bcnt[rv[q].y >> 7] + rk[q]] = rv[q];
    }
}

__global__ __launch_bounds__(256) void k_bdeg(const int* __restrict__ bo, const uint2* __restrict__ rec,
                                              int* __restrict__ deg) {
    __shared__ int cnt[128];
    int b = blockIdx.x, tid = threadIdx.x;
    if (tid < 128) cnt[tid] = 0;
    __syncthreads();
    int lo = bo[b], hi = bo[b + 1];
    for (int i = lo + tid; i < hi; i += 256)
        atomicAdd(&cnt[rec[i].y & 127], 1);
    __syncthreads();
    if (tid < 128) {
        int n = (b << 7) + tid;
        if (n < NN) deg[n] = cnt[tid];
    }
}

__global__ __launch_bounds__(256) void k_scan1(const int* __restrict__ deg,
                                               int* __restrict__ offs, int* __restrict__ bsum) {
    __shared__ int lds_w[4];
    int i = blockIdx.x * 256 + threadIdx.x;
    int v = (i < NN) ? deg[i] : 0;
    int lane = threadIdx.x & 63, wid = threadIdx.x >> 6;
    int incl = v;
#pragma unroll
    for (int ofs = 1; ofs < 64; ofs <<= 1) {
        int o = __shfl_up(incl, ofs);
        if (lane >= ofs) incl += o;
    }
    if (lane == 63) lds_w[wid] = incl;
    __syncthreads();
    int wadd = 0;
    for (int w = 0; w < wid; ++w) wadd += lds_w[w];
    incl += wadd;
    if (i < NN) offs[i] = incl - v;
    if (threadIdx.x == 255) bsum[blockIdx.x] = incl;
}

__global__ void k_scan2(const int* __restrict__ bsum, int* __restrict__ bpre) {
    __shared__ int lds_w[4];
    int lane = threadIdx.x & 63, wid = threadIdx.x >> 6;
    int v = (threadIdx.x < SCAN_BLOCKS) ? bsum[threadIdx.x] : 0;
    int incl = v;
#pragma unroll
    for (int ofs = 1; ofs < 64; ofs <<= 1) {
        int o = __shfl_up(incl, ofs);
        if (lane >= ofs) incl += o;
    }
    if (lane == 63) lds_w[wid] = incl;
    __syncthreads();
    int wadd = 0;
    for (int w = 0; w < wid; ++w) wadd += lds_w[w];
    incl += wadd;
    bpre[threadIdx.x] = incl - v;
}

__global__ void k_scan3(int* __restrict__ offs, const int* __restrict__ bpre) {
    int i = blockIdx.x * 256 + threadIdx.x;
    if (i < NN) offs[i] = offs[i] + bpre[blockIdx.x];
    if (i == 0) offs[NN] = ET;
}

__global__ __launch_bounds__(256) void k_unbin(
    const int* __restrict__ offs, const int* __restrict__ bo,
    const uint2* __restrict__ rec, int* __restrict__ csr) {
    __shared__ int lcur[128];
    int b = blockIdx.x, tid = threadIdx.x;
    if (tid < 128) {
        int n = (b << 7) + tid;
        lcur[tid] = (n < NN) ? offs[n] : 0;
    }
    __syncthreads();
    int lo = bo[b], hi = bo[b + 1];
    for (int i = lo + tid; i < hi; i += 256) {
        uint2 r = rec[i];
        int pos = atomicAdd(&lcur[r.y & 127], 1);
        csr[pos] = (int)r.x;
    }
}

// ---------------- K4: layer-1 aggregation. Wave per dst; lane = (slot g = l>>4, f4 q = l&15).
__global__ __launch_bounds__(256) void k_agg1(
    const int* __restrict__ offs, const int* __restrict__ csr,
    const float* __restrict__ h1, const float* __restrict__ as1, const float* __restrict__ ad1,
    const float* __restrict__ bias1, float* __restrict__ h1o) {
    int l = threadIdx.x & 63;
    int dst = blockIdx.x * 4 + (threadIdx.x >> 6);
    if (dst >= NN) return;
    int g = l >> 4;            // edge slot 0..3
    int q = l & 15;            // float4 index in 64-ch row
    int h = q >> 1;            // head
    int beg = offs[dst], end = offs[dst + 1];
    int lastj = end - 1;       // deg >= 1 (self-loop)
    float adh = ad1[dst * 8 + h];
    const float4* __restrict__ h1f = reinterpret_cast<const float4*>(h1);

    float4 acc = make_float4(0.f, 0.f, 0.f, 0.f);
    float dsum = 0.f;

    int sA[4], sB[4];
#pragma unroll
    for (int p = 0; p < 4; ++p) sA[p] = csr[min(beg + p * 4 + g, lastj)];
    for (int j = beg; j < end; j += 16) {
#pragma unroll
        for (int p = 0; p < 4; ++p) sB[p] = csr[min(j + 16 + p * 4 + g, lastj)];
        float av[4]; float4 vv[4];
#pragma unroll
        for (int p = 0; p < 4; ++p) {
            av[p] = as1[sA[p] * 8 + h];
            vv[p] = h1f[sA[p] * 16 + q];
        }
#pragma unroll
        for (int p = 0; p < 4; ++p) {
            float e = av[p] + adh; e = (e > 0.f) ? e : 0.2f * e;
            float w = __expf(e);
            w = (j + p * 4 + g < end) ? w : 0.f;
            acc.x += w * vv[p].x; acc.y += w * vv[p].y;
            acc.z += w * vv[p].z; acc.w += w * vv[p].w;
            dsum += w;
        }
#pragma unroll
        for (int p = 0; p < 4; ++p) sA[p] = sB[p];
    }

#pragma unroll
    for (int ofs = 16; ofs <= 32; ofs <<= 1) {
        acc.x += __shfl_xor(acc.x, ofs);
        acc.y += __shfl_xor(acc.y, ofs);
        acc.z += __shfl_xor(acc.z, ofs);
        acc.w += __shfl_xor(acc.w, ofs);
        dsum  += __shfl_xor(dsum, ofs);
    }

    if (g == 0) {
        float inv = 1.f / (dsum + 1e-16f);
        const float4 bq = reinterpret_cast<const float4*>(bias1)[q];
        float4 r;
        r.x = acc.x * inv + bq.x;
        r.y = acc.y * inv + bq.y;
        r.z = acc.z * inv + bq.z;
        r.w = acc.w * inv + bq.w;
        r.x = (r.x > 0.f) ? r.x : (__expf(r.x) - 1.f);
        r.y = (r.y > 0.f) ? r.y : (__expf(r.y) - 1.f);
        r.z = (r.z > 0.f) ? r.z : (__expf(r.z) - 1.f);
        r.w = (r.w > 0.f) ? r.w : (__expf(r.w) - 1.f);
        reinterpret_cast<float4*>(h1o)[dst * 16 + q] = r;
    }
}

// ---------------- K6: h2 = h1o @ W2 (+ alpha2 reductions). 32 lanes per node.
__global__ __launch_bounds__(256) void k_gemm2(
    const float* __restrict__ h1o, const float* __restrict__ W2,
    const float* __restrict__ aS, const float* __restrict__ aD,
    float* __restrict__ h2, float* __restrict__ as2, float* __restrict__ ad2) {
    int c = threadIdx.x & 31;
    int n = blockIdx.x * 8 + (threadIdx.x >> 5);
    if (n >= NN) return;
    const float4* hf = reinterpret_cast<const float4*>(h1o + n * 64);
    float acc = 0.f;
#pragma unroll
    for (int k4 = 0; k4 < 16; ++k4) {
        float4 hv = hf[k4];
        acc += hv.x * W2[(k4 * 4 + 0) * 32 + c] + hv.y * W2[(k4 * 4 + 1) * 32 + c] +
               hv.z * W2[(k4 * 4 + 2) * 32 + c] + hv.w * W2[(k4 * 4 + 3) * 32 + c];
    }
    h2[n * 32 + c] = acc;
    float ps = acc * aS[c], pd = acc * aD[c];
#pragma unroll
    for (int o = 1; o < 32; o <<= 1) { ps += __shfl_xor(ps, o); pd += __shfl_xor(pd, o); }
    if (c == 0) { as2[n] = ps; ad2[n] = pd; }
}

// ---------------- K7: layer-2 aggregation. Wave per dst; lane = (slot g = l>>3, f4 q = l&7).
__global__ __launch_bounds__(256) void k_agg2(
    const int* __restrict__ offs, const int* __restrict__ csr,
    const float* __restrict__ h2, const float* __restrict__ as2, const float* __restrict__ ad2,
    const float* __restrict__ bias2, float* __restrict__ o2) {
    int l = threadIdx.x & 63;
    int dst = blockIdx.x * 4 + (threadIdx.x >> 6);
    if (dst >= NN) return;
    int g = l >> 3;            // edge slot 0..7
    int q = l & 7;             // float4 index in 32-ch row
    int beg = offs[dst], end = offs[dst + 1];
    int lastj = end - 1;
    float adh = ad2[dst];
    const float4* __restrict__ h2f = reinterpret_cast<const float4*>(h2);

    float4 acc = make_float4(0.f, 0.f, 0.f, 0.f);
    float dsum = 0.f;

    int sA[4], sB[4];
#pragma unroll
    for (int p = 0; p < 4; ++p) sA[p] = csr[min(beg + p * 8 + g, lastj)];
    for (int j = beg; j < end; j += 32) {
#pragma unroll
        for (int p = 0; p < 4; ++p) sB[p] = csr[min(j + 32 + p * 8 + g, lastj)];
        float av[4]; float4 vv[4];
#pragma unroll
        for (int p = 0; p < 4; ++p) {
            av[p] = as2[sA[p]];
            vv[p] = h2f[sA[p] * 8 + q];
        }
#pragma unroll
        for (int p = 0; p < 4; ++p) {
            float e = av[p] + adh; e = (e > 0.f) ? e : 0.2f * e;
            float w = __expf(e);
            w = (j + p * 8 + g < end) ? w : 0.f;
            acc.x += w * vv[p].x; acc.y += w * vv[p].y;
            acc.z += w * vv[p].z; acc.w += w * vv[p].w;
            dsum += w;
        }
#pragma unroll
        for (int p = 0; p < 4; ++p) sA[p] = sB[p];
    }

#pragma unroll
    for (int ofs = 8; ofs <= 32; ofs <<= 1) {
        acc.x += __shfl_xor(acc.x, ofs);
        acc.y += __shfl_xor(acc.y, ofs);
        acc.z += __shfl_xor(acc.z, ofs);
        acc.w += __shfl_xor(acc.w, ofs);
        dsum  += __shfl_xor(dsum, ofs);
    }

    if (g == 0) {
        float inv = 1.f / (dsum + 1e-16f);
        const float4 bq = reinterpret_cast<const float4*>(bias2)[q];
        float4 r;
        r.x = acc.x * inv + bq.x;
        r.y = acc.y * inv + bq.y;
        r.z = acc.z * inv + bq.z;
        r.w = acc.w * inv + bq.w;
        reinterpret_cast<float4*>(o2)[dst * 8 + q] = r;
    }
}

// ---------------- K8: graph boundaries from sorted batch.
__global__ void k_bound(const int* __restrict__ batch, int* __restrict__ lo) {
    int n = blockIdx.x * 256 + threadIdx.x;
    if (n >= NN) return;
    int b = batch[n];
    if (n == 0) {
        for (int g = 0; g <= b; ++g) lo[g] = 0;
    } else {
        int pb = batch[n - 1];
        for (int g = pb + 1; g <= b; ++g) lo[g] = n;
    }
    if (n == NN - 1) {
        for (int g = b + 1; g <= NG; ++g) lo[g] = NN;
    }
}

// ---------------- K9: pooled sums.
__global__ __launch_bounds__(256) void k_pool(const float* __restrict__ o2, const int* __restrict__ lo,
                                              float* __restrict__ pooled) {
    __shared__ float red[256];
    int g = blockIdx.x & 63, q = blockIdx.x >> 6;
    int beg = lo[g], end = lo[g + 1];
    int c = threadIdx.x & 31, row = threadIdx.x >> 5;
    float s = 0.f;
    for (int n = beg + q * 8 + row; n < end; n += 32) s += o2[n * 32 + c];
    red[threadIdx.x] = s;
    __syncthreads();
    for (int rr = 4; rr >= 1; rr >>= 1) {
        if (row < rr) red[threadIdx.x] += red[(row + rr) * 32 + c];
        __syncthreads();
    }
    if (row == 0) atomicAdd(&pooled[g * 32 + c], red[c]);
}

// ---------------- K10: mean + final linear -> out[64][2]
__global__ void k_fin(const float* __restrict__ pooled, const int* __restrict__ lo,
                      const float* __restrict__ lw, const float* __restrict__ lb,
                      float* __restrict__ out) {
    int t = threadIdx.x;
    if (t >= 128) return;
    int g = t >> 1, o = t & 1;
    int cnt = lo[g + 1] - lo[g];
    float inv = 1.f / fmaxf((float)cnt, 1.f);
    float s = 0.f;
#pragma unroll
    for (int c = 0; c < 32; ++c) s += pooled[g * 32 + c] * lw[c * 2 + o];
    out[g * 2 + o] = s * inv + lb[o];
}

// ----------------------------------------------------------------------------
extern "C" void kernel_launch(void* const* d_in, const int* in_sizes, int n_in,
                              void* d_out, int out_size, void* d_ws, size_t ws_size,
                              hipStream_t stream) {
    const float* x   = (const float*)d_in[0];
    const int*   ei  = (const int*)d_in[1];     // [2][NE]
    const int*   bat = (const int*)d_in[2];
    const float* W1  = (const float*)d_in[3];
    const float* aS1 = (const float*)d_in[4];
    const float* aD1 = (const float*)d_in[5];
    const float* b1  = (const float*)d_in[6];
    const float* W2  = (const float*)d_in[7];
    const float* aS2 = (const float*)d_in[8];
    const float* aD2 = (const float*)d_in[9];
    const float* b2  = (const float*)d_in[10];
    const float* lw  = (const float*)d_in[11];
    const float* lb  = (const float*)d_in[12];
    float* out = (float*)d_out;

    const int* esrc = ei;
    const int* edst = ei + NE;

    char* ws = (char*)d_ws;
    size_t off = 0;
    auto alloc = [&](size_t bytes) -> void* {
        off = (off + 255) & ~(size_t)255;
        void* p = ws + off;
        off += bytes;
        return p;
    };

    float* regA = (float*)alloc((size_t)NN * 64 * 4);   // h1; later reused: h2 @ 0, o2 @ NN*32
    float* h1   = regA;
    float* h2   = regA;                                  // alias (h1 dead after k_agg1)
    float* o2   = regA + (size_t)NN * 32;                // alias
    float* h1o  = (float*)alloc((size_t)NN * 64 * 4);
    float* as1  = (float*)alloc((size_t)NN * 8 * 4);
    float* ad1  = (float*)alloc((size_t)NN * 8 * 4);
    float* as2  = (float*)alloc((size_t)NN * 4);
    float* ad2  = (float*)alloc((size_t)NN * 4);
    int*   offs = (int*)alloc((size_t)(NN + 1) * 4);
    int*   deg  = (int*)alloc((size_t)NN * 4);
    int*   csr  = (int*)alloc((size_t)ET * 4);
    uint2* rec  = (uint2*)alloc((size_t)ET * 8);
    int*   bdeg = (int*)alloc((size_t)NB * 4);
    int*   bo   = (int*)alloc((size_t)(NB + 1) * 4);
    int*   bcur = (int*)alloc((size_t)NB * 4);
    float* Wt2  = (float*)alloc((size_t)512 * 64 * 4);
    int*   bsum = (int*)alloc(256 * 4);
    int*   bpre = (int*)alloc(256 * 4);
    float* pooled = (float*)alloc((size_t)NG * 32 * 4);
    int*   lo   = (int*)alloc((size_t)(NG + 1) * 4);
    if (off > ws_size) return;   // workspace too small: leave d_out poisoned (visible failure)

    hipMemsetAsync(bdeg, 0, (size_t)NB * 4, stream);
    hipMemsetAsync(pooled, 0, (size_t)NG * 32 * 4, stream);

    k_wt<<<32, 256, 0, stream>>>(W1, Wt2);
    k_gemm1<<<(NN + 63) / 64, 256, 0, stream>>>(x, Wt2, h1);
    k_asad<<<(NN * 16) / 256, 256, 0, stream>>>(h1, aS1, aD1, as1, ad1);

    k_bhist<<<BIN_BLOCKS, 256, 0, stream>>>(edst, bdeg);
    k_bscan<<<1, 512, 0, stream>>>(bdeg, bo, bcur);
    k_bin<<<BIN_BLOCKS, 256, 0, stream>>>(esrc, edst, bcur, rec);
    k_bdeg<<<NB, 256, 0, stream>>>(bo, rec, deg);
    k_scan1<<<SCAN_BLOCKS, 256, 0, stream>>>(deg, offs, bsum);
    k_scan2<<<1, 256, 0, stream>>>(bsum, bpre);
    k_scan3<<<SCAN_BLOCKS, 256, 0, stream>>>(offs, bpre);
    k_unbin<<<NB, 256, 0, stream>>>(offs, bo, rec, csr);

    k_agg1<<<(NN + 3) / 4, 256, 0, stream>>>(offs, csr, h1, as1, ad1, b1, h1o);
    k_gemm2<<<(NN + 7) / 8, 256, 0, stream>>>(h1o, W2, aS2, aD2, h2, as2, ad2);
    k_agg2<<<(NN + 3) / 4, 256, 0, stream>>>(offs, csr, h2, as2, ad2, b2, o2);

    k_bound<<<SCAN_BLOCKS, 256, 0, stream>>>(bat, lo);
    k_pool<<<NG * 4, 256, 0, stream>>>(o2, lo, pooled);
    k_fin<<<1, 128, 0, stream>>>(pooled, lo, lw, lb, out);
}